// Round 3
// baseline (1681.972 us; speedup 1.0000x reference)
//
#include <hip/hip_runtime.h>
#include <math.h>

#define HH 512
#define WW 512
#define HW (HH*WW)          // 262144
#define BATCH 4
#define NCH 18              // simulated channels (18,19 overwritten at end)
#define BHW (BATCH*HW)
#define TILE 64
#define TP 80               // TILE + 2*HALO
#define TC (TP*TP)          // 6400
#define NT 512

__device__ __constant__ int cDY[8] = {-1,-1, 0, 1, 1, 1, 0,-1};
__device__ __constant__ int cDX[8] = { 0, 1, 1, 1, 0,-1,-1,-1};

// bucket (3 bits) | enough (bit 3)  -- arithmetic identical to rounds 0/1 (passed)
__global__ __launch_bounds__(256) void bv_bucket_kernel(
    const float* __restrict__ vel, unsigned char* __restrict__ bk)
{
    int idx = blockIdx.x*256 + threadIdx.x;
    if (idx >= BHW) return;
    int b = idx >> 18;
    int rem = idx & (HW-1);
    const float* vb = vel + (size_t)b*2*HW;
    float vy = vb[rem];
    float vx = vb[HW + rem];
    float a2 = vy*vy;
    float b2 = vx*vx;
    float mag = sqrtf(a2 + b2);
    float xx = vx / (mag + 0.001f);
    float af = (float)acos((double)xx);
    const float inv2pi = (float)(1.0/(2.0*3.14159265358979323846));
    float raw = inv2pi * af;
    float ang = (vy < 0.0f) ? (1.0f - raw) : raw;
    float t = ang * 8.0f + 0.5f;
    int bkt = (int)floorf(t);
    bkt &= 7;
    unsigned char e = (mag > 0.1f) ? (unsigned char)8 : (unsigned char)0;
    bk[idx] = (unsigned char)(bkt | e);
}

// One fused outer iteration: 8 direction steps, all 18 channels + vdelta.
// 64x64 tile + halo 8 in LDS. Cone property: value_s(i) correct iff
// ring(i) >= s; consumed mask bits always derive from valid values.
__global__ __launch_bounds__(NT) void bv_fused_kernel(
    const float* __restrict__ Win, int Cin,
    float* __restrict__ Wout, int Cout,
    const unsigned char* __restrict__ bkall,
    const float* __restrict__ vel,       // iteration-start velocity
    float* __restrict__ vdout,           // velocity after this iteration
    const float* __restrict__ elem_empty)
{
    __shared__ __align__(16) float SH[4*TC];   // 102.4 KB
    __shared__ unsigned char MSH[TC];          // sa bits per step
    __shared__ unsigned char KSH[TC];          // BK, later SB bits
    __shared__ float EV[NCH];

    const int tid = threadIdx.x;
    const int blk = blockIdx.x;
    const int tx = blk & 7, ty = (blk >> 3) & 7, b = blk >> 6;
    const int x0 = tx*TILE - 8, y0 = ty*TILE - 8;

    const float* inb  = Win  + (size_t)b*Cin*HW;
    float*       outb = Wout + (size_t)b*Cout*HW;
    const unsigned char* bkb = bkall + ((size_t)b << 18);
    const float* velb = vel   + (size_t)b*2*HW;
    float*       vdb  = vdout + (size_t)b*2*HW;

    if (tid < NCH) EV[tid] = elem_empty[tid];

    float* A0 = SH;        float* A1 = SH + TC;
    float* B0 = SH + 2*TC; float* B1 = SH + 3*TC;

    // ---- load ch0, ch1, BK; zero masks (OOB-of-image cells -> 0) ----
    for (int l = tid; l < TC; l += NT) {
        int ly = l / TP, lx = l - ly*TP;
        int gy = y0 + ly, gx = x0 + lx;
        bool in = ((unsigned)gy < HH) && ((unsigned)gx < WW);
        int g = gy*WW + gx;
        float v0 = 0.f, v1 = 0.f; unsigned char kk = 0;
        if (in) { v0 = inb[g]; v1 = inb[HW + g]; kk = bkb[g]; }
        A0[l] = v0; A1[l] = v1; KSH[l] = kk; MSH[l] = 0;
    }
    __syncthreads();

    // ---- phase 1: mask generation + ch0/ch1 evolution ----
    #pragma unroll
    for (int a = 0; a < 8; ++a) {
        const int doff = cDY[a]*TP + cDX[a];
        const int tgt = a | 8;
        float* cA0 = (a & 1) ? B0 : A0;
        float* cA1 = (a & 1) ? B1 : A1;
        float* nA0 = (a & 1) ? A0 : B0;
        float* nA1 = (a & 1) ? A1 : B1;
        // sa bits: match(bk) & empty(i+d) & ~wall(i). OOB cells: KSH=0 -> no match.
        for (int l = tid; l < TC; l += NT) {
            int ln = l + doff; ln = ln < 0 ? 0 : (ln >= TC ? TC-1 : ln);
            if (((KSH[l] & 15) == tgt) && (cA0[ln] > 0.5f) && !(cA1[l] > 0.5f))
                MSH[l] |= (unsigned char)(1 << a);
        }
        __syncthreads();
        // evolve ch0/ch1 (exact reference op order)
        for (int l = tid; l < TC; l += NT) {
            int lo = l - doff; lo = lo < 0 ? 0 : (lo >= TC ? TC-1 : lo);
            float sa = (float)((MSH[l]  >> a) & 1);
            float sb = (float)((MSH[lo] >> a) & 1);
            float w0 = cA0[l], w1 = cA1[l];
            float wo0 = cA0[lo], wo1 = cA1[lo];
            float e0 = EV[0], e1 = EV[1];
            float r0 = w0 - sa*w0; r0 = r0 - sb*w0; r0 = r0 + sa*e0; r0 = r0 + sb*wo0;
            float r1 = w1 - sa*w1; r1 = r1 - sb*w1; r1 = r1 + sa*e1; r1 = r1 + sb*wo1;
            nA0[l] = r0; nA1[l] = r1;
        }
        __syncthreads();
    }
    // final ch0/ch1 in A0/A1 (8 swaps, even)

    // ---- write ch0/ch1 interior; build SB bits into KSH (BK dead now) ----
    for (int li = tid; li < TILE*TILE; li += NT) {
        int iy = li >> 6, ix = li & 63;
        int l = (iy + 8)*TP + ix + 8;
        int g = (ty*TILE + iy)*WW + tx*TILE + ix;
        outb[g]      = A0[l];
        outb[HW + g] = A1[l];
    }
    for (int l = tid; l < TC; l += NT) {
        unsigned sb8 = 0;
        #pragma unroll
        for (int a = 0; a < 8; ++a) {
            int lo = l - (cDY[a]*TP + cDX[a]);
            lo = lo < 0 ? 0 : (lo >= TC ? TC-1 : lo);
            sb8 |= (unsigned)((MSH[lo] >> a) & 1) << a;
        }
        KSH[l] = (unsigned char)sb8;   // writes KSH, reads MSH: no overlap
    }
    __syncthreads();

    // ---- vdelta (exact per-step order; vel fixed during iteration) ----
    for (int li = tid; li < TILE*TILE; li += NT) {
        int iy = li >> 6, ix = li & 63;
        int l = (iy + 8)*TP + ix + 8;
        int gy = ty*TILE + iy, gx = tx*TILE + ix;
        int g = gy*WW + gx;
        unsigned mm = MSH[l], sbb = KSH[l];
        float vy = velb[g], vx = velb[HW + g];
        float ddy = vy, ddx = vx;
        unsigned act = mm | sbb;
        if (act) {
            #pragma unroll
            for (int a = 0; a < 8; ++a) {
                if ((act >> a) & 1) {
                    float sa = (float)((mm  >> a) & 1);
                    float sb = (float)((sbb >> a) & 1);
                    float voy = 0.f, vox = 0.f;
                    if (sb != 0.f) {
                        int go = g - (cDY[a]*WW + cDX[a]);  // in-image when sb=1
                        voy = velb[go]; vox = velb[HW + go];
                    }
                    ddy = ddy - (sa*vy)*0.5f; ddy = ddy + (sb*voy)*0.5f;
                    ddx = ddx - (sa*vx)*0.5f; ddx = ddx + (sb*vox)*0.5f;
                }
            }
        }
        vdb[g]      = ddy;
        vdb[HW + g] = ddx;
    }

    // ---- phase 2: passive channels in pairs, values in registers ----
    float2* PA = reinterpret_cast<float2*>(SH);
    float2* PB = reinterpret_cast<float2*>(SH + 2*TC);

    unsigned mm[13], sbb[13];
    #pragma unroll
    for (int k = 0; k < 13; ++k) {
        int l = tid + k*NT;
        mm[k] = 0; sbb[k] = 0;
        if (l < TC) { mm[k] = MSH[l]; sbb[k] = KSH[l]; }
    }

    #pragma unroll 1
    for (int cp = 0; cp < 8; ++cp) {
        const int c = 2 + cp*2;
        const float* p0 = inb + (size_t)c*HW;
        const float* p1 = p0 + HW;
        float2 V[13];
        #pragma unroll
        for (int k = 0; k < 13; ++k) {
            int l = tid + k*NT;
            V[k] = make_float2(0.f, 0.f);
            if (l < TC) {
                int ly = l / TP, lx = l - ly*TP;
                int gy = y0 + ly, gx = x0 + lx;
                bool in = ((unsigned)gy < HH) && ((unsigned)gx < WW);
                int g = gy*WW + gx;
                float v0 = 0.f, v1 = 0.f;
                if (in) { v0 = p0[g]; v1 = p1[g]; }
                V[k] = make_float2(v0, v1);
                PA[l] = V[k]; PB[l] = V[k];   // seed both (inactive cells never rewrite)
            }
        }
        __syncthreads();
        const float e0 = EV[c], e1 = EV[c+1];
        #pragma unroll
        for (int a = 0; a < 8; ++a) {
            const int doff = cDY[a]*TP + cDX[a];
            float2* cur = (a & 1) ? PB : PA;
            float2* nxt = (a & 1) ? PA : PB;
            #pragma unroll
            for (int k = 0; k < 13; ++k) {
                int l = tid + k*NT;
                if (l < TC && (mm[k] | sbb[k])) {
                    float sa = (float)((mm[k]  >> a) & 1);
                    float sb = (float)((sbb[k] >> a) & 1);
                    float2 w = V[k];
                    float2 wo = make_float2(0.f, 0.f);
                    if (sb != 0.f) {
                        int lo = l - doff; lo = lo < 0 ? 0 : (lo >= TC ? TC-1 : lo);
                        wo = cur[lo];
                    }
                    float r0 = w.x - sa*w.x; r0 = r0 - sb*w.x; r0 = r0 + sa*e0; r0 = r0 + sb*wo.x;
                    float r1 = w.y - sa*w.y; r1 = r1 - sb*w.y; r1 = r1 + sa*e1; r1 = r1 + sb*wo.y;
                    V[k] = make_float2(r0, r1);
                    nxt[l] = V[k];            // keep ping-pong fresh every step
                }
            }
            __syncthreads();
        }
        // write out from registers (no LDS read; step-7 sync protects reuse)
        #pragma unroll
        for (int k = 0; k < 13; ++k) {
            int l = tid + k*NT;
            if (l < TC) {
                int ly = l / TP, lx = l - ly*TP;
                if (ly >= 8 && ly < 72 && lx >= 8 && lx < 72) {
                    int g = (y0 + ly)*WW + x0 + lx;
                    outb[(size_t)c*HW + g]     = V[k].x;
                    outb[(size_t)(c+1)*HW + g] = V[k].y;
                }
            }
        }
    }
}

// smooth(0.95*v): conv3x3(ones/18, zero-pad) + center*0.5 -> world ch18,19
__global__ __launch_bounds__(256) void bv_smooth_kernel(
    const float* __restrict__ vin, float* __restrict__ dout)
{
    int idx = blockIdx.x*256 + threadIdx.x;
    if (idx >= BATCH*2*HW) return;
    int x = idx & (WW-1);
    int y = (idx >> 9) & (HH-1);
    int c = (idx >> 18) & 1;
    int b = idx >> 19;
    const float* vb = vin + (size_t)(b*2 + c)*HW;
    const float w18 = (float)(1.0/18.0);
    float acc = 0.0f;
    for (int ky = -1; ky <= 1; ++ky) {
        int yy = y + ky;
        if ((unsigned)yy >= HH) continue;
        for (int kx = -1; kx <= 1; ++kx) {
            int xx2 = x + kx;
            if ((unsigned)xx2 >= WW) continue;
            float s = 0.95f * vb[yy*WW + xx2];
            acc += s * w18;
        }
    }
    float sc = 0.95f * vb[y*WW + x];
    float res = acc + sc * 0.5f;
    dout[((size_t)b*20 + 18 + c)*HW + (size_t)(y<<9) + x] = res;
}

__global__ __launch_bounds__(256) void bv_copyvel_kernel(float* __restrict__ dout)
{
    int idx = blockIdx.x*256 + threadIdx.x;
    if (idx >= BATCH*2*HW) return;
    int x = idx & (WW-1);
    int y = (idx >> 9) & (HH-1);
    int c = (idx >> 18) & 1;
    int b = idx >> 19;
    float v = dout[((size_t)b*20 + 18 + c)*HW + (size_t)(y<<9) + x];
    dout[(size_t)BATCH*20*HW + (size_t)idx] = v;
}

extern "C" void kernel_launch(void* const* d_in, const int* in_sizes, int n_in,
                              void* d_out, int out_size, void* d_ws, size_t ws_size,
                              hipStream_t stream)
{
    const float* world_in   = (const float*)d_in[0];
    const float* vel_in     = (const float*)d_in[1];
    const float* elem_empty = (const float*)d_in[2];
    float* out = (float*)d_out;

    // ws layout: worldA (18ch) | vd1 | bk
    float* wsA  = (float*)d_ws;                               // 4*18*HW floats
    float* vd1  = wsA + (size_t)BATCH*NCH*HW;                 // 4*2*HW floats
    unsigned char* bk = (unsigned char*)(vd1 + (size_t)BATCH*2*HW);
    float* vel2 = out + (size_t)BATCH*20*HW;                  // out tail

    dim3 blk(256);
    dim3 grd((BHW + 255)/256);
    dim3 g2((BATCH*2*HW + 255)/256);
    dim3 gf(BATCH*8*8);      // 256 tile-blocks
    dim3 bf(NT);

    // ---- iteration 1 ----
    bv_bucket_kernel<<<grd, blk, 0, stream>>>(vel_in, bk);
    bv_fused_kernel<<<gf, bf, 0, stream>>>(world_in, 20, wsA, NCH, bk,
                                           vel_in, vd1, elem_empty);
    // ---- iteration 2 ----
    bv_bucket_kernel<<<grd, blk, 0, stream>>>(vd1, bk);
    bv_fused_kernel<<<gf, bf, 0, stream>>>(wsA, NCH, out, 20, bk,
                                           vd1, vel2, elem_empty);
    // ---- epilogue ----
    bv_smooth_kernel<<<g2, blk, 0, stream>>>(vel2, out);
    bv_copyvel_kernel<<<g2, blk, 0, stream>>>(out);
}

// Round 4
// 887.334 us; speedup vs baseline: 1.8955x; 1.8955x over previous
//
#include <hip/hip_runtime.h>
#include <math.h>

#define HH 512
#define WW 512
#define HW (HH*WW)          // 262144
#define BATCH 4
#define NCH 18              // simulated channels (18,19 overwritten at end)
#define BHW (BATCH*HW)

__device__ __constant__ int cDY[8] = {-1,-1, 0, 1, 1, 1, 0,-1};
__device__ __constant__ int cDX[8] = { 0, 1, 1, 1, 0,-1,-1,-1};
__device__ __constant__ int cDG[8] = {-512,-511,1,513,512,511,-1,-513}; // dy*WW+dx
__device__ __constant__ int cDT[8] = {-48,-47,1,49,48,47,-1,-49};       // dy*ATP+dx

// bucket (3 bits) | enough (bit 3)  -- arithmetic identical to rounds 0-2 (passed)
__global__ __launch_bounds__(256) void bv_bucket_kernel(
    const float* __restrict__ vel, unsigned char* __restrict__ bk)
{
    int idx = blockIdx.x*256 + threadIdx.x;
    if (idx >= BHW) return;
    int b = idx >> 18;
    int rem = idx & (HW-1);
    const float* vb = vel + (size_t)b*2*HW;
    float vy = vb[rem];
    float vx = vb[HW + rem];
    float a2 = vy*vy;
    float b2 = vx*vx;
    float mag = sqrtf(a2 + b2);
    float xx = vx / (mag + 0.001f);
    float af = (float)acos((double)xx);
    const float inv2pi = (float)(1.0/(2.0*3.14159265358979323846));
    float raw = inv2pi * af;
    float ang = (vy < 0.0f) ? (1.0f - raw) : raw;
    float t = ang * 8.0f + 0.5f;
    int bkt = (int)floorf(t);
    bkt &= 7;
    unsigned char e = (mag > 0.1f) ? (unsigned char)8 : (unsigned char)0;
    bk[idx] = (unsigned char)(bkt | e);
}

// ---- Kernel A: evolve ch0/ch1 in LDS (32x32 tile + halo 8), emit masks,
//      final ch0/ch1, and vdelta. Validity: V_a valid iff ring >= a.
#define ATP 48
#define ATC (48*48)   // 2304
#define ANT 256

__global__ __launch_bounds__(ANT) void bv_mask_kernel(
    const float* __restrict__ Win, int Cin,
    float* __restrict__ Wout, int Cout,
    const unsigned char* __restrict__ bkall,
    const float* __restrict__ vel,
    float* __restrict__ vdout,
    unsigned char* __restrict__ Mout,
    unsigned char* __restrict__ SBout,
    const float* __restrict__ elem_empty)
{
    __shared__ float A0[ATC], A1[ATC], B0[ATC], B1[ATC];   // 36.9 KB
    __shared__ unsigned char MSH[ATC], KSH[ATC];           // 4.6 KB

    const int tid = threadIdx.x;
    const int blk = blockIdx.x;
    const int tx = blk & 15, ty = (blk >> 4) & 15, b = blk >> 8;
    const int x0 = tx*32 - 8, y0 = ty*32 - 8;

    const float* inb  = Win  + (size_t)b*Cin*HW;
    float*       outb = Wout + (size_t)b*Cout*HW;
    const unsigned char* bkb = bkall + ((size_t)b << 18);
    const float* velb = vel   + (size_t)b*2*HW;
    float*       vdb  = vdout + (size_t)b*2*HW;
    unsigned char* Mb  = Mout  + ((size_t)b << 18);
    unsigned char* SBb = SBout + ((size_t)b << 18);

    const float e0 = elem_empty[0];
    const float e1 = elem_empty[1];

    for (int l = tid; l < ATC; l += ANT) {
        int ly = l / ATP, lx = l - ly*ATP;
        int gy = y0 + ly, gx = x0 + lx;
        bool in = ((unsigned)gy < HH) && ((unsigned)gx < WW);
        int g = gy*WW + gx;
        float v0 = 0.f, v1 = 0.f; unsigned char kk = 0;
        if (in) { v0 = inb[g]; v1 = inb[HW + g]; kk = bkb[g]; }
        A0[l] = v0; A1[l] = v1; KSH[l] = kk; MSH[l] = 0;
    }
    __syncthreads();

    #pragma unroll
    for (int a = 0; a < 8; ++a) {
        const int doff = cDT[a];
        const int tgt = a | 8;
        float* cA0 = (a & 1) ? B0 : A0;
        float* cA1 = (a & 1) ? B1 : A1;
        float* nA0 = (a & 1) ? A0 : B0;
        float* nA1 = (a & 1) ? A1 : B1;
        for (int l = tid; l < ATC; l += ANT) {
            int ln = l + doff; ln = ln < 0 ? 0 : (ln >= ATC ? ATC-1 : ln);
            if (((KSH[l] & 15) == tgt) && (cA0[ln] > 0.5f) && !(cA1[l] > 0.5f))
                MSH[l] |= (unsigned char)(1 << a);
        }
        __syncthreads();
        for (int l = tid; l < ATC; l += ANT) {
            int lo = l - doff; lo = lo < 0 ? 0 : (lo >= ATC ? ATC-1 : lo);
            float sa = (float)((MSH[l]  >> a) & 1);
            float sb = (float)((MSH[lo] >> a) & 1);
            float w0 = cA0[l], w1 = cA1[l];
            float wo0 = cA0[lo], wo1 = cA1[lo];
            float r0 = w0 - sa*w0; r0 = r0 - sb*w0; r0 = r0 + sa*e0; r0 = r0 + sb*wo0;
            float r1 = w1 - sa*w1; r1 = r1 - sb*w1; r1 = r1 + sa*e1; r1 = r1 + sb*wo1;
            nA0[l] = r0; nA1[l] = r1;
        }
        __syncthreads();
    }
    // final ch0/ch1 in A0/A1

    // SB bits into KSH (bk dead); valid for interior (proof in notes)
    for (int l = tid; l < ATC; l += ANT) {
        unsigned sb8 = 0;
        #pragma unroll
        for (int a = 0; a < 8; ++a) {
            int lo = l - cDT[a]; lo = lo < 0 ? 0 : (lo >= ATC ? ATC-1 : lo);
            sb8 |= (unsigned)((MSH[lo] >> a) & 1) << a;
        }
        KSH[l] = (unsigned char)sb8;
    }
    __syncthreads();

    // interior: write ch0/ch1, M, SB, vdelta
    for (int li = tid; li < 32*32; li += ANT) {
        int iy = li >> 5, ix = li & 31;
        int l = (iy + 8)*ATP + ix + 8;
        int gy = ty*32 + iy, gx = tx*32 + ix;
        int g = gy*WW + gx;
        outb[g]      = A0[l];
        outb[HW + g] = A1[l];
        unsigned mm = MSH[l], sbb = KSH[l];
        Mb[g]  = (unsigned char)mm;
        SBb[g] = (unsigned char)sbb;

        float vy = velb[g], vx = velb[HW + g];
        float ddy = vy, ddx = vx;
        unsigned act = mm | sbb;
        if (act) {
            #pragma unroll
            for (int a = 0; a < 8; ++a) {
                if ((act >> a) & 1) {
                    float sa = (float)((mm  >> a) & 1);
                    float sb = (float)((sbb >> a) & 1);
                    float voy = 0.f, vox = 0.f;
                    if (sb != 0.f) {
                        int go = g - cDG[a];     // in-image when sb=1
                        voy = velb[go]; vox = velb[HW + go];
                    }
                    ddy = ddy - (sa*vy)*0.5f; ddy = ddy + (sb*voy)*0.5f;
                    ddx = ddx - (sa*vx)*0.5f; ddx = ddx + (sb*vox)*0.5f;
                }
            }
        }
        vdb[g]      = ddy;
        vdb[HW + g] = ddx;
    }
}

// ---- rare-path evaluator: subtraction trees (both sa&sb in one step).
// Depth <= 8 (step strictly decreases along every edge).
__device__ __attribute__((noinline)) float bv_eval(
    int cell, int stp,
    const unsigned char* __restrict__ M,
    const unsigned char* __restrict__ SB,
    const float* __restrict__ initc)
{
    float vstk[10]; int vsp = 0;
    int cs_cell[10], cs_stp[10], cs_ph[10]; int csp = 0;
    cs_cell[0] = cell; cs_stp[0] = stp; cs_ph[0] = 0; csp = 1;
    while (csp > 0) {
        int ph = cs_ph[csp-1];
        if (ph == 0) {
            int cc = cs_cell[csp-1], ss = cs_stp[csp-1];
            float result = 0.0f; int have = 0;
            while (true) {
                if (ss < 0) { result = initc[cc]; have = 1; break; }
                unsigned m = M[cc], sb = SB[cc];
                unsigned evt = (m | sb) & ((2u << ss) - 1u);
                if (!evt) { result = initc[cc]; have = 1; break; }
                int bb = 31 - __builtin_clz(evt);
                int ia = (m >> bb) & 1, ib = (sb >> bb) & 1;
                if (ia && ib) {
                    cs_cell[csp-1] = cc; cs_stp[csp-1] = bb; cs_ph[csp-1] = 1;
                    cs_cell[csp] = cc - cDG[bb]; cs_stp[csp] = bb - 1; cs_ph[csp] = 0; csp++;
                    break;
                }
                if (ia) { result = 0.0f; have = 1; break; }   // e=0 for c>=2
                cc -= cDG[bb]; ss = bb - 1;
            }
            if (have) { vstk[vsp++] = result; csp--; }
        } else if (ph == 1) {
            cs_ph[csp-1] = 2;
            cs_cell[csp] = cs_cell[csp-1]; cs_stp[csp] = cs_stp[csp-1] - 1;
            cs_ph[csp] = 0; csp++;
        } else {
            float Bv = vstk[--vsp]; float Av = vstk[--vsp];
            vstk[vsp++] = Av - Bv;   // fl(wo - w) == ref's fl(-w + wo)
            csp--;
        }
    }
    return vstk[0];
}

// ---- Kernel B: apply provenance to 16 passive channels. No LDS/barriers.
__global__ __launch_bounds__(256) void bv_apply_kernel(
    const float* __restrict__ Win, int Cin,
    float* __restrict__ Wout, int Cout,
    const unsigned char* __restrict__ M,
    const unsigned char* __restrict__ SB)
{
    int t = blockIdx.x*256 + threadIdx.x;   // over BHW/4
    if (t >= BHW/4) return;
    int p = t << 2;
    int b = p >> 18;
    int own = p & (HW-1);
    const float* inb  = Win  + (size_t)b*Cin*HW;
    float*       outb = Wout + (size_t)b*Cout*HW;
    const unsigned char* Mb  = M  + ((size_t)b << 18);
    const unsigned char* SBb = SB + ((size_t)b << 18);

    uchar4 m4 = *(const uchar4*)(Mb + own);
    uchar4 s4 = *(const uchar4*)(SBb + own);
    unsigned mv[4] = {m4.x, m4.y, m4.z, m4.w};
    unsigned sv[4] = {s4.x, s4.y, s4.z, s4.w};

    int src[4], kind[4], tstp[4];   // kind: 0=INIT@src, 1=ZERO, 2=TREE
    #pragma unroll
    for (int j = 0; j < 4; ++j) {
        int cc = own + j, ss = 7, kd = 0;
        unsigned m = mv[j], sb = sv[j];
        while (true) {
            unsigned evt = (m | sb) & ((2u << ss) - 1u);
            if (!evt) { kd = 0; break; }
            int bb = 31 - __builtin_clz(evt);
            int ia = (m >> bb) & 1, ib = (sb >> bb) & 1;
            if (ia && ib) { kd = 2; break; }
            if (ia) { kd = 1; break; }
            cc -= cDG[bb]; ss = bb - 1;          // sb-only: exact value move
            if (ss < 0) { kd = 0; break; }
            m = Mb[cc]; sb = SBb[cc];
        }
        src[j] = cc; kind[j] = kd; tstp[j] = ss;
    }

    bool fast = true;
    #pragma unroll
    for (int j = 0; j < 4; ++j) fast = fast && (kind[j] == 0) && (src[j] == own + j);

    if (fast) {
        #pragma unroll
        for (int c = 2; c < NCH; ++c) {
            float4 v = *(const float4*)(inb + (size_t)c*HW + own);
            *(float4*)(outb + (size_t)c*HW + own) = v;
        }
        return;
    }
    #pragma unroll
    for (int c = 2; c < NCH; ++c) {
        const float* ic = inb + (size_t)c*HW;
        float4 v = *(const float4*)(ic + own);
        float r[4] = {v.x, v.y, v.z, v.w};
        #pragma unroll
        for (int j = 0; j < 4; ++j) {
            if (kind[j] == 1) r[j] = 0.0f;
            else if (kind[j] == 2) r[j] = bv_eval(src[j], tstp[j], Mb, SBb, ic);
            else if (src[j] != own + j) r[j] = ic[src[j]];
        }
        *(float4*)(outb + (size_t)c*HW + own) = make_float4(r[0], r[1], r[2], r[3]);
    }
}

// smooth(0.95*v): conv3x3(ones/18, zero-pad) + center*0.5 -> world ch18,19
__global__ __launch_bounds__(256) void bv_smooth_kernel(
    const float* __restrict__ vin, float* __restrict__ dout)
{
    int idx = blockIdx.x*256 + threadIdx.x;
    if (idx >= BATCH*2*HW) return;
    int x = idx & (WW-1);
    int y = (idx >> 9) & (HH-1);
    int c = (idx >> 18) & 1;
    int b = idx >> 19;
    const float* vb = vin + (size_t)(b*2 + c)*HW;
    const float w18 = (float)(1.0/18.0);
    float acc = 0.0f;
    for (int ky = -1; ky <= 1; ++ky) {
        int yy = y + ky;
        if ((unsigned)yy >= HH) continue;
        for (int kx = -1; kx <= 1; ++kx) {
            int xx2 = x + kx;
            if ((unsigned)xx2 >= WW) continue;
            float s = 0.95f * vb[yy*WW + xx2];
            acc += s * w18;
        }
    }
    float sc = 0.95f * vb[y*WW + x];
    float res = acc + sc * 0.5f;
    dout[((size_t)b*20 + 18 + c)*HW + (size_t)(y<<9) + x] = res;
}

__global__ __launch_bounds__(256) void bv_copyvel_kernel(float* __restrict__ dout)
{
    int idx = blockIdx.x*256 + threadIdx.x;
    if (idx >= BATCH*2*HW) return;
    int x = idx & (WW-1);
    int y = (idx >> 9) & (HH-1);
    int c = (idx >> 18) & 1;
    int b = idx >> 19;
    float v = dout[((size_t)b*20 + 18 + c)*HW + (size_t)(y<<9) + x];
    dout[(size_t)BATCH*20*HW + (size_t)idx] = v;
}

extern "C" void kernel_launch(void* const* d_in, const int* in_sizes, int n_in,
                              void* d_out, int out_size, void* d_ws, size_t ws_size,
                              hipStream_t stream)
{
    const float* world_in   = (const float*)d_in[0];
    const float* vel_in     = (const float*)d_in[1];
    const float* elem_empty = (const float*)d_in[2];
    float* out = (float*)d_out;

    // ws layout (~86.5 MB): worldA (18ch) | vd1 | bk | M | SB
    float* wsA = (float*)d_ws;                                 // 4*18*HW floats
    float* vd1 = wsA + (size_t)BATCH*NCH*HW;                   // 4*2*HW floats
    unsigned char* bk  = (unsigned char*)(vd1 + (size_t)BATCH*2*HW); // BHW
    unsigned char* Mb  = bk + (size_t)BHW;                     // BHW
    unsigned char* SBb = Mb + (size_t)BHW;                     // BHW
    float* vel2 = out + (size_t)BATCH*20*HW;                   // out tail

    dim3 blk(256);
    dim3 grd((BHW + 255)/256);
    dim3 g2((BATCH*2*HW + 255)/256);
    dim3 gA(BATCH*16*16);       // 1024 tile-blocks
    dim3 gB((BHW/4 + 255)/256); // 1024

    // ---- iteration 1 ----
    bv_bucket_kernel<<<grd, blk, 0, stream>>>(vel_in, bk);
    bv_mask_kernel<<<gA, dim3(ANT), 0, stream>>>(world_in, 20, wsA, NCH, bk,
                                                 vel_in, vd1, Mb, SBb, elem_empty);
    bv_apply_kernel<<<gB, blk, 0, stream>>>(world_in, 20, wsA, NCH, Mb, SBb);
    // ---- iteration 2 ----
    bv_bucket_kernel<<<grd, blk, 0, stream>>>(vd1, bk);
    bv_mask_kernel<<<gA, dim3(ANT), 0, stream>>>(wsA, NCH, out, 20, bk,
                                                 vd1, vel2, Mb, SBb, elem_empty);
    bv_apply_kernel<<<gB, blk, 0, stream>>>(wsA, NCH, out, 20, Mb, SBb);
    // ---- epilogue ----
    bv_smooth_kernel<<<g2, blk, 0, stream>>>(vel2, out);
    bv_copyvel_kernel<<<g2, blk, 0, stream>>>(out);
}

// Round 5
// 868.308 us; speedup vs baseline: 1.9371x; 1.0219x over previous
//
#include <hip/hip_runtime.h>
#include <math.h>

#define HH 512
#define WW 512
#define HW (HH*WW)          // 262144
#define BATCH 4
#define NCH 18              // simulated channels (18,19 overwritten at end)
#define BHW (BATCH*HW)

__device__ __constant__ int cDG[8] = {-512,-511,1,513,512,511,-1,-513}; // dy*WW+dx
__device__ __constant__ int cDT[8] = {-48,-47,1,49,48,47,-1,-49};       // dy*ATP+dx

// bucket (3 bits) | enough (bit 3)  -- arithmetic identical to rounds 0-3 (passed)
__global__ __launch_bounds__(256) void bv_bucket_kernel(
    const float* __restrict__ vel, unsigned char* __restrict__ bk)
{
    int idx = blockIdx.x*256 + threadIdx.x;
    if (idx >= BHW) return;
    int b = idx >> 18;
    int rem = idx & (HW-1);
    const float* vb = vel + (size_t)b*2*HW;
    float vy = vb[rem];
    float vx = vb[HW + rem];
    float a2 = vy*vy;
    float b2 = vx*vx;
    float mag = sqrtf(a2 + b2);
    float xx = vx / (mag + 0.001f);
    float af = (float)acos((double)xx);
    const float inv2pi = (float)(1.0/(2.0*3.14159265358979323846));
    float raw = inv2pi * af;
    float ang = (vy < 0.0f) ? (1.0f - raw) : raw;
    float t = ang * 8.0f + 0.5f;
    int bkt = (int)floorf(t);
    bkt &= 7;
    unsigned char e = (mag > 0.1f) ? (unsigned char)8 : (unsigned char)0;
    bk[idx] = (unsigned char)(bkt | e);
}

// ---- Kernel A: evolve ch0/ch1 in LDS (32x32 tile + halo 8), emit masks,
//      final ch0/ch1, vdelta, and per-cell provenance record (walk in LDS).
//      Validity: M/SB bits <= s at cc valid iff ring(cc) >= s+1; walk keeps
//      ring >= ss+1 invariant (each event: ss decreases, cell moves <= 1).
#define ATP 48
#define ATC (48*48)   // 2304
#define ANT 256

__global__ __launch_bounds__(ANT) void bv_mask_kernel(
    const float* __restrict__ Win, int Cin,
    float* __restrict__ Wout, int Cout,
    const unsigned char* __restrict__ bkall,
    const float* __restrict__ vel,
    float* __restrict__ vdout,
    unsigned char* __restrict__ Mout,
    unsigned char* __restrict__ SBout,
    int* __restrict__ SrcOut,
    const float* __restrict__ elem_empty)
{
    __shared__ float A0[ATC], A1[ATC], B0[ATC], B1[ATC];   // 36.9 KB
    __shared__ unsigned char MSH[ATC], KSH[ATC];           // 4.6 KB

    const int tid = threadIdx.x;
    const int blk = blockIdx.x;
    const int tx = blk & 15, ty = (blk >> 4) & 15, b = blk >> 8;
    const int x0 = tx*32 - 8, y0 = ty*32 - 8;

    const float* inb  = Win  + (size_t)b*Cin*HW;
    float*       outb = Wout + (size_t)b*Cout*HW;
    const unsigned char* bkb = bkall + ((size_t)b << 18);
    const float* velb = vel   + (size_t)b*2*HW;
    float*       vdb  = vdout + (size_t)b*2*HW;
    unsigned char* Mb  = Mout  + ((size_t)b << 18);
    unsigned char* SBb = SBout + ((size_t)b << 18);
    int*           Srb = SrcOut + ((size_t)b << 18);

    const float e0 = elem_empty[0];
    const float e1 = elem_empty[1];

    for (int l = tid; l < ATC; l += ANT) {
        int ly = l / ATP, lx = l - ly*ATP;
        int gy = y0 + ly, gx = x0 + lx;
        bool in = ((unsigned)gy < HH) && ((unsigned)gx < WW);
        int g = gy*WW + gx;
        float v0 = 0.f, v1 = 0.f; unsigned char kk = 0;
        if (in) { v0 = inb[g]; v1 = inb[HW + g]; kk = bkb[g]; }
        A0[l] = v0; A1[l] = v1; KSH[l] = kk; MSH[l] = 0;
    }
    __syncthreads();

    #pragma unroll
    for (int a = 0; a < 8; ++a) {
        const int doff = cDT[a];
        const int tgt = a | 8;
        float* cA0 = (a & 1) ? B0 : A0;
        float* cA1 = (a & 1) ? B1 : A1;
        float* nA0 = (a & 1) ? A0 : B0;
        float* nA1 = (a & 1) ? A1 : B1;
        for (int l = tid; l < ATC; l += ANT) {
            int ln = l + doff; ln = ln < 0 ? 0 : (ln >= ATC ? ATC-1 : ln);
            if (((KSH[l] & 15) == tgt) && (cA0[ln] > 0.5f) && !(cA1[l] > 0.5f))
                MSH[l] |= (unsigned char)(1 << a);
        }
        __syncthreads();
        for (int l = tid; l < ATC; l += ANT) {
            int lo = l - doff; lo = lo < 0 ? 0 : (lo >= ATC ? ATC-1 : lo);
            float sa = (float)((MSH[l]  >> a) & 1);
            float sb = (float)((MSH[lo] >> a) & 1);
            float w0 = cA0[l], w1 = cA1[l];
            float wo0 = cA0[lo], wo1 = cA1[lo];
            float r0 = w0 - sa*w0; r0 = r0 - sb*w0; r0 = r0 + sa*e0; r0 = r0 + sb*wo0;
            float r1 = w1 - sa*w1; r1 = r1 - sb*w1; r1 = r1 + sa*e1; r1 = r1 + sb*wo1;
            nA0[l] = r0; nA1[l] = r1;
        }
        __syncthreads();
    }
    // final ch0/ch1 in A0/A1

    // SB bits into KSH (bk dead)
    for (int l = tid; l < ATC; l += ANT) {
        unsigned sb8 = 0;
        #pragma unroll
        for (int a = 0; a < 8; ++a) {
            int lo = l - cDT[a]; lo = lo < 0 ? 0 : (lo >= ATC ? ATC-1 : lo);
            sb8 |= (unsigned)((MSH[lo] >> a) & 1) << a;
        }
        KSH[l] = (unsigned char)sb8;
    }
    __syncthreads();

    // interior: write ch0/ch1, M, SB, vdelta, provenance record
    for (int li = tid; li < 32*32; li += ANT) {
        int iy = li >> 5, ix = li & 31;
        int l = (iy + 8)*ATP + ix + 8;
        int gy = ty*32 + iy, gx = tx*32 + ix;
        int g = gy*WW + gx;
        outb[g]      = A0[l];
        outb[HW + g] = A1[l];
        unsigned mm = MSH[l], sbb = KSH[l];
        Mb[g]  = (unsigned char)mm;
        SBb[g] = (unsigned char)sbb;

        // vdelta (exact per-step order; vel fixed during iteration)
        float vy = velb[g], vx = velb[HW + g];
        float ddy = vy, ddx = vx;
        unsigned act = mm | sbb;
        if (act) {
            #pragma unroll
            for (int a = 0; a < 8; ++a) {
                if ((act >> a) & 1) {
                    float sa = (float)((mm  >> a) & 1);
                    float sb = (float)((sbb >> a) & 1);
                    float voy = 0.f, vox = 0.f;
                    if (sb != 0.f) {
                        int go = g - cDG[a];     // in-image when sb=1
                        voy = velb[go]; vox = velb[HW + go];
                    }
                    ddy = ddy - (sa*vy)*0.5f; ddy = ddy + (sb*voy)*0.5f;
                    ddx = ddx - (sa*vx)*0.5f; ddx = ddx + (sb*vox)*0.5f;
                }
            }
        }
        vdb[g]      = ddy;
        vdb[HW + g] = ddx;

        // provenance walk in LDS: kind 0=COPY(src) 1=ZERO 2=TREE(src,step)
        int cc = l, ss = 7, kd = 0;
        unsigned m = mm, sb = sbb;
        while (true) {
            unsigned evt = (m | sb) & ((2u << ss) - 1u);
            if (!evt) { kd = 0; break; }
            int bb = 31 - __builtin_clz(evt);
            int ia = (m >> bb) & 1, ib = (sb >> bb) & 1;
            if (ia && ib) { kd = 2; break; }        // tree at (cc, bound ss)
            if (ia) { kd = 1; break; }              // e=0 for c>=2 -> ZERO
            cc -= cDT[bb]; ss = bb - 1;             // sb-only: exact value move
            if (ss < 0) { kd = 0; break; }
            m = MSH[cc]; sb = KSH[cc];
        }
        int cly = cc / ATP, clx = cc - cly*ATP;
        int gsrc = (y0 + cly)*WW + (x0 + clx);      // in-image by construction
        int sst = (kd == 2) ? ss : 0;
        Srb[g] = (kd << 30) | (sst << 27) | gsrc;
    }
}

// ---- rare-path evaluator (global masks): subtraction trees. Depth <= 8.
__device__ __attribute__((noinline)) float bv_eval(
    int cell, int stp,
    const unsigned char* __restrict__ M,
    const unsigned char* __restrict__ SB,
    const float* __restrict__ initc)
{
    float vstk[10]; int vsp = 0;
    int cs_cell[10], cs_stp[10], cs_ph[10]; int csp = 0;
    cs_cell[0] = cell; cs_stp[0] = stp; cs_ph[0] = 0; csp = 1;
    while (csp > 0) {
        int ph = cs_ph[csp-1];
        if (ph == 0) {
            int cc = cs_cell[csp-1], ss = cs_stp[csp-1];
            float result = 0.0f; int have = 0;
            while (true) {
                if (ss < 0) { result = initc[cc]; have = 1; break; }
                unsigned m = M[cc], sb = SB[cc];
                unsigned evt = (m | sb) & ((2u << ss) - 1u);
                if (!evt) { result = initc[cc]; have = 1; break; }
                int bb = 31 - __builtin_clz(evt);
                int ia = (m >> bb) & 1, ib = (sb >> bb) & 1;
                if (ia && ib) {
                    cs_cell[csp-1] = cc; cs_stp[csp-1] = bb; cs_ph[csp-1] = 1;
                    cs_cell[csp] = cc - cDG[bb]; cs_stp[csp] = bb - 1; cs_ph[csp] = 0; csp++;
                    break;
                }
                if (ia) { result = 0.0f; have = 1; break; }
                cc -= cDG[bb]; ss = bb - 1;
            }
            if (have) { vstk[vsp++] = result; csp--; }
        } else if (ph == 1) {
            cs_ph[csp-1] = 2;
            cs_cell[csp] = cs_cell[csp-1]; cs_stp[csp] = cs_stp[csp-1] - 1;
            cs_ph[csp] = 0; csp++;
        } else {
            float Bv = vstk[--vsp]; float Av = vstk[--vsp];
            vstk[vsp++] = Av - Bv;   // fl(wo - w)
            csp--;
        }
    }
    return vstk[0];
}

// ---- Kernel B: apply precomputed provenance to 16 passive channels.
__global__ __launch_bounds__(256) void bv_apply_kernel(
    const float* __restrict__ Win, int Cin,
    float* __restrict__ Wout, int Cout,
    const int* __restrict__ Src,
    const unsigned char* __restrict__ M,
    const unsigned char* __restrict__ SB)
{
    int t = blockIdx.x*256 + threadIdx.x;   // over BHW/4
    if (t >= BHW/4) return;
    int p = t << 2;
    int b = p >> 18;
    int own = p & (HW-1);
    const float* inb  = Win  + (size_t)b*Cin*HW;
    float*       outb = Wout + (size_t)b*Cout*HW;
    const unsigned char* Mb  = M  + ((size_t)b << 18);
    const unsigned char* SBb = SB + ((size_t)b << 18);
    const int* Srb = Src + ((size_t)b << 18);

    int4 s4 = *(const int4*)(Srb + own);
    unsigned sv[4] = {(unsigned)s4.x, (unsigned)s4.y, (unsigned)s4.z, (unsigned)s4.w};
    int kind[4], idx[4], stp[4];
    #pragma unroll
    for (int j = 0; j < 4; ++j) {
        kind[j] = (int)(sv[j] >> 30);
        stp[j]  = (int)((sv[j] >> 27) & 7u);
        idx[j]  = (int)(sv[j] & 0x3FFFFu);
    }

    bool fast = true;
    #pragma unroll
    for (int j = 0; j < 4; ++j) fast = fast && (kind[j] == 0) && (idx[j] == own + j);

    if (fast) {
        #pragma unroll
        for (int c = 2; c < NCH; ++c) {
            float4 v = *(const float4*)(inb + (size_t)c*HW + own);
            *(float4*)(outb + (size_t)c*HW + own) = v;
        }
        return;
    }
    #pragma unroll
    for (int c = 2; c < NCH; ++c) {
        const float* ic = inb + (size_t)c*HW;
        float r[4];
        #pragma unroll
        for (int j = 0; j < 4; ++j) {
            if (kind[j] == 1)      r[j] = 0.0f;
            else if (kind[j] == 2) r[j] = bv_eval(idx[j], stp[j], Mb, SBb, ic);
            else                   r[j] = ic[idx[j]];   // independent dword gather
        }
        *(float4*)(outb + (size_t)c*HW + own) = make_float4(r[0], r[1], r[2], r[3]);
    }
}

// smooth(0.95*v): conv3x3(ones/18, zero-pad) + center*0.5 -> world ch18,19
__global__ __launch_bounds__(256) void bv_smooth_kernel(
    const float* __restrict__ vin, float* __restrict__ dout)
{
    int idx = blockIdx.x*256 + threadIdx.x;
    if (idx >= BATCH*2*HW) return;
    int x = idx & (WW-1);
    int y = (idx >> 9) & (HH-1);
    int c = (idx >> 18) & 1;
    int b = idx >> 19;
    const float* vb = vin + (size_t)(b*2 + c)*HW;
    const float w18 = (float)(1.0/18.0);
    float acc = 0.0f;
    for (int ky = -1; ky <= 1; ++ky) {
        int yy = y + ky;
        if ((unsigned)yy >= HH) continue;
        for (int kx = -1; kx <= 1; ++kx) {
            int xx2 = x + kx;
            if ((unsigned)xx2 >= WW) continue;
            float s = 0.95f * vb[yy*WW + xx2];
            acc += s * w18;
        }
    }
    float sc = 0.95f * vb[y*WW + x];
    float res = acc + sc * 0.5f;
    dout[((size_t)b*20 + 18 + c)*HW + (size_t)(y<<9) + x] = res;
}

__global__ __launch_bounds__(256) void bv_copyvel_kernel(float* __restrict__ dout)
{
    int idx = blockIdx.x*256 + threadIdx.x;
    if (idx >= BATCH*2*HW) return;
    int x = idx & (WW-1);
    int y = (idx >> 9) & (HH-1);
    int c = (idx >> 18) & 1;
    int b = idx >> 19;
    float v = dout[((size_t)b*20 + 18 + c)*HW + (size_t)(y<<9) + x];
    dout[(size_t)BATCH*20*HW + (size_t)idx] = v;
}

extern "C" void kernel_launch(void* const* d_in, const int* in_sizes, int n_in,
                              void* d_out, int out_size, void* d_ws, size_t ws_size,
                              hipStream_t stream)
{
    const float* world_in   = (const float*)d_in[0];
    const float* vel_in     = (const float*)d_in[1];
    const float* elem_empty = (const float*)d_in[2];
    float* out = (float*)d_out;

    // ws layout (~91.2 MB): worldA (18ch) | vd1 | bk | M | SB | Src
    float* wsA = (float*)d_ws;                                 // 4*18*HW floats
    float* vd1 = wsA + (size_t)BATCH*NCH*HW;                   // 4*2*HW floats
    unsigned char* bk  = (unsigned char*)(vd1 + (size_t)BATCH*2*HW); // BHW
    unsigned char* Mb  = bk + (size_t)BHW;                     // BHW
    unsigned char* SBb = Mb + (size_t)BHW;                     // BHW
    int* Srcb = (int*)(SBb + (size_t)BHW);                     // BHW ints
    float* vel2 = out + (size_t)BATCH*20*HW;                   // out tail

    dim3 blk(256);
    dim3 grd((BHW + 255)/256);
    dim3 g2((BATCH*2*HW + 255)/256);
    dim3 gA(BATCH*16*16);       // 1024 tile-blocks
    dim3 gB((BHW/4 + 255)/256); // 1024

    // ---- iteration 1 ----
    bv_bucket_kernel<<<grd, blk, 0, stream>>>(vel_in, bk);
    bv_mask_kernel<<<gA, dim3(ANT), 0, stream>>>(world_in, 20, wsA, NCH, bk,
                                                 vel_in, vd1, Mb, SBb, Srcb, elem_empty);
    bv_apply_kernel<<<gB, blk, 0, stream>>>(world_in, 20, wsA, NCH, Srcb, Mb, SBb);
    // ---- iteration 2 ----
    bv_bucket_kernel<<<grd, blk, 0, stream>>>(vd1, bk);
    bv_mask_kernel<<<gA, dim3(ANT), 0, stream>>>(wsA, NCH, out, 20, bk,
                                                 vd1, vel2, Mb, SBb, Srcb, elem_empty);
    bv_apply_kernel<<<gB, blk, 0, stream>>>(wsA, NCH, out, 20, Srcb, Mb, SBb);
    // ---- epilogue ----
    bv_smooth_kernel<<<g2, blk, 0, stream>>>(vel2, out);
    bv_copyvel_kernel<<<g2, blk, 0, stream>>>(out);
}

// Round 6
// 661.767 us; speedup vs baseline: 2.5416x; 1.3121x over previous
//
#include <hip/hip_runtime.h>
#include <math.h>

#define HH 512
#define WW 512
#define HW (HH*WW)          // 262144
#define BATCH 4
#define NCH 18              // simulated channels (18,19 overwritten at end)
#define BHW (BATCH*HW)

__device__ __constant__ int cDG[8] = {-512,-511,1,513,512,511,-1,-513}; // dy*WW+dx
__device__ __constant__ int cDT[8] = {-48,-47,1,49,48,47,-1,-49};       // dy*ATP+dx

// bucket (3 bits) | enough (bit 3); also zeroes the program counter
__global__ __launch_bounds__(256) void bv_bucket_kernel(
    const float* __restrict__ vel, unsigned char* __restrict__ bk,
    unsigned* __restrict__ pcount)
{
    int idx = blockIdx.x*256 + threadIdx.x;
    if (idx == 0) *pcount = 0;
    if (idx >= BHW) return;
    int b = idx >> 18;
    int rem = idx & (HW-1);
    const float* vb = vel + (size_t)b*2*HW;
    float vy = vb[rem];
    float vx = vb[HW + rem];
    float a2 = vy*vy;
    float b2 = vx*vx;
    float mag = sqrtf(a2 + b2);
    float xx = vx / (mag + 0.001f);
    float af = (float)acos((double)xx);
    const float inv2pi = (float)(1.0/(2.0*3.14159265358979323846));
    float raw = inv2pi * af;
    float ang = (vy < 0.0f) ? (1.0f - raw) : raw;
    float t = ang * 8.0f + 0.5f;
    int bkt = (int)floorf(t);
    bkt &= 7;
    unsigned char e = (mag > 0.1f) ? (unsigned char)8 : (unsigned char)0;
    bk[idx] = (unsigned char)(bkt | e);
}

// ---- Kernel A: evolve ch0/ch1 in LDS (32x32 tile + halo 8), emit masks,
//      final ch0/ch1, vdelta, provenance record; tree cells emit a postfix
//      program (built from LDS masks) into a bump-allocated global buffer.
//      Record: bits[31:30]=kind. 0=COPY payload gsrc; 1=ZERO; 2=PROG payload
//      offset; 3=EVAL payload (ss<<18)|gsrc (fallback, overflow only).
#define ATP 48
#define ATC (48*48)   // 2304
#define ANT 256

__global__ __launch_bounds__(ANT) void bv_mask_kernel(
    const float* __restrict__ Win, int Cin,
    float* __restrict__ Wout, int Cout,
    const unsigned char* __restrict__ bkall,
    const float* __restrict__ vel,
    float* __restrict__ vdout,
    unsigned char* __restrict__ Mout,
    unsigned char* __restrict__ SBout,
    int* __restrict__ SrcOut,
    unsigned* __restrict__ prog,
    unsigned* __restrict__ pcount,
    unsigned progcap,
    const float* __restrict__ elem_empty)
{
    __shared__ float A0[ATC], A1[ATC], B0[ATC], B1[ATC];   // 36.9 KB
    __shared__ unsigned char MSH[ATC], KSH[ATC];           // 4.6 KB

    const int tid = threadIdx.x;
    const int blk = blockIdx.x;
    const int tx = blk & 15, ty = (blk >> 4) & 15, b = blk >> 8;
    const int x0 = tx*32 - 8, y0 = ty*32 - 8;

    const float* inb  = Win  + (size_t)b*Cin*HW;
    float*       outb = Wout + (size_t)b*Cout*HW;
    const unsigned char* bkb = bkall + ((size_t)b << 18);
    const float* velb = vel   + (size_t)b*2*HW;
    float*       vdb  = vdout + (size_t)b*2*HW;
    unsigned char* Mb  = Mout  + ((size_t)b << 18);
    unsigned char* SBb = SBout + ((size_t)b << 18);
    int*           Srb = SrcOut + ((size_t)b << 18);

    const float e0 = elem_empty[0];
    const float e1 = elem_empty[1];

    for (int l = tid; l < ATC; l += ANT) {
        int ly = l / ATP, lx = l - ly*ATP;
        int gy = y0 + ly, gx = x0 + lx;
        bool in = ((unsigned)gy < HH) && ((unsigned)gx < WW);
        int g = gy*WW + gx;
        float v0 = 0.f, v1 = 0.f; unsigned char kk = 0;
        if (in) { v0 = inb[g]; v1 = inb[HW + g]; kk = bkb[g]; }
        A0[l] = v0; A1[l] = v1; KSH[l] = kk; MSH[l] = 0;
    }
    __syncthreads();

    #pragma unroll
    for (int a = 0; a < 8; ++a) {
        const int doff = cDT[a];
        const int tgt = a | 8;
        float* cA0 = (a & 1) ? B0 : A0;
        float* cA1 = (a & 1) ? B1 : A1;
        float* nA0 = (a & 1) ? A0 : B0;
        float* nA1 = (a & 1) ? A1 : B1;
        for (int l = tid; l < ATC; l += ANT) {
            int ln = l + doff; ln = ln < 0 ? 0 : (ln >= ATC ? ATC-1 : ln);
            if (((KSH[l] & 15) == tgt) && (cA0[ln] > 0.5f) && !(cA1[l] > 0.5f))
                MSH[l] |= (unsigned char)(1 << a);
        }
        __syncthreads();
        for (int l = tid; l < ATC; l += ANT) {
            int lo = l - doff; lo = lo < 0 ? 0 : (lo >= ATC ? ATC-1 : lo);
            float sa = (float)((MSH[l]  >> a) & 1);
            float sb = (float)((MSH[lo] >> a) & 1);
            float w0 = cA0[l], w1 = cA1[l];
            float wo0 = cA0[lo], wo1 = cA1[lo];
            float r0 = w0 - sa*w0; r0 = r0 - sb*w0; r0 = r0 + sa*e0; r0 = r0 + sb*wo0;
            float r1 = w1 - sa*w1; r1 = r1 - sb*w1; r1 = r1 + sa*e1; r1 = r1 + sb*wo1;
            nA0[l] = r0; nA1[l] = r1;
        }
        __syncthreads();
    }
    // final ch0/ch1 in A0/A1

    // SB bits into KSH (bk dead)
    for (int l = tid; l < ATC; l += ANT) {
        unsigned sb8 = 0;
        #pragma unroll
        for (int a = 0; a < 8; ++a) {
            int lo = l - cDT[a]; lo = lo < 0 ? 0 : (lo >= ATC ? ATC-1 : lo);
            sb8 |= (unsigned)((MSH[lo] >> a) & 1) << a;
        }
        KSH[l] = (unsigned char)sb8;
    }
    __syncthreads();

    // interior: write ch0/ch1, M, SB, vdelta, provenance record
    for (int li = tid; li < 32*32; li += ANT) {
        int iy = li >> 5, ix = li & 31;
        int l = (iy + 8)*ATP + ix + 8;
        int gy = ty*32 + iy, gx = tx*32 + ix;
        int g = gy*WW + gx;
        outb[g]      = A0[l];
        outb[HW + g] = A1[l];
        unsigned mm = MSH[l], sbb = KSH[l];
        Mb[g]  = (unsigned char)mm;
        SBb[g] = (unsigned char)sbb;

        // vdelta (exact per-step order; vel fixed during iteration)
        float vy = velb[g], vx = velb[HW + g];
        float ddy = vy, ddx = vx;
        unsigned act = mm | sbb;
        if (act) {
            #pragma unroll
            for (int a = 0; a < 8; ++a) {
                if ((act >> a) & 1) {
                    float sa = (float)((mm  >> a) & 1);
                    float sb = (float)((sbb >> a) & 1);
                    float voy = 0.f, vox = 0.f;
                    if (sb != 0.f) {
                        int go = g - cDG[a];     // in-image when sb=1
                        voy = velb[go]; vox = velb[HW + go];
                    }
                    ddy = ddy - (sa*vy)*0.5f; ddy = ddy + (sb*voy)*0.5f;
                    ddx = ddx - (sa*vx)*0.5f; ddx = ddx + (sb*vox)*0.5f;
                }
            }
        }
        vdb[g]      = ddy;
        vdb[HW + g] = ddx;

        // provenance walk in LDS
        int cc = l, ss = 7, kd = 0;
        unsigned m = mm, sb = sbb;
        while (true) {
            unsigned evt = (m | sb) & ((2u << ss) - 1u);
            if (!evt) { kd = 0; break; }
            int bb = 31 - __builtin_clz(evt);
            int ia = (m >> bb) & 1, ib = (sb >> bb) & 1;
            if (ia && ib) { kd = 2; break; }        // tree at (cc, ss)
            if (ia) { kd = 1; break; }              // e=0 for c>=2 -> ZERO
            cc -= cDT[bb]; ss = bb - 1;             // sb-only: exact value move
            if (ss < 0) { kd = 0; break; }
            m = MSH[cc]; sb = KSH[cc];
        }
        unsigned rec;
        if (kd == 0) {
            int cly = cc / ATP, clx = cc - cly*ATP;
            rec = (unsigned)((y0 + cly)*WW + (x0 + clx));
        } else if (kd == 1) {
            rec = 1u << 30;
        } else {
            // build postfix program mirroring bv_eval's traversal exactly
            unsigned pbuf[48]; int n = 0; bool ok = true;
            int st_c[11], st_s[11], st_p[11]; int sp = 0;
            st_c[0] = cc; st_s[0] = ss; st_p[0] = 0; sp = 1;
            #define BV_EMIT(v) do { if (n < 46) pbuf[n++] = (v); else ok = false; } while (0)
            while (sp > 0 && ok) {
                int ph = st_p[sp-1];
                if (ph == 0) {
                    int c2 = st_c[sp-1], s2 = st_s[sp-1];
                    while (true) {
                        if (s2 < 0) {
                            int cly = c2 / ATP, clx = c2 - cly*ATP;
                            BV_EMIT((unsigned)((y0 + cly)*WW + (x0 + clx)));
                            sp--; break;
                        }
                        unsigned m2 = MSH[c2], k2 = KSH[c2];
                        unsigned ev2 = (m2 | k2) & ((2u << s2) - 1u);
                        if (!ev2) {
                            int cly = c2 / ATP, clx = c2 - cly*ATP;
                            BV_EMIT((unsigned)((y0 + cly)*WW + (x0 + clx)));
                            sp--; break;
                        }
                        int b3 = 31 - __builtin_clz(ev2);
                        int i2 = (m2 >> b3) & 1, j2 = (k2 >> b3) & 1;
                        if (i2 && j2) {
                            st_c[sp-1] = c2; st_s[sp-1] = b3; st_p[sp-1] = 1;
                            if (sp < 11) { st_c[sp] = c2 - cDT[b3]; st_s[sp] = b3 - 1; st_p[sp] = 0; sp++; }
                            else ok = false;
                            break;
                        }
                        if (i2) { BV_EMIT(1u << 30); sp--; break; }
                        c2 -= cDT[b3]; s2 = b3 - 1;
                    }
                } else if (ph == 1) {
                    st_p[sp-1] = 2;
                    if (sp < 11) { st_c[sp] = st_c[sp-1]; st_s[sp] = st_s[sp-1] - 1; st_p[sp] = 0; sp++; }
                    else ok = false;
                } else {
                    BV_EMIT(2u << 30);   // SUB
                    sp--;
                }
            }
            #undef BV_EMIT
            rec = 0;
            if (ok) {
                pbuf[n++] = 3u << 30;    // END
                unsigned base = atomicAdd(pcount, (unsigned)n);
                if (base + (unsigned)n <= progcap) {
                    for (int q = 0; q < n; ++q) prog[base + q] = pbuf[q];
                    rec = (2u << 30) | base;
                } else ok = false;
            }
            if (!ok) {
                int cly = cc / ATP, clx = cc - cly*ATP;
                unsigned gsrc = (unsigned)((y0 + cly)*WW + (x0 + clx));
                rec = (3u << 30) | ((unsigned)ss << 18) | gsrc;
            }
        }
        Srb[g] = (int)rec;
    }
}

// ---- fallback evaluator (global masks): only for program-buffer overflow.
__device__ __attribute__((noinline)) float bv_eval(
    int cell, int stp,
    const unsigned char* __restrict__ M,
    const unsigned char* __restrict__ SB,
    const float* __restrict__ initc)
{
    float vstk[10]; int vsp = 0;
    int cs_cell[10], cs_stp[10], cs_ph[10]; int csp = 0;
    cs_cell[0] = cell; cs_stp[0] = stp; cs_ph[0] = 0; csp = 1;
    while (csp > 0) {
        int ph = cs_ph[csp-1];
        if (ph == 0) {
            int cc = cs_cell[csp-1], ss = cs_stp[csp-1];
            float result = 0.0f; int have = 0;
            while (true) {
                if (ss < 0) { result = initc[cc]; have = 1; break; }
                unsigned m = M[cc], sb = SB[cc];
                unsigned evt = (m | sb) & ((2u << ss) - 1u);
                if (!evt) { result = initc[cc]; have = 1; break; }
                int bb = 31 - __builtin_clz(evt);
                int ia = (m >> bb) & 1, ib = (sb >> bb) & 1;
                if (ia && ib) {
                    cs_cell[csp-1] = cc; cs_stp[csp-1] = bb; cs_ph[csp-1] = 1;
                    cs_cell[csp] = cc - cDG[bb]; cs_stp[csp] = bb - 1; cs_ph[csp] = 0; csp++;
                    break;
                }
                if (ia) { result = 0.0f; have = 1; break; }
                cc -= cDG[bb]; ss = bb - 1;
            }
            if (have) { vstk[vsp++] = result; csp--; }
        } else if (ph == 1) {
            cs_ph[csp-1] = 2;
            cs_cell[csp] = cs_cell[csp-1]; cs_stp[csp] = cs_stp[csp-1] - 1;
            cs_ph[csp] = 0; csp++;
        } else {
            float Bv = vstk[--vsp]; float Av = vstk[--vsp];
            vstk[vsp++] = Av - Bv;
            csp--;
        }
    }
    return vstk[0];
}

// postfix replay: independent gathers, depth <= 10
__device__ inline float bv_replay(const unsigned* __restrict__ pr,
                                  const float* __restrict__ ic)
{
    float vst[11]; int vsp = 0;
    while (true) {
        unsigned w = *pr++;
        unsigned k = w >> 30;
        if (k == 0)      vst[vsp++] = ic[w & 0x3FFFFu];
        else if (k == 1) vst[vsp++] = 0.0f;
        else if (k == 2) { float Bv = vst[--vsp]; float Av = vst[--vsp]; vst[vsp++] = Av - Bv; }
        else break;
    }
    return vst[0];
}

// ---- Kernel B: apply precomputed provenance to 16 passive channels.
__global__ __launch_bounds__(256) void bv_apply_kernel(
    const float* __restrict__ Win, int Cin,
    float* __restrict__ Wout, int Cout,
    const int* __restrict__ Src,
    const unsigned* __restrict__ prog,
    const unsigned char* __restrict__ M,
    const unsigned char* __restrict__ SB)
{
    int t = blockIdx.x*256 + threadIdx.x;   // over BHW/4
    if (t >= BHW/4) return;
    int p = t << 2;
    int b = p >> 18;
    int own = p & (HW-1);
    const float* inb  = Win  + (size_t)b*Cin*HW;
    float*       outb = Wout + (size_t)b*Cout*HW;
    const unsigned char* Mb  = M  + ((size_t)b << 18);
    const unsigned char* SBb = SB + ((size_t)b << 18);
    const int* Srb = Src + ((size_t)b << 18);

    int4 s4 = *(const int4*)(Srb + own);
    unsigned sv[4] = {(unsigned)s4.x, (unsigned)s4.y, (unsigned)s4.z, (unsigned)s4.w};
    int kind[4], idx[4]; unsigned off[4]; int stp[4];
    #pragma unroll
    for (int j = 0; j < 4; ++j) {
        kind[j] = (int)(sv[j] >> 30);
        idx[j]  = (int)(sv[j] & 0x3FFFFu);
        off[j]  = sv[j] & 0x3FFFFFFFu;
        stp[j]  = (int)((sv[j] >> 18) & 7u);
    }

    bool fast = true;
    #pragma unroll
    for (int j = 0; j < 4; ++j) fast = fast && (kind[j] == 0) && (idx[j] == own + j);

    if (fast) {
        #pragma unroll
        for (int c = 2; c < NCH; ++c) {
            float4 v = *(const float4*)(inb + (size_t)c*HW + own);
            *(float4*)(outb + (size_t)c*HW + own) = v;
        }
        return;
    }
    #pragma unroll
    for (int c = 2; c < NCH; ++c) {
        const float* ic = inb + (size_t)c*HW;
        float r[4];
        #pragma unroll
        for (int j = 0; j < 4; ++j) {
            if (kind[j] == 0)      r[j] = ic[idx[j]];       // independent gather
            else if (kind[j] == 1) r[j] = 0.0f;
            else if (kind[j] == 2) r[j] = bv_replay(prog + off[j], ic);
            else                   r[j] = bv_eval(idx[j], stp[j], Mb, SBb, ic);
        }
        *(float4*)(outb + (size_t)c*HW + own) = make_float4(r[0], r[1], r[2], r[3]);
    }
}

// smooth(0.95*v): conv3x3(ones/18, zero-pad) + center*0.5 -> world ch18,19
__global__ __launch_bounds__(256) void bv_smooth_kernel(
    const float* __restrict__ vin, float* __restrict__ dout)
{
    int idx = blockIdx.x*256 + threadIdx.x;
    if (idx >= BATCH*2*HW) return;
    int x = idx & (WW-1);
    int y = (idx >> 9) & (HH-1);
    int c = (idx >> 18) & 1;
    int b = idx >> 19;
    const float* vb = vin + (size_t)(b*2 + c)*HW;
    const float w18 = (float)(1.0/18.0);
    float acc = 0.0f;
    for (int ky = -1; ky <= 1; ++ky) {
        int yy = y + ky;
        if ((unsigned)yy >= HH) continue;
        for (int kx = -1; kx <= 1; ++kx) {
            int xx2 = x + kx;
            if ((unsigned)xx2 >= WW) continue;
            float s = 0.95f * vb[yy*WW + xx2];
            acc += s * w18;
        }
    }
    float sc = 0.95f * vb[y*WW + x];
    float res = acc + sc * 0.5f;
    dout[((size_t)b*20 + 18 + c)*HW + (size_t)(y<<9) + x] = res;
}

__global__ __launch_bounds__(256) void bv_copyvel_kernel(float* __restrict__ dout)
{
    int idx = blockIdx.x*256 + threadIdx.x;
    if (idx >= BATCH*2*HW) return;
    int x = idx & (WW-1);
    int y = (idx >> 9) & (HH-1);
    int c = (idx >> 18) & 1;
    int b = idx >> 19;
    float v = dout[((size_t)b*20 + 18 + c)*HW + (size_t)(y<<9) + x];
    dout[(size_t)BATCH*20*HW + (size_t)idx] = v;
}

extern "C" void kernel_launch(void* const* d_in, const int* in_sizes, int n_in,
                              void* d_out, int out_size, void* d_ws, size_t ws_size,
                              hipStream_t stream)
{
    const float* world_in   = (const float*)d_in[0];
    const float* vel_in     = (const float*)d_in[1];
    const float* elem_empty = (const float*)d_in[2];
    float* out = (float*)d_out;

    // ws layout (~95.4 MB): worldA (18ch) | vd1 | bk | M | SB | Src | cnt | prog
    float* wsA = (float*)d_ws;                                 // 4*18*HW floats
    float* vd1 = wsA + (size_t)BATCH*NCH*HW;                   // 4*2*HW floats
    unsigned char* bk  = (unsigned char*)(vd1 + (size_t)BATCH*2*HW); // BHW
    unsigned char* Mb  = bk + (size_t)BHW;                     // BHW
    unsigned char* SBb = Mb + (size_t)BHW;                     // BHW
    int* Srcb = (int*)(SBb + (size_t)BHW);                     // BHW ints
    unsigned* pcount = (unsigned*)(Srcb + (size_t)BHW);        // 64 B slot
    unsigned* progb  = pcount + 16;
    size_t used = (size_t)((char*)progb - (char*)d_ws);
    unsigned progcap = 0;
    if (ws_size > used + 4096)
        progcap = (unsigned)((ws_size - used - 4096) / 4);
    if (progcap > (1u << 20)) progcap = 1u << 20;              // 4 MB cap
    float* vel2 = out + (size_t)BATCH*20*HW;                   // out tail

    dim3 blk(256);
    dim3 grd((BHW + 255)/256);
    dim3 g2((BATCH*2*HW + 255)/256);
    dim3 gA(BATCH*16*16);       // 1024 tile-blocks
    dim3 gB((BHW/4 + 255)/256); // 1024

    // ---- iteration 1 ----
    bv_bucket_kernel<<<grd, blk, 0, stream>>>(vel_in, bk, pcount);
    bv_mask_kernel<<<gA, dim3(ANT), 0, stream>>>(world_in, 20, wsA, NCH, bk,
                                                 vel_in, vd1, Mb, SBb, Srcb,
                                                 progb, pcount, progcap, elem_empty);
    bv_apply_kernel<<<gB, blk, 0, stream>>>(world_in, 20, wsA, NCH, Srcb, progb, Mb, SBb);
    // ---- iteration 2 ----
    bv_bucket_kernel<<<grd, blk, 0, stream>>>(vd1, bk, pcount);
    bv_mask_kernel<<<gA, dim3(ANT), 0, stream>>>(wsA, NCH, out, 20, bk,
                                                 vd1, vel2, Mb, SBb, Srcb,
                                                 progb, pcount, progcap, elem_empty);
    bv_apply_kernel<<<gB, blk, 0, stream>>>(wsA, NCH, out, 20, Srcb, progb, Mb, SBb);
    // ---- epilogue ----
    bv_smooth_kernel<<<g2, blk, 0, stream>>>(vel2, out);
    bv_copyvel_kernel<<<g2, blk, 0, stream>>>(out);
}

// Round 7
// 572.819 us; speedup vs baseline: 2.9363x; 1.1553x over previous
//
#include <hip/hip_runtime.h>
#include <math.h>

#define HH 512
#define WW 512
#define HW (HH*WW)          // 262144
#define BATCH 4
#define NCH 18              // simulated channels (18,19 overwritten at end)
#define BHW (BATCH*HW)

__device__ __constant__ int cDG[8] = {-512,-511,1,513,512,511,-1,-513}; // dy*WW+dx
__device__ __constant__ int cDT[8] = {-48,-47,1,49,48,47,-1,-49};       // dy*ATP+dx

// bucket (3 bits) | enough (bit 3); also zeroes the program counter
__global__ __launch_bounds__(256) void bv_bucket_kernel(
    const float* __restrict__ vel, unsigned char* __restrict__ bk,
    unsigned* __restrict__ pcount)
{
    int idx = blockIdx.x*256 + threadIdx.x;
    if (idx == 0) *pcount = 0;
    if (idx >= BHW) return;
    int b = idx >> 18;
    int rem = idx & (HW-1);
    const float* vb = vel + (size_t)b*2*HW;
    float vy = vb[rem];
    float vx = vb[HW + rem];
    float a2 = vy*vy;
    float b2 = vx*vx;
    float mag = sqrtf(a2 + b2);
    float xx = vx / (mag + 0.001f);
    float af = (float)acos((double)xx);
    const float inv2pi = (float)(1.0/(2.0*3.14159265358979323846));
    float raw = inv2pi * af;
    float ang = (vy < 0.0f) ? (1.0f - raw) : raw;
    float t = ang * 8.0f + 0.5f;
    int bkt = (int)floorf(t);
    bkt &= 7;
    unsigned char e = (mag > 0.1f) ? (unsigned char)8 : (unsigned char)0;
    bk[idx] = (unsigned char)(bkt | e);
}

// ---- Kernel A: evolve ch0/ch1 in LDS (32x32 tile + halo 8), fused
//      mask+evolve single pass per step (sb recomputed from pre-step state:
//      sa(q)=f(K[q],cA0[q+d],cA1[q]); for cell l, cA0[lo+d]==cA0[l]).
//      Per-thread register carry of own cells' v0/v1/K/M.
//      Rim(ring-0) cells may differ from two-pass version: never consumed
//      (walk invariant ring >= ss+1). Record: bits[31:30]=kind. 0=COPY gsrc;
//      1=ZERO; 2=PROG offset; 3=EVAL (ss<<18)|gsrc (overflow fallback).
#define ATP 48
#define ATC (48*48)   // 2304 = 4*512 + 256
#define ANT 512

__global__ __launch_bounds__(ANT) void bv_mask_kernel(
    const float* __restrict__ Win, int Cin,
    float* __restrict__ Wout, int Cout,
    const unsigned char* __restrict__ bkall,
    const float* __restrict__ vel,
    float* __restrict__ vdout,
    unsigned char* __restrict__ Mout,
    unsigned char* __restrict__ SBout,
    int* __restrict__ SrcOut,
    unsigned* __restrict__ prog,
    unsigned* __restrict__ pcount,
    unsigned progcap,
    const float* __restrict__ elem_empty)
{
    __shared__ float A0[ATC], A1[ATC], B0[ATC], B1[ATC];   // 36.9 KB
    __shared__ unsigned char MSH[ATC], KSH[ATC];           // 4.6 KB

    const int tid = threadIdx.x;
    const int blk = blockIdx.x;
    const int tx = blk & 15, ty = (blk >> 4) & 15, b = blk >> 8;
    const int x0 = tx*32 - 8, y0 = ty*32 - 8;

    const float* inb  = Win  + (size_t)b*Cin*HW;
    float*       outb = Wout + (size_t)b*Cout*HW;
    const unsigned char* bkb = bkall + ((size_t)b << 18);
    const float* velb = vel   + (size_t)b*2*HW;
    float*       vdb  = vdout + (size_t)b*2*HW;
    unsigned char* Mb  = Mout  + ((size_t)b << 18);
    unsigned char* SBb = SBout + ((size_t)b << 18);
    int*           Srb = SrcOut + ((size_t)b << 18);

    const float e0 = elem_empty[0];
    const float e1 = elem_empty[1];

    float v0r[4], v1r[4];
    unsigned kreg[4], mreg[4];

    // ---- load: LDS + register copies for owned cells ----
    #pragma unroll
    for (int k = 0; k < 4; ++k) {
        int l = tid + (k << 9);
        int ly = l / ATP, lx = l - ly*ATP;
        int gy = y0 + ly, gx = x0 + lx;
        bool in = ((unsigned)gy < HH) && ((unsigned)gx < WW);
        int g = gy*WW + gx;
        float v0 = 0.f, v1 = 0.f; unsigned char kk = 0;
        if (in) { v0 = inb[g]; v1 = inb[HW + g]; kk = bkb[g]; }
        A0[l] = v0; A1[l] = v1; KSH[l] = kk;
        v0r[k] = v0; v1r[k] = v1; kreg[k] = kk; mreg[k] = 0;
    }
    if (tid < 256) {    // tail cells: LDS-resident state
        int l = 2048 + tid;
        int ly = l / ATP, lx = l - ly*ATP;
        int gy = y0 + ly, gx = x0 + lx;
        bool in = ((unsigned)gy < HH) && ((unsigned)gx < WW);
        int g = gy*WW + gx;
        float v0 = 0.f, v1 = 0.f; unsigned char kk = 0;
        if (in) { v0 = inb[g]; v1 = inb[HW + g]; kk = bkb[g]; }
        A0[l] = v0; A1[l] = v1; KSH[l] = kk; MSH[l] = 0;
    }
    __syncthreads();

    // ---- 8 fused steps, one barrier each ----
    #pragma unroll
    for (int a = 0; a < 8; ++a) {
        const int doff = cDT[a];
        const unsigned tgt = (unsigned)(a | 8);
        const float* cA0 = (a & 1) ? B0 : A0;
        const float* cA1 = (a & 1) ? B1 : A1;
        float* nA0 = (a & 1) ? A0 : B0;
        float* nA1 = (a & 1) ? A1 : B1;
        #pragma unroll
        for (int k = 0; k < 4; ++k) {
            const int l = tid + (k << 9);
            int ln = l + doff; ln = ln < 0 ? 0 : (ln >= ATC ? ATC-1 : ln);
            int lo = l - doff; lo = lo < 0 ? 0 : (lo >= ATC ? ATC-1 : lo);
            float a0l = v0r[k], a1l = v1r[k];
            float a0n = cA0[ln];
            float a0o = cA0[lo], a1o = cA1[lo];
            unsigned ko = KSH[lo];
            bool sal = ((kreg[k] & 15u) == tgt) & (a0n > 0.5f) & !(a1l > 0.5f);
            bool sao = ((ko & 15u) == tgt) & (a0l > 0.5f) & !(a1o > 0.5f);
            mreg[k] |= (sal ? 1u : 0u) << a;
            float sa = sal ? 1.0f : 0.0f;
            float sb = sao ? 1.0f : 0.0f;
            float r0 = a0l - sa*a0l; r0 = r0 - sb*a0l; r0 = r0 + sa*e0; r0 = r0 + sb*a0o;
            float r1 = a1l - sa*a1l; r1 = r1 - sb*a1l; r1 = r1 + sa*e1; r1 = r1 + sb*a1o;
            v0r[k] = r0; v1r[k] = r1;
            nA0[l] = r0; nA1[l] = r1;
        }
        if (tid < 256) {
            const int l = 2048 + tid;
            int ln = l + doff; ln = ln < 0 ? 0 : (ln >= ATC ? ATC-1 : ln);
            int lo = l - doff; lo = lo < 0 ? 0 : (lo >= ATC ? ATC-1 : lo);
            float a0l = cA0[l], a1l = cA1[l];
            float a0n = cA0[ln];
            float a0o = cA0[lo], a1o = cA1[lo];
            unsigned kl = KSH[l], ko = KSH[lo];
            bool sal = ((kl & 15u) == tgt) & (a0n > 0.5f) & !(a1l > 0.5f);
            bool sao = ((ko & 15u) == tgt) & (a0l > 0.5f) & !(a1o > 0.5f);
            if (sal) MSH[l] |= (unsigned char)(1u << a);
            float sa = sal ? 1.0f : 0.0f;
            float sb = sao ? 1.0f : 0.0f;
            float r0 = a0l - sa*a0l; r0 = r0 - sb*a0l; r0 = r0 + sa*e0; r0 = r0 + sb*a0o;
            float r1 = a1l - sa*a1l; r1 = r1 - sb*a1l; r1 = r1 + sa*e1; r1 = r1 + sb*a1o;
            nA0[l] = r0; nA1[l] = r1;
        }
        __syncthreads();
    }
    // final ch0/ch1 in A0/A1

    // flush register M bits to LDS
    #pragma unroll
    for (int k = 0; k < 4; ++k) MSH[tid + (k << 9)] = (unsigned char)mreg[k];
    __syncthreads();

    // SB bits into KSH (bk dead)
    for (int l = tid; l < ATC; l += ANT) {
        unsigned sb8 = 0;
        #pragma unroll
        for (int a = 0; a < 8; ++a) {
            int lo = l - cDT[a]; lo = lo < 0 ? 0 : (lo >= ATC ? ATC-1 : lo);
            sb8 |= (unsigned)((MSH[lo] >> a) & 1) << a;
        }
        KSH[l] = (unsigned char)sb8;
    }
    __syncthreads();

    // interior: write ch0/ch1, M, SB, vdelta, provenance record
    for (int li = tid; li < 32*32; li += ANT) {
        int iy = li >> 5, ix = li & 31;
        int l = (iy + 8)*ATP + ix + 8;
        int gy = ty*32 + iy, gx = tx*32 + ix;
        int g = gy*WW + gx;
        outb[g]      = A0[l];
        outb[HW + g] = A1[l];
        unsigned mm = MSH[l], sbb = KSH[l];
        Mb[g]  = (unsigned char)mm;
        SBb[g] = (unsigned char)sbb;

        // vdelta (exact per-step order; vel fixed during iteration)
        float vy = velb[g], vx = velb[HW + g];
        float ddy = vy, ddx = vx;
        unsigned act = mm | sbb;
        if (act) {
            #pragma unroll
            for (int a = 0; a < 8; ++a) {
                if ((act >> a) & 1) {
                    float sa = (float)((mm  >> a) & 1);
                    float sb = (float)((sbb >> a) & 1);
                    float voy = 0.f, vox = 0.f;
                    if (sb != 0.f) {
                        int go = g - cDG[a];     // in-image when sb=1
                        voy = velb[go]; vox = velb[HW + go];
                    }
                    ddy = ddy - (sa*vy)*0.5f; ddy = ddy + (sb*voy)*0.5f;
                    ddx = ddx - (sa*vx)*0.5f; ddx = ddx + (sb*vox)*0.5f;
                }
            }
        }
        vdb[g]      = ddy;
        vdb[HW + g] = ddx;

        // provenance walk in LDS
        int cc = l, ss = 7, kd = 0;
        unsigned m = mm, sb = sbb;
        while (true) {
            unsigned evt = (m | sb) & ((2u << ss) - 1u);
            if (!evt) { kd = 0; break; }
            int bb = 31 - __builtin_clz(evt);
            int ia = (m >> bb) & 1, ib = (sb >> bb) & 1;
            if (ia && ib) { kd = 2; break; }        // tree at (cc, ss)
            if (ia) { kd = 1; break; }              // e=0 for c>=2 -> ZERO
            cc -= cDT[bb]; ss = bb - 1;             // sb-only: exact value move
            if (ss < 0) { kd = 0; break; }
            m = MSH[cc]; sb = KSH[cc];
        }
        unsigned rec;
        if (kd == 0) {
            int cly = cc / ATP, clx = cc - cly*ATP;
            rec = (unsigned)((y0 + cly)*WW + (x0 + clx));
        } else if (kd == 1) {
            rec = 1u << 30;
        } else {
            // build postfix program mirroring bv_eval's traversal exactly
            unsigned pbuf[48]; int n = 0; bool ok = true;
            int st_c[11], st_s[11], st_p[11]; int sp = 0;
            st_c[0] = cc; st_s[0] = ss; st_p[0] = 0; sp = 1;
            #define BV_EMIT(v) do { if (n < 46) pbuf[n++] = (v); else ok = false; } while (0)
            while (sp > 0 && ok) {
                int ph = st_p[sp-1];
                if (ph == 0) {
                    int c2 = st_c[sp-1], s2 = st_s[sp-1];
                    while (true) {
                        if (s2 < 0) {
                            int cly = c2 / ATP, clx = c2 - cly*ATP;
                            BV_EMIT((unsigned)((y0 + cly)*WW + (x0 + clx)));
                            sp--; break;
                        }
                        unsigned m2 = MSH[c2], k2 = KSH[c2];
                        unsigned ev2 = (m2 | k2) & ((2u << s2) - 1u);
                        if (!ev2) {
                            int cly = c2 / ATP, clx = c2 - cly*ATP;
                            BV_EMIT((unsigned)((y0 + cly)*WW + (x0 + clx)));
                            sp--; break;
                        }
                        int b3 = 31 - __builtin_clz(ev2);
                        int i2 = (m2 >> b3) & 1, j2 = (k2 >> b3) & 1;
                        if (i2 && j2) {
                            st_c[sp-1] = c2; st_s[sp-1] = b3; st_p[sp-1] = 1;
                            if (sp < 11) { st_c[sp] = c2 - cDT[b3]; st_s[sp] = b3 - 1; st_p[sp] = 0; sp++; }
                            else ok = false;
                            break;
                        }
                        if (i2) { BV_EMIT(1u << 30); sp--; break; }
                        c2 -= cDT[b3]; s2 = b3 - 1;
                    }
                } else if (ph == 1) {
                    st_p[sp-1] = 2;
                    if (sp < 11) { st_c[sp] = st_c[sp-1]; st_s[sp] = st_s[sp-1] - 1; st_p[sp] = 0; sp++; }
                    else ok = false;
                } else {
                    BV_EMIT(2u << 30);   // SUB
                    sp--;
                }
            }
            #undef BV_EMIT
            rec = 0;
            if (ok) {
                pbuf[n++] = 3u << 30;    // END
                unsigned base = atomicAdd(pcount, (unsigned)n);
                if (base + (unsigned)n <= progcap) {
                    for (int q = 0; q < n; ++q) prog[base + q] = pbuf[q];
                    rec = (2u << 30) | base;
                } else ok = false;
            }
            if (!ok) {
                int cly = cc / ATP, clx = cc - cly*ATP;
                unsigned gsrc = (unsigned)((y0 + cly)*WW + (x0 + clx));
                rec = (3u << 30) | ((unsigned)ss << 18) | gsrc;
            }
        }
        Srb[g] = (int)rec;
    }
}

// ---- fallback evaluator (global masks): only for program-buffer overflow.
__device__ __attribute__((noinline)) float bv_eval(
    int cell, int stp,
    const unsigned char* __restrict__ M,
    const unsigned char* __restrict__ SB,
    const float* __restrict__ initc)
{
    float vstk[10]; int vsp = 0;
    int cs_cell[10], cs_stp[10], cs_ph[10]; int csp = 0;
    cs_cell[0] = cell; cs_stp[0] = stp; cs_ph[0] = 0; csp = 1;
    while (csp > 0) {
        int ph = cs_ph[csp-1];
        if (ph == 0) {
            int cc = cs_cell[csp-1], ss = cs_stp[csp-1];
            float result = 0.0f; int have = 0;
            while (true) {
                if (ss < 0) { result = initc[cc]; have = 1; break; }
                unsigned m = M[cc], sb = SB[cc];
                unsigned evt = (m | sb) & ((2u << ss) - 1u);
                if (!evt) { result = initc[cc]; have = 1; break; }
                int bb = 31 - __builtin_clz(evt);
                int ia = (m >> bb) & 1, ib = (sb >> bb) & 1;
                if (ia && ib) {
                    cs_cell[csp-1] = cc; cs_stp[csp-1] = bb; cs_ph[csp-1] = 1;
                    cs_cell[csp] = cc - cDG[bb]; cs_stp[csp] = bb - 1; cs_ph[csp] = 0; csp++;
                    break;
                }
                if (ia) { result = 0.0f; have = 1; break; }
                cc -= cDG[bb]; ss = bb - 1;
            }
            if (have) { vstk[vsp++] = result; csp--; }
        } else if (ph == 1) {
            cs_ph[csp-1] = 2;
            cs_cell[csp] = cs_cell[csp-1]; cs_stp[csp] = cs_stp[csp-1] - 1;
            cs_ph[csp] = 0; csp++;
        } else {
            float Bv = vstk[--vsp]; float Av = vstk[--vsp];
            vstk[vsp++] = Av - Bv;
            csp--;
        }
    }
    return vstk[0];
}

// postfix replay: independent gathers, depth <= 10
__device__ inline float bv_replay(const unsigned* __restrict__ pr,
                                  const float* __restrict__ ic)
{
    float vst[11]; int vsp = 0;
    while (true) {
        unsigned w = *pr++;
        unsigned k = w >> 30;
        if (k == 0)      vst[vsp++] = ic[w & 0x3FFFFu];
        else if (k == 1) vst[vsp++] = 0.0f;
        else if (k == 2) { float Bv = vst[--vsp]; float Av = vst[--vsp]; vst[vsp++] = Av - Bv; }
        else break;
    }
    return vst[0];
}

// ---- Kernel B: apply precomputed provenance to 16 passive channels.
__global__ __launch_bounds__(256) void bv_apply_kernel(
    const float* __restrict__ Win, int Cin,
    float* __restrict__ Wout, int Cout,
    const int* __restrict__ Src,
    const unsigned* __restrict__ prog,
    const unsigned char* __restrict__ M,
    const unsigned char* __restrict__ SB)
{
    int t = blockIdx.x*256 + threadIdx.x;   // over BHW/4
    if (t >= BHW/4) return;
    int p = t << 2;
    int b = p >> 18;
    int own = p & (HW-1);
    const float* inb  = Win  + (size_t)b*Cin*HW;
    float*       outb = Wout + (size_t)b*Cout*HW;
    const unsigned char* Mb  = M  + ((size_t)b << 18);
    const unsigned char* SBb = SB + ((size_t)b << 18);
    const int* Srb = Src + ((size_t)b << 18);

    int4 s4 = *(const int4*)(Srb + own);
    unsigned sv[4] = {(unsigned)s4.x, (unsigned)s4.y, (unsigned)s4.z, (unsigned)s4.w};
    int kind[4], idx[4]; unsigned off[4]; int stp[4];
    #pragma unroll
    for (int j = 0; j < 4; ++j) {
        kind[j] = (int)(sv[j] >> 30);
        idx[j]  = (int)(sv[j] & 0x3FFFFu);
        off[j]  = sv[j] & 0x3FFFFFFFu;
        stp[j]  = (int)((sv[j] >> 18) & 7u);
    }

    bool fast = true;
    #pragma unroll
    for (int j = 0; j < 4; ++j) fast = fast && (kind[j] == 0) && (idx[j] == own + j);

    if (fast) {
        #pragma unroll
        for (int c = 2; c < NCH; ++c) {
            float4 v = *(const float4*)(inb + (size_t)c*HW + own);
            *(float4*)(outb + (size_t)c*HW + own) = v;
        }
        return;
    }
    #pragma unroll
    for (int c = 2; c < NCH; ++c) {
        const float* ic = inb + (size_t)c*HW;
        float r[4];
        #pragma unroll
        for (int j = 0; j < 4; ++j) {
            if (kind[j] == 0)      r[j] = ic[idx[j]];       // independent gather
            else if (kind[j] == 1) r[j] = 0.0f;
            else if (kind[j] == 2) r[j] = bv_replay(prog + off[j], ic);
            else                   r[j] = bv_eval(idx[j], stp[j], Mb, SBb, ic);
        }
        *(float4*)(outb + (size_t)c*HW + own) = make_float4(r[0], r[1], r[2], r[3]);
    }
}

// smooth(0.95*v): conv3x3(ones/18, zero-pad) + center*0.5 -> world ch18,19
__global__ __launch_bounds__(256) void bv_smooth_kernel(
    const float* __restrict__ vin, float* __restrict__ dout)
{
    int idx = blockIdx.x*256 + threadIdx.x;
    if (idx >= BATCH*2*HW) return;
    int x = idx & (WW-1);
    int y = (idx >> 9) & (HH-1);
    int c = (idx >> 18) & 1;
    int b = idx >> 19;
    const float* vb = vin + (size_t)(b*2 + c)*HW;
    const float w18 = (float)(1.0/18.0);
    float acc = 0.0f;
    for (int ky = -1; ky <= 1; ++ky) {
        int yy = y + ky;
        if ((unsigned)yy >= HH) continue;
        for (int kx = -1; kx <= 1; ++kx) {
            int xx2 = x + kx;
            if ((unsigned)xx2 >= WW) continue;
            float s = 0.95f * vb[yy*WW + xx2];
            acc += s * w18;
        }
    }
    float sc = 0.95f * vb[y*WW + x];
    float res = acc + sc * 0.5f;
    dout[((size_t)b*20 + 18 + c)*HW + (size_t)(y<<9) + x] = res;
}

__global__ __launch_bounds__(256) void bv_copyvel_kernel(float* __restrict__ dout)
{
    int idx = blockIdx.x*256 + threadIdx.x;
    if (idx >= BATCH*2*HW) return;
    int x = idx & (WW-1);
    int y = (idx >> 9) & (HH-1);
    int c = (idx >> 18) & 1;
    int b = idx >> 19;
    float v = dout[((size_t)b*20 + 18 + c)*HW + (size_t)(y<<9) + x];
    dout[(size_t)BATCH*20*HW + (size_t)idx] = v;
}

extern "C" void kernel_launch(void* const* d_in, const int* in_sizes, int n_in,
                              void* d_out, int out_size, void* d_ws, size_t ws_size,
                              hipStream_t stream)
{
    const float* world_in   = (const float*)d_in[0];
    const float* vel_in     = (const float*)d_in[1];
    const float* elem_empty = (const float*)d_in[2];
    float* out = (float*)d_out;

    // ws layout (~95.4 MB): worldA (18ch) | vd1 | bk | M | SB | Src | cnt | prog
    float* wsA = (float*)d_ws;                                 // 4*18*HW floats
    float* vd1 = wsA + (size_t)BATCH*NCH*HW;                   // 4*2*HW floats
    unsigned char* bk  = (unsigned char*)(vd1 + (size_t)BATCH*2*HW); // BHW
    unsigned char* Mb  = bk + (size_t)BHW;                     // BHW
    unsigned char* SBb = Mb + (size_t)BHW;                     // BHW
    int* Srcb = (int*)(SBb + (size_t)BHW);                     // BHW ints
    unsigned* pcount = (unsigned*)(Srcb + (size_t)BHW);        // 64 B slot
    unsigned* progb  = pcount + 16;
    size_t used = (size_t)((char*)progb - (char*)d_ws);
    unsigned progcap = 0;
    if (ws_size > used + 4096)
        progcap = (unsigned)((ws_size - used - 4096) / 4);
    if (progcap > (1u << 20)) progcap = 1u << 20;              // 4 MB cap
    float* vel2 = out + (size_t)BATCH*20*HW;                   // out tail

    dim3 blk(256);
    dim3 grd((BHW + 255)/256);
    dim3 g2((BATCH*2*HW + 255)/256);
    dim3 gA(BATCH*16*16);       // 1024 tile-blocks
    dim3 gB((BHW/4 + 255)/256); // 1024

    // ---- iteration 1 ----
    bv_bucket_kernel<<<grd, blk, 0, stream>>>(vel_in, bk, pcount);
    bv_mask_kernel<<<gA, dim3(ANT), 0, stream>>>(world_in, 20, wsA, NCH, bk,
                                                 vel_in, vd1, Mb, SBb, Srcb,
                                                 progb, pcount, progcap, elem_empty);
    bv_apply_kernel<<<gB, blk, 0, stream>>>(world_in, 20, wsA, NCH, Srcb, progb, Mb, SBb);
    // ---- iteration 2 ----
    bv_bucket_kernel<<<grd, blk, 0, stream>>>(vd1, bk, pcount);
    bv_mask_kernel<<<gA, dim3(ANT), 0, stream>>>(wsA, NCH, out, 20, bk,
                                                 vd1, vel2, Mb, SBb, Srcb,
                                                 progb, pcount, progcap, elem_empty);
    bv_apply_kernel<<<gB, blk, 0, stream>>>(wsA, NCH, out, 20, Srcb, progb, Mb, SBb);
    // ---- epilogue ----
    bv_smooth_kernel<<<g2, blk, 0, stream>>>(vel2, out);
    bv_copyvel_kernel<<<g2, blk, 0, stream>>>(out);
}

// Round 8
// 467.808 us; speedup vs baseline: 3.5954x; 1.2245x over previous
//
#include <hip/hip_runtime.h>
#include <math.h>

#define HH 512
#define WW 512
#define HW (HH*WW)          // 262144
#define BATCH 4
#define NCH 18              // simulated channels (18,19 overwritten at end)
#define BHW (BATCH*HW)

__device__ __constant__ int cDG[8] = {-512,-511,1,513,512,511,-1,-513}; // dy*WW+dx
__device__ __constant__ int cDT[8] = {-48,-47,1,49,48,47,-1,-49};       // dy*ATP+dx

// bucket (3 bits) | enough (bit 3); also zeroes the program counter
__global__ __launch_bounds__(256) void bv_bucket_kernel(
    const float* __restrict__ vel, unsigned char* __restrict__ bk,
    unsigned* __restrict__ pcount)
{
    int idx = blockIdx.x*256 + threadIdx.x;
    if (idx == 0) *pcount = 0;
    if (idx >= BHW) return;
    int b = idx >> 18;
    int rem = idx & (HW-1);
    const float* vb = vel + (size_t)b*2*HW;
    float vy = vb[rem];
    float vx = vb[HW + rem];
    float a2 = vy*vy;
    float b2 = vx*vx;
    float mag = sqrtf(a2 + b2);
    float xx = vx / (mag + 0.001f);
    float af = (float)acos((double)xx);
    const float inv2pi = (float)(1.0/(2.0*3.14159265358979323846));
    float raw = inv2pi * af;
    float ang = (vy < 0.0f) ? (1.0f - raw) : raw;
    float t = ang * 8.0f + 0.5f;
    int bkt = (int)floorf(t);
    bkt &= 7;
    unsigned char e = (mag > 0.1f) ? (unsigned char)8 : (unsigned char)0;
    bk[idx] = (unsigned char)(bkt | e);
}

// ---- Kernel A: evolve ch0/ch1 in LDS (32x32 tile + halo 8), fused
//      mask+evolve single pass per step; per-thread register carry.
//      Record: bits[31:30]=kind. 0=COPY gsrc; 1=ZERO; 2=PROG offset;
//      3=EVAL (ss<<18)|gsrc (overflow fallback).
#define ATP 48
#define ATC (48*48)   // 2304 = 4*512 + 256
#define ANT 512

__global__ __launch_bounds__(ANT) void bv_mask_kernel(
    const float* __restrict__ Win, int Cin,
    float* __restrict__ Wout, int Cout,
    const unsigned char* __restrict__ bkall,
    const float* __restrict__ vel,
    float* __restrict__ vdout,
    unsigned char* __restrict__ Mout,
    unsigned char* __restrict__ SBout,
    int* __restrict__ SrcOut,
    unsigned* __restrict__ prog,
    unsigned* __restrict__ pcount,
    unsigned progcap,
    const float* __restrict__ elem_empty)
{
    __shared__ float A0[ATC], A1[ATC], B0[ATC], B1[ATC];   // 36.9 KB
    __shared__ unsigned char MSH[ATC], KSH[ATC];           // 4.6 KB

    const int tid = threadIdx.x;
    const int blk = blockIdx.x;
    const int tx = blk & 15, ty = (blk >> 4) & 15, b = blk >> 8;
    const int x0 = tx*32 - 8, y0 = ty*32 - 8;

    const float* inb  = Win  + (size_t)b*Cin*HW;
    float*       outb = Wout + (size_t)b*Cout*HW;
    const unsigned char* bkb = bkall + ((size_t)b << 18);
    const float* velb = vel   + (size_t)b*2*HW;
    float*       vdb  = vdout + (size_t)b*2*HW;
    unsigned char* Mb  = Mout  + ((size_t)b << 18);
    unsigned char* SBb = SBout + ((size_t)b << 18);
    int*           Srb = SrcOut + ((size_t)b << 18);

    const float e0 = elem_empty[0];
    const float e1 = elem_empty[1];

    float v0r[4], v1r[4];
    unsigned kreg[4], mreg[4];

    // ---- load: LDS + register copies for owned cells ----
    #pragma unroll
    for (int k = 0; k < 4; ++k) {
        int l = tid + (k << 9);
        int ly = l / ATP, lx = l - ly*ATP;
        int gy = y0 + ly, gx = x0 + lx;
        bool in = ((unsigned)gy < HH) && ((unsigned)gx < WW);
        int g = gy*WW + gx;
        float v0 = 0.f, v1 = 0.f; unsigned char kk = 0;
        if (in) { v0 = inb[g]; v1 = inb[HW + g]; kk = bkb[g]; }
        A0[l] = v0; A1[l] = v1; KSH[l] = kk;
        v0r[k] = v0; v1r[k] = v1; kreg[k] = kk; mreg[k] = 0;
    }
    if (tid < 256) {    // tail cells: LDS-resident state
        int l = 2048 + tid;
        int ly = l / ATP, lx = l - ly*ATP;
        int gy = y0 + ly, gx = x0 + lx;
        bool in = ((unsigned)gy < HH) && ((unsigned)gx < WW);
        int g = gy*WW + gx;
        float v0 = 0.f, v1 = 0.f; unsigned char kk = 0;
        if (in) { v0 = inb[g]; v1 = inb[HW + g]; kk = bkb[g]; }
        A0[l] = v0; A1[l] = v1; KSH[l] = kk; MSH[l] = 0;
    }
    __syncthreads();

    // ---- 8 fused steps, one barrier each ----
    #pragma unroll
    for (int a = 0; a < 8; ++a) {
        const int doff = cDT[a];
        const unsigned tgt = (unsigned)(a | 8);
        const float* cA0 = (a & 1) ? B0 : A0;
        const float* cA1 = (a & 1) ? B1 : A1;
        float* nA0 = (a & 1) ? A0 : B0;
        float* nA1 = (a & 1) ? A1 : B1;
        #pragma unroll
        for (int k = 0; k < 4; ++k) {
            const int l = tid + (k << 9);
            int ln = l + doff; ln = ln < 0 ? 0 : (ln >= ATC ? ATC-1 : ln);
            int lo = l - doff; lo = lo < 0 ? 0 : (lo >= ATC ? ATC-1 : lo);
            float a0l = v0r[k], a1l = v1r[k];
            float a0n = cA0[ln];
            float a0o = cA0[lo], a1o = cA1[lo];
            unsigned ko = KSH[lo];
            bool sal = ((kreg[k] & 15u) == tgt) & (a0n > 0.5f) & !(a1l > 0.5f);
            bool sao = ((ko & 15u) == tgt) & (a0l > 0.5f) & !(a1o > 0.5f);
            mreg[k] |= (sal ? 1u : 0u) << a;
            float sa = sal ? 1.0f : 0.0f;
            float sb = sao ? 1.0f : 0.0f;
            float r0 = a0l - sa*a0l; r0 = r0 - sb*a0l; r0 = r0 + sa*e0; r0 = r0 + sb*a0o;
            float r1 = a1l - sa*a1l; r1 = r1 - sb*a1l; r1 = r1 + sa*e1; r1 = r1 + sb*a1o;
            v0r[k] = r0; v1r[k] = r1;
            nA0[l] = r0; nA1[l] = r1;
        }
        if (tid < 256) {
            const int l = 2048 + tid;
            int ln = l + doff; ln = ln < 0 ? 0 : (ln >= ATC ? ATC-1 : ln);
            int lo = l - doff; lo = lo < 0 ? 0 : (lo >= ATC ? ATC-1 : lo);
            float a0l = cA0[l], a1l = cA1[l];
            float a0n = cA0[ln];
            float a0o = cA0[lo], a1o = cA1[lo];
            unsigned kl = KSH[l], ko = KSH[lo];
            bool sal = ((kl & 15u) == tgt) & (a0n > 0.5f) & !(a1l > 0.5f);
            bool sao = ((ko & 15u) == tgt) & (a0l > 0.5f) & !(a1o > 0.5f);
            if (sal) MSH[l] |= (unsigned char)(1u << a);
            float sa = sal ? 1.0f : 0.0f;
            float sb = sao ? 1.0f : 0.0f;
            float r0 = a0l - sa*a0l; r0 = r0 - sb*a0l; r0 = r0 + sa*e0; r0 = r0 + sb*a0o;
            float r1 = a1l - sa*a1l; r1 = r1 - sb*a1l; r1 = r1 + sa*e1; r1 = r1 + sb*a1o;
            nA0[l] = r0; nA1[l] = r1;
        }
        __syncthreads();
    }
    // final ch0/ch1 in A0/A1

    // flush register M bits to LDS
    #pragma unroll
    for (int k = 0; k < 4; ++k) MSH[tid + (k << 9)] = (unsigned char)mreg[k];
    __syncthreads();

    // SB bits into KSH (bk dead)
    for (int l = tid; l < ATC; l += ANT) {
        unsigned sb8 = 0;
        #pragma unroll
        for (int a = 0; a < 8; ++a) {
            int lo = l - cDT[a]; lo = lo < 0 ? 0 : (lo >= ATC ? ATC-1 : lo);
            sb8 |= (unsigned)((MSH[lo] >> a) & 1) << a;
        }
        KSH[l] = (unsigned char)sb8;
    }
    __syncthreads();

    // interior: write ch0/ch1, M, SB, vdelta, provenance record
    for (int li = tid; li < 32*32; li += ANT) {
        int iy = li >> 5, ix = li & 31;
        int l = (iy + 8)*ATP + ix + 8;
        int gy = ty*32 + iy, gx = tx*32 + ix;
        int g = gy*WW + gx;
        outb[g]      = A0[l];
        outb[HW + g] = A1[l];
        unsigned mm = MSH[l], sbb = KSH[l];
        Mb[g]  = (unsigned char)mm;
        SBb[g] = (unsigned char)sbb;

        // vdelta (exact per-step order; vel fixed during iteration)
        float vy = velb[g], vx = velb[HW + g];
        float ddy = vy, ddx = vx;
        unsigned act = mm | sbb;
        if (act) {
            #pragma unroll
            for (int a = 0; a < 8; ++a) {
                if ((act >> a) & 1) {
                    float sa = (float)((mm  >> a) & 1);
                    float sb = (float)((sbb >> a) & 1);
                    float voy = 0.f, vox = 0.f;
                    if (sb != 0.f) {
                        int go = g - cDG[a];     // in-image when sb=1
                        voy = velb[go]; vox = velb[HW + go];
                    }
                    ddy = ddy - (sa*vy)*0.5f; ddy = ddy + (sb*voy)*0.5f;
                    ddx = ddx - (sa*vx)*0.5f; ddx = ddx + (sb*vox)*0.5f;
                }
            }
        }
        vdb[g]      = ddy;
        vdb[HW + g] = ddx;

        // provenance walk in LDS
        int cc = l, ss = 7, kd = 0;
        unsigned m = mm, sb = sbb;
        while (true) {
            unsigned evt = (m | sb) & ((2u << ss) - 1u);
            if (!evt) { kd = 0; break; }
            int bb = 31 - __builtin_clz(evt);
            int ia = (m >> bb) & 1, ib = (sb >> bb) & 1;
            if (ia && ib) { kd = 2; break; }        // tree at (cc, ss)
            if (ia) { kd = 1; break; }              // e=0 for c>=2 -> ZERO
            cc -= cDT[bb]; ss = bb - 1;             // sb-only: exact value move
            if (ss < 0) { kd = 0; break; }
            m = MSH[cc]; sb = KSH[cc];
        }
        unsigned rec;
        if (kd == 0) {
            int cly = cc / ATP, clx = cc - cly*ATP;
            rec = (unsigned)((y0 + cly)*WW + (x0 + clx));
        } else if (kd == 1) {
            rec = 1u << 30;
        } else {
            // build postfix program mirroring bv_eval's traversal exactly
            unsigned pbuf[48]; int n = 0; bool ok = true;
            int st_c[11], st_s[11], st_p[11]; int sp = 0;
            st_c[0] = cc; st_s[0] = ss; st_p[0] = 0; sp = 1;
            #define BV_EMIT(v) do { if (n < 46) pbuf[n++] = (v); else ok = false; } while (0)
            while (sp > 0 && ok) {
                int ph = st_p[sp-1];
                if (ph == 0) {
                    int c2 = st_c[sp-1], s2 = st_s[sp-1];
                    while (true) {
                        if (s2 < 0) {
                            int cly = c2 / ATP, clx = c2 - cly*ATP;
                            BV_EMIT((unsigned)((y0 + cly)*WW + (x0 + clx)));
                            sp--; break;
                        }
                        unsigned m2 = MSH[c2], k2 = KSH[c2];
                        unsigned ev2 = (m2 | k2) & ((2u << s2) - 1u);
                        if (!ev2) {
                            int cly = c2 / ATP, clx = c2 - cly*ATP;
                            BV_EMIT((unsigned)((y0 + cly)*WW + (x0 + clx)));
                            sp--; break;
                        }
                        int b3 = 31 - __builtin_clz(ev2);
                        int i2 = (m2 >> b3) & 1, j2 = (k2 >> b3) & 1;
                        if (i2 && j2) {
                            st_c[sp-1] = c2; st_s[sp-1] = b3; st_p[sp-1] = 1;
                            if (sp < 11) { st_c[sp] = c2 - cDT[b3]; st_s[sp] = b3 - 1; st_p[sp] = 0; sp++; }
                            else ok = false;
                            break;
                        }
                        if (i2) { BV_EMIT(1u << 30); sp--; break; }
                        c2 -= cDT[b3]; s2 = b3 - 1;
                    }
                } else if (ph == 1) {
                    st_p[sp-1] = 2;
                    if (sp < 11) { st_c[sp] = st_c[sp-1]; st_s[sp] = st_s[sp-1] - 1; st_p[sp] = 0; sp++; }
                    else ok = false;
                } else {
                    BV_EMIT(2u << 30);   // SUB
                    sp--;
                }
            }
            #undef BV_EMIT
            rec = 0;
            if (ok) {
                pbuf[n++] = 3u << 30;    // END
                unsigned base = atomicAdd(pcount, (unsigned)n);
                if (base + (unsigned)n <= progcap) {
                    for (int q = 0; q < n; ++q) prog[base + q] = pbuf[q];
                    rec = (2u << 30) | base;
                } else ok = false;
            }
            if (!ok) {
                int cly = cc / ATP, clx = cc - cly*ATP;
                unsigned gsrc = (unsigned)((y0 + cly)*WW + (x0 + clx));
                rec = (3u << 30) | ((unsigned)ss << 18) | gsrc;
            }
        }
        Srb[g] = (int)rec;
    }
}

// ---- fallback evaluator (global masks): only for program-buffer overflow.
__device__ __attribute__((noinline)) float bv_eval(
    int cell, int stp,
    const unsigned char* __restrict__ M,
    const unsigned char* __restrict__ SB,
    const float* __restrict__ initc)
{
    float vstk[10]; int vsp = 0;
    int cs_cell[10], cs_stp[10], cs_ph[10]; int csp = 0;
    cs_cell[0] = cell; cs_stp[0] = stp; cs_ph[0] = 0; csp = 1;
    while (csp > 0) {
        int ph = cs_ph[csp-1];
        if (ph == 0) {
            int cc = cs_cell[csp-1], ss = cs_stp[csp-1];
            float result = 0.0f; int have = 0;
            while (true) {
                if (ss < 0) { result = initc[cc]; have = 1; break; }
                unsigned m = M[cc], sb = SB[cc];
                unsigned evt = (m | sb) & ((2u << ss) - 1u);
                if (!evt) { result = initc[cc]; have = 1; break; }
                int bb = 31 - __builtin_clz(evt);
                int ia = (m >> bb) & 1, ib = (sb >> bb) & 1;
                if (ia && ib) {
                    cs_cell[csp-1] = cc; cs_stp[csp-1] = bb; cs_ph[csp-1] = 1;
                    cs_cell[csp] = cc - cDG[bb]; cs_stp[csp] = bb - 1; cs_ph[csp] = 0; csp++;
                    break;
                }
                if (ia) { result = 0.0f; have = 1; break; }
                cc -= cDG[bb]; ss = bb - 1;
            }
            if (have) { vstk[vsp++] = result; csp--; }
        } else if (ph == 1) {
            cs_ph[csp-1] = 2;
            cs_cell[csp] = cs_cell[csp-1]; cs_stp[csp] = cs_stp[csp-1] - 1;
            cs_ph[csp] = 0; csp++;
        } else {
            float Bv = vstk[--vsp]; float Av = vstk[--vsp];
            vstk[vsp++] = Av - Bv;
            csp--;
        }
    }
    return vstk[0];
}

// postfix replay: independent gathers, depth <= 10
__device__ inline float bv_replay(const unsigned* __restrict__ pr,
                                  const float* __restrict__ ic)
{
    float vst[11]; int vsp = 0;
    while (true) {
        unsigned w = *pr++;
        unsigned k = w >> 30;
        if (k == 0)      vst[vsp++] = ic[w & 0x3FFFFu];
        else if (k == 1) vst[vsp++] = 0.0f;
        else if (k == 2) { float Bv = vst[--vsp]; float Av = vst[--vsp]; vst[vsp++] = Av - Bv; }
        else break;
    }
    return vst[0];
}

// ---- Kernel B: apply precomputed provenance; channel-group parallel.
//      grid = (BHW/4/256, 4): blockIdx.y selects 4 channels -> 4x TLP.
__global__ __launch_bounds__(256) void bv_apply_kernel(
    const float* __restrict__ Win, int Cin,
    float* __restrict__ Wout, int Cout,
    const int* __restrict__ Src,
    const unsigned* __restrict__ prog,
    const unsigned char* __restrict__ M,
    const unsigned char* __restrict__ SB)
{
    int t = blockIdx.x*256 + threadIdx.x;   // over BHW/4
    if (t >= BHW/4) return;
    const int c0 = 2 + blockIdx.y*4;        // channel group [c0, c0+4)
    int p = t << 2;
    int b = p >> 18;
    int own = p & (HW-1);
    const float* inb  = Win  + (size_t)b*Cin*HW;
    float*       outb = Wout + (size_t)b*Cout*HW;
    const unsigned char* Mb  = M  + ((size_t)b << 18);
    const unsigned char* SBb = SB + ((size_t)b << 18);
    const int* Srb = Src + ((size_t)b << 18);

    int4 s4 = *(const int4*)(Srb + own);
    unsigned sv[4] = {(unsigned)s4.x, (unsigned)s4.y, (unsigned)s4.z, (unsigned)s4.w};
    int kind[4], idx[4]; unsigned off[4]; int stp[4];
    #pragma unroll
    for (int j = 0; j < 4; ++j) {
        kind[j] = (int)(sv[j] >> 30);
        idx[j]  = (int)(sv[j] & 0x3FFFFu);
        off[j]  = sv[j] & 0x3FFFFFFFu;
        stp[j]  = (int)((sv[j] >> 18) & 7u);
    }

    bool fast = true;
    #pragma unroll
    for (int j = 0; j < 4; ++j) fast = fast && (kind[j] == 0) && (idx[j] == own + j);

    if (fast) {
        #pragma unroll
        for (int c = 0; c < 4; ++c) {
            float4 v = *(const float4*)(inb + (size_t)(c0 + c)*HW + own);
            *(float4*)(outb + (size_t)(c0 + c)*HW + own) = v;
        }
        return;
    }
    #pragma unroll
    for (int c = 0; c < 4; ++c) {
        const float* ic = inb + (size_t)(c0 + c)*HW;
        float r[4];
        #pragma unroll
        for (int j = 0; j < 4; ++j) {
            if (kind[j] == 0)      r[j] = ic[idx[j]];       // independent gather
            else if (kind[j] == 1) r[j] = 0.0f;
            else if (kind[j] == 2) r[j] = bv_replay(prog + off[j], ic);
            else                   r[j] = bv_eval(idx[j], stp[j], Mb, SBb, ic);
        }
        *(float4*)(outb + (size_t)(c0 + c)*HW + own) = make_float4(r[0], r[1], r[2], r[3]);
    }
}

// smooth(0.95*v): conv3x3(ones/18, zero-pad) + center*0.5 -> world ch18,19
__global__ __launch_bounds__(256) void bv_smooth_kernel(
    const float* __restrict__ vin, float* __restrict__ dout)
{
    int idx = blockIdx.x*256 + threadIdx.x;
    if (idx >= BATCH*2*HW) return;
    int x = idx & (WW-1);
    int y = (idx >> 9) & (HH-1);
    int c = (idx >> 18) & 1;
    int b = idx >> 19;
    const float* vb = vin + (size_t)(b*2 + c)*HW;
    const float w18 = (float)(1.0/18.0);
    float acc = 0.0f;
    for (int ky = -1; ky <= 1; ++ky) {
        int yy = y + ky;
        if ((unsigned)yy >= HH) continue;
        for (int kx = -1; kx <= 1; ++kx) {
            int xx2 = x + kx;
            if ((unsigned)xx2 >= WW) continue;
            float s = 0.95f * vb[yy*WW + xx2];
            acc += s * w18;
        }
    }
    float sc = 0.95f * vb[y*WW + x];
    float res = acc + sc * 0.5f;
    dout[((size_t)b*20 + 18 + c)*HW + (size_t)(y<<9) + x] = res;
}

__global__ __launch_bounds__(256) void bv_copyvel_kernel(float* __restrict__ dout)
{
    int idx = blockIdx.x*256 + threadIdx.x;
    if (idx >= BATCH*2*HW) return;
    int x = idx & (WW-1);
    int y = (idx >> 9) & (HH-1);
    int c = (idx >> 18) & 1;
    int b = idx >> 19;
    float v = dout[((size_t)b*20 + 18 + c)*HW + (size_t)(y<<9) + x];
    dout[(size_t)BATCH*20*HW + (size_t)idx] = v;
}

extern "C" void kernel_launch(void* const* d_in, const int* in_sizes, int n_in,
                              void* d_out, int out_size, void* d_ws, size_t ws_size,
                              hipStream_t stream)
{
    const float* world_in   = (const float*)d_in[0];
    const float* vel_in     = (const float*)d_in[1];
    const float* elem_empty = (const float*)d_in[2];
    float* out = (float*)d_out;

    // ws layout (~95.4 MB): worldA (18ch) | vd1 | bk | M | SB | Src | cnt | prog
    float* wsA = (float*)d_ws;                                 // 4*18*HW floats
    float* vd1 = wsA + (size_t)BATCH*NCH*HW;                   // 4*2*HW floats
    unsigned char* bk  = (unsigned char*)(vd1 + (size_t)BATCH*2*HW); // BHW
    unsigned char* Mb  = bk + (size_t)BHW;                     // BHW
    unsigned char* SBb = Mb + (size_t)BHW;                     // BHW
    int* Srcb = (int*)(SBb + (size_t)BHW);                     // BHW ints
    unsigned* pcount = (unsigned*)(Srcb + (size_t)BHW);        // 64 B slot
    unsigned* progb  = pcount + 16;
    size_t used = (size_t)((char*)progb - (char*)d_ws);
    unsigned progcap = 0;
    if (ws_size > used + 4096)
        progcap = (unsigned)((ws_size - used - 4096) / 4);
    if (progcap > (1u << 20)) progcap = 1u << 20;              // 4 MB cap
    float* vel2 = out + (size_t)BATCH*20*HW;                   // out tail

    dim3 blk(256);
    dim3 grd((BHW + 255)/256);
    dim3 g2((BATCH*2*HW + 255)/256);
    dim3 gA(BATCH*16*16);            // 1024 tile-blocks
    dim3 gB(BHW/4/256, 4);           // 1024 x 4 channel-groups

    // ---- iteration 1 ----
    bv_bucket_kernel<<<grd, blk, 0, stream>>>(vel_in, bk, pcount);
    bv_mask_kernel<<<gA, dim3(ANT), 0, stream>>>(world_in, 20, wsA, NCH, bk,
                                                 vel_in, vd1, Mb, SBb, Srcb,
                                                 progb, pcount, progcap, elem_empty);
    bv_apply_kernel<<<gB, blk, 0, stream>>>(world_in, 20, wsA, NCH, Srcb, progb, Mb, SBb);
    // ---- iteration 2 ----
    bv_bucket_kernel<<<grd, blk, 0, stream>>>(vd1, bk, pcount);
    bv_mask_kernel<<<gA, dim3(ANT), 0, stream>>>(wsA, NCH, out, 20, bk,
                                                 vd1, vel2, Mb, SBb, Srcb,
                                                 progb, pcount, progcap, elem_empty);
    bv_apply_kernel<<<gB, blk, 0, stream>>>(wsA, NCH, out, 20, Srcb, progb, Mb, SBb);
    // ---- epilogue ----
    bv_smooth_kernel<<<g2, blk, 0, stream>>>(vel2, out);
    bv_copyvel_kernel<<<g2, blk, 0, stream>>>(out);
}

// Round 9
// 408.091 us; speedup vs baseline: 4.1216x; 1.1463x over previous
//
#include <hip/hip_runtime.h>
#include <math.h>

#define HH 512
#define WW 512
#define HW (HH*WW)          // 262144
#define BATCH 4
#define NCH 18              // simulated channels (18,19 overwritten at end)
#define BHW (BATCH*HW)

__device__ __constant__ int cDG[8] = {-512,-511,1,513,512,511,-1,-513}; // dy*WW+dx
__device__ __constant__ int cDT[8] = {-48,-47,1,49,48,47,-1,-49};       // dy*ATP+dx

// bucket (3 bits) | enough (bit 3); also zeroes the program counter
__global__ __launch_bounds__(256) void bv_bucket_kernel(
    const float* __restrict__ vel, unsigned char* __restrict__ bk,
    unsigned* __restrict__ pcount)
{
    int idx = blockIdx.x*256 + threadIdx.x;
    if (idx == 0) *pcount = 0;
    if (idx >= BHW) return;
    int b = idx >> 18;
    int rem = idx & (HW-1);
    const float* vb = vel + (size_t)b*2*HW;
    float vy = vb[rem];
    float vx = vb[HW + rem];
    float a2 = vy*vy;
    float b2 = vx*vx;
    float mag = sqrtf(a2 + b2);
    float xx = vx / (mag + 0.001f);
    float af = (float)acos((double)xx);
    const float inv2pi = (float)(1.0/(2.0*3.14159265358979323846));
    float raw = inv2pi * af;
    float ang = (vy < 0.0f) ? (1.0f - raw) : raw;
    float t = ang * 8.0f + 0.5f;
    int bkt = (int)floorf(t);
    bkt &= 7;
    unsigned char e = (mag > 0.1f) ? (unsigned char)8 : (unsigned char)0;
    bk[idx] = (unsigned char)(bkt | e);
}

#define ATP 48
#define ATC (48*48)   // 2304 = 4*512 + 256
#define ANT 512

// postfix-program builder; dst==nullptr -> count only. Returns word count
// (incl END) or -1 on depth/length overflow. Mirrors the walk semantics.
__device__ int bv_build(int cc, int ss,
                        const unsigned char* __restrict__ MSHb,
                        const unsigned char* __restrict__ SBb,
                        int y0, int x0, unsigned* __restrict__ dst)
{
    int n = 0; bool ok = true;
    int st_c[11], st_s[11], st_p[11]; int sp = 0;
    st_c[0] = cc; st_s[0] = ss; st_p[0] = 0; sp = 1;
    #define BV_EMIT(v) do { if (n < 47) { if (dst) dst[n] = (v); n++; } else ok = false; } while (0)
    while (sp > 0 && ok) {
        int ph = st_p[sp-1];
        if (ph == 0) {
            int c2 = st_c[sp-1], s2 = st_s[sp-1];
            while (true) {
                if (s2 < 0) {
                    int cly = c2 / ATP, clx = c2 - cly*ATP;
                    BV_EMIT((unsigned)((y0 + cly)*WW + (x0 + clx)));
                    sp--; break;
                }
                unsigned m2 = MSHb[c2], k2 = SBb[c2];
                unsigned ev2 = (m2 | k2) & ((2u << s2) - 1u);
                if (!ev2) {
                    int cly = c2 / ATP, clx = c2 - cly*ATP;
                    BV_EMIT((unsigned)((y0 + cly)*WW + (x0 + clx)));
                    sp--; break;
                }
                int b3 = 31 - __builtin_clz(ev2);
                int i2 = (m2 >> b3) & 1, j2 = (k2 >> b3) & 1;
                if (i2 && j2) {
                    st_c[sp-1] = c2; st_s[sp-1] = b3; st_p[sp-1] = 1;
                    if (sp < 11) { st_c[sp] = c2 - cDT[b3]; st_s[sp] = b3 - 1; st_p[sp] = 0; sp++; }
                    else ok = false;
                    break;
                }
                if (i2) { BV_EMIT(1u << 30); sp--; break; }
                c2 -= cDT[b3]; s2 = b3 - 1;
            }
        } else if (ph == 1) {
            st_p[sp-1] = 2;
            if (sp < 11) { st_c[sp] = st_c[sp-1]; st_s[sp] = st_s[sp-1] - 1; st_p[sp] = 0; sp++; }
            else ok = false;
        } else {
            BV_EMIT(2u << 30);   // SUB
            sp--;
        }
    }
    if (!ok) return -1;
    BV_EMIT(3u << 30);           // END
    #undef BV_EMIT
    return ok ? n : -1;
}

// ---- Kernel A: fused mask+evolve (as R7) + block-aggregated program
//      allocation (1 global atomic/block) + LDS 38.3 KB (4 blocks/CU):
//      tail-M in register; M/SB byte arrays alias dead B0 after step 8.
__global__ __launch_bounds__(ANT) void bv_mask_kernel(
    const float* __restrict__ Win, int Cin,
    float* __restrict__ Wout, int Cout,
    const unsigned char* __restrict__ bkall,
    const float* __restrict__ vel,
    float* __restrict__ vdout,
    unsigned char* __restrict__ Mg,
    unsigned char* __restrict__ SBg,
    int* __restrict__ SrcOut,
    unsigned* __restrict__ prog,
    unsigned* __restrict__ pcount,
    unsigned progcap,
    const float* __restrict__ elem_empty)
{
    __shared__ float A0[ATC], A1[ATC], B0F[ATC], B1F[ATC];   // 36.9 KB
    __shared__ unsigned char KSH[ATC];                       // 2.3 KB
    __shared__ unsigned sCnt[2];                             // [0]=len sum, [1]=base

    unsigned char* MSHb = (unsigned char*)B0F;               // post-steps M bytes
    unsigned char* SBb  = ((unsigned char*)B0F) + ATC;       // post-steps SB bytes

    const int tid = threadIdx.x;
    const int blk = blockIdx.x;
    const int tx = blk & 15, ty = (blk >> 4) & 15, b = blk >> 8;
    const int x0 = tx*32 - 8, y0 = ty*32 - 8;

    const float* inb  = Win  + (size_t)b*Cin*HW;
    float*       outb = Wout + (size_t)b*Cout*HW;
    const unsigned char* bkb = bkall + ((size_t)b << 18);
    const float* velb = vel   + (size_t)b*2*HW;
    float*       vdb  = vdout + (size_t)b*2*HW;
    unsigned char* Mob  = Mg  + ((size_t)b << 18);
    unsigned char* SBob = SBg + ((size_t)b << 18);
    int*           Srb  = SrcOut + ((size_t)b << 18);

    const float e0 = elem_empty[0];
    const float e1 = elem_empty[1];

    float v0r[4], v1r[4];
    unsigned kreg[4], mreg[4];
    unsigned mtail = 0;

    if (tid == 0) sCnt[0] = 0;

    // ---- load: LDS + register copies for owned cells ----
    #pragma unroll
    for (int k = 0; k < 4; ++k) {
        int l = tid + (k << 9);
        int ly = l / ATP, lx = l - ly*ATP;
        int gy = y0 + ly, gx = x0 + lx;
        bool in = ((unsigned)gy < HH) && ((unsigned)gx < WW);
        int g = gy*WW + gx;
        float v0 = 0.f, v1 = 0.f; unsigned char kk = 0;
        if (in) { v0 = inb[g]; v1 = inb[HW + g]; kk = bkb[g]; }
        A0[l] = v0; A1[l] = v1; KSH[l] = kk;
        v0r[k] = v0; v1r[k] = v1; kreg[k] = kk; mreg[k] = 0;
    }
    if (tid < 256) {    // tail cells: LDS-resident values, register M
        int l = 2048 + tid;
        int ly = l / ATP, lx = l - ly*ATP;
        int gy = y0 + ly, gx = x0 + lx;
        bool in = ((unsigned)gy < HH) && ((unsigned)gx < WW);
        int g = gy*WW + gx;
        float v0 = 0.f, v1 = 0.f; unsigned char kk = 0;
        if (in) { v0 = inb[g]; v1 = inb[HW + g]; kk = bkb[g]; }
        A0[l] = v0; A1[l] = v1; KSH[l] = kk;
    }
    __syncthreads();

    // ---- 8 fused steps, one barrier each ----
    #pragma unroll
    for (int a = 0; a < 8; ++a) {
        const int doff = cDT[a];
        const unsigned tgt = (unsigned)(a | 8);
        const float* cA0 = (a & 1) ? B0F : A0;
        const float* cA1 = (a & 1) ? B1F : A1;
        float* nA0 = (a & 1) ? A0 : B0F;
        float* nA1 = (a & 1) ? A1 : B1F;
        #pragma unroll
        for (int k = 0; k < 4; ++k) {
            const int l = tid + (k << 9);
            int ln = l + doff; ln = ln < 0 ? 0 : (ln >= ATC ? ATC-1 : ln);
            int lo = l - doff; lo = lo < 0 ? 0 : (lo >= ATC ? ATC-1 : lo);
            float a0l = v0r[k], a1l = v1r[k];
            float a0n = cA0[ln];
            float a0o = cA0[lo], a1o = cA1[lo];
            unsigned ko = KSH[lo];
            bool sal = ((kreg[k] & 15u) == tgt) & (a0n > 0.5f) & !(a1l > 0.5f);
            bool sao = ((ko & 15u) == tgt) & (a0l > 0.5f) & !(a1o > 0.5f);
            mreg[k] |= (sal ? 1u : 0u) << a;
            float sa = sal ? 1.0f : 0.0f;
            float sb = sao ? 1.0f : 0.0f;
            float r0 = a0l - sa*a0l; r0 = r0 - sb*a0l; r0 = r0 + sa*e0; r0 = r0 + sb*a0o;
            float r1 = a1l - sa*a1l; r1 = r1 - sb*a1l; r1 = r1 + sa*e1; r1 = r1 + sb*a1o;
            v0r[k] = r0; v1r[k] = r1;
            nA0[l] = r0; nA1[l] = r1;
        }
        if (tid < 256) {
            const int l = 2048 + tid;
            int ln = l + doff; ln = ln < 0 ? 0 : (ln >= ATC ? ATC-1 : ln);
            int lo = l - doff; lo = lo < 0 ? 0 : (lo >= ATC ? ATC-1 : lo);
            float a0l = cA0[l], a1l = cA1[l];
            float a0n = cA0[ln];
            float a0o = cA0[lo], a1o = cA1[lo];
            unsigned kl = KSH[l], ko = KSH[lo];
            bool sal = ((kl & 15u) == tgt) & (a0n > 0.5f) & !(a1l > 0.5f);
            bool sao = ((ko & 15u) == tgt) & (a0l > 0.5f) & !(a1o > 0.5f);
            if (sal) mtail |= 1u << a;
            float sa = sal ? 1.0f : 0.0f;
            float sb = sao ? 1.0f : 0.0f;
            float r0 = a0l - sa*a0l; r0 = r0 - sb*a0l; r0 = r0 + sa*e0; r0 = r0 + sb*a0o;
            float r1 = a1l - sa*a1l; r1 = r1 - sb*a1l; r1 = r1 + sa*e1; r1 = r1 + sb*a1o;
            nA0[l] = r0; nA1[l] = r1;
        }
        __syncthreads();
    }
    // final ch0/ch1 in A0/A1; B0F/B1F dead -> alias as M/SB byte arrays

    #pragma unroll
    for (int k = 0; k < 4; ++k) MSHb[tid + (k << 9)] = (unsigned char)mreg[k];
    if (tid < 256) MSHb[2048 + tid] = (unsigned char)mtail;
    __syncthreads();

    // SB bits
    for (int l = tid; l < ATC; l += ANT) {
        unsigned sb8 = 0;
        #pragma unroll
        for (int a = 0; a < 8; ++a) {
            int lo = l - cDT[a]; lo = lo < 0 ? 0 : (lo >= ATC ? ATC-1 : lo);
            sb8 |= (unsigned)((MSHb[lo] >> a) & 1) << a;
        }
        SBb[l] = (unsigned char)sb8;
    }
    __syncthreads();

    // ---- pass A: interior writes, vdelta, walk; trees reserve LDS space ----
    int tKind[2]; unsigned tLoc[2], tN[2]; int tCc[2], tSs[2];
    #pragma unroll
    for (int it = 0; it < 2; ++it) {
        tKind[it] = 0;
        int li = tid + (it << 9);
        int iy = li >> 5, ix = li & 31;
        int l = (iy + 8)*ATP + ix + 8;
        int gy = ty*32 + iy, gx = tx*32 + ix;
        int g = gy*WW + gx;
        outb[g]      = A0[l];
        outb[HW + g] = A1[l];
        unsigned mm = MSHb[l], sbb = SBb[l];
        Mob[g]  = (unsigned char)mm;
        SBob[g] = (unsigned char)sbb;

        // vdelta (exact per-step order; vel fixed during iteration)
        float vy = velb[g], vx = velb[HW + g];
        float ddy = vy, ddx = vx;
        unsigned act = mm | sbb;
        if (act) {
            #pragma unroll
            for (int a = 0; a < 8; ++a) {
                if ((act >> a) & 1) {
                    float sa = (float)((mm  >> a) & 1);
                    float sb = (float)((sbb >> a) & 1);
                    float voy = 0.f, vox = 0.f;
                    if (sb != 0.f) {
                        int go = g - cDG[a];     // in-image when sb=1
                        voy = velb[go]; vox = velb[HW + go];
                    }
                    ddy = ddy - (sa*vy)*0.5f; ddy = ddy + (sb*voy)*0.5f;
                    ddx = ddx - (sa*vx)*0.5f; ddx = ddx + (sb*vox)*0.5f;
                }
            }
        }
        vdb[g]      = ddy;
        vdb[HW + g] = ddx;

        // provenance walk in LDS
        int cc = l, ss = 7, kd = 0;
        unsigned m = mm, sb = sbb;
        while (true) {
            unsigned evt = (m | sb) & ((2u << ss) - 1u);
            if (!evt) { kd = 0; break; }
            int bb = 31 - __builtin_clz(evt);
            int ia = (m >> bb) & 1, ib = (sb >> bb) & 1;
            if (ia && ib) { kd = 2; break; }        // tree at (cc, ss)
            if (ia) { kd = 1; break; }              // e=0 for c>=2 -> ZERO
            cc -= cDT[bb]; ss = bb - 1;             // sb-only: exact value move
            if (ss < 0) { kd = 0; break; }
            m = MSHb[cc]; sb = SBb[cc];
        }
        if (kd == 0) {
            int cly = cc / ATP, clx = cc - cly*ATP;
            Srb[g] = (int)(unsigned)((y0 + cly)*WW + (x0 + clx));
        } else if (kd == 1) {
            Srb[g] = (int)(1u << 30);
        } else {
            int n = bv_build(cc, ss, MSHb, SBb, y0, x0, (unsigned*)0);
            if (n < 0) {
                int cly = cc / ATP, clx = cc - cly*ATP;
                unsigned gsrc = (unsigned)((y0 + cly)*WW + (x0 + clx));
                Srb[g] = (int)((3u << 30) | ((unsigned)ss << 18) | gsrc);
            } else {
                tKind[it] = 2; tCc[it] = cc; tSs[it] = ss; tN[it] = (unsigned)n;
                tLoc[it] = atomicAdd(&sCnt[0], (unsigned)n);   // fast LDS atomic
            }
        }
    }
    __syncthreads();
    if (tid == 0) sCnt[1] = sCnt[0] ? atomicAdd(pcount, sCnt[0]) : 0u;
    __syncthreads();
    unsigned gbase = sCnt[1];

    // ---- pass B: emit tree programs at reserved offsets ----
    #pragma unroll
    for (int it = 0; it < 2; ++it) {
        if (tKind[it] != 2) continue;
        int li = tid + (it << 9);
        int iy = li >> 5, ix = li & 31;
        int g = (ty*32 + iy)*WW + tx*32 + ix;
        unsigned o = gbase + tLoc[it];
        if ((unsigned long long)o + tN[it] <= (unsigned long long)progcap) {
            bv_build(tCc[it], tSs[it], MSHb, SBb, y0, x0, prog + o);
            Srb[g] = (int)((2u << 30) | o);
        } else {
            int cly = tCc[it] / ATP, clx = tCc[it] - cly*ATP;
            unsigned gsrc = (unsigned)((y0 + cly)*WW + (x0 + clx));
            Srb[g] = (int)((3u << 30) | ((unsigned)tSs[it] << 18) | gsrc);
        }
    }
}

// ---- fallback evaluator (global masks): only for program overflow.
__device__ __attribute__((noinline)) float bv_eval(
    int cell, int stp,
    const unsigned char* __restrict__ M,
    const unsigned char* __restrict__ SB,
    const float* __restrict__ initc)
{
    float vstk[10]; int vsp = 0;
    int cs_cell[10], cs_stp[10], cs_ph[10]; int csp = 0;
    cs_cell[0] = cell; cs_stp[0] = stp; cs_ph[0] = 0; csp = 1;
    while (csp > 0) {
        int ph = cs_ph[csp-1];
        if (ph == 0) {
            int cc = cs_cell[csp-1], ss = cs_stp[csp-1];
            float result = 0.0f; int have = 0;
            while (true) {
                if (ss < 0) { result = initc[cc]; have = 1; break; }
                unsigned m = M[cc], sb = SB[cc];
                unsigned evt = (m | sb) & ((2u << ss) - 1u);
                if (!evt) { result = initc[cc]; have = 1; break; }
                int bb = 31 - __builtin_clz(evt);
                int ia = (m >> bb) & 1, ib = (sb >> bb) & 1;
                if (ia && ib) {
                    cs_cell[csp-1] = cc; cs_stp[csp-1] = bb; cs_ph[csp-1] = 1;
                    cs_cell[csp] = cc - cDG[bb]; cs_stp[csp] = bb - 1; cs_ph[csp] = 0; csp++;
                    break;
                }
                if (ia) { result = 0.0f; have = 1; break; }
                cc -= cDG[bb]; ss = bb - 1;
            }
            if (have) { vstk[vsp++] = result; csp--; }
        } else if (ph == 1) {
            cs_ph[csp-1] = 2;
            cs_cell[csp] = cs_cell[csp-1]; cs_stp[csp] = cs_stp[csp-1] - 1;
            cs_ph[csp] = 0; csp++;
        } else {
            float Bv = vstk[--vsp]; float Av = vstk[--vsp];
            vstk[vsp++] = Av - Bv;
            csp--;
        }
    }
    return vstk[0];
}

// postfix replay: independent gathers, depth <= 10
__device__ inline float bv_replay(const unsigned* __restrict__ pr,
                                  const float* __restrict__ ic)
{
    float vst[11]; int vsp = 0;
    while (true) {
        unsigned w = *pr++;
        unsigned k = w >> 30;
        if (k == 0)      vst[vsp++] = ic[w & 0x3FFFFu];
        else if (k == 1) vst[vsp++] = 0.0f;
        else if (k == 2) { float Bv = vst[--vsp]; float Av = vst[--vsp]; vst[vsp++] = Av - Bv; }
        else break;
    }
    return vst[0];
}

// ---- Kernel B: apply precomputed provenance; channel-group parallel.
__global__ __launch_bounds__(256) void bv_apply_kernel(
    const float* __restrict__ Win, int Cin,
    float* __restrict__ Wout, int Cout,
    const int* __restrict__ Src,
    const unsigned* __restrict__ prog,
    const unsigned char* __restrict__ M,
    const unsigned char* __restrict__ SB)
{
    int t = blockIdx.x*256 + threadIdx.x;   // over BHW/4
    if (t >= BHW/4) return;
    const int c0 = 2 + blockIdx.y*4;        // channel group [c0, c0+4)
    int p = t << 2;
    int b = p >> 18;
    int own = p & (HW-1);
    const float* inb  = Win  + (size_t)b*Cin*HW;
    float*       outb = Wout + (size_t)b*Cout*HW;
    const unsigned char* Mb  = M  + ((size_t)b << 18);
    const unsigned char* SBb = SB + ((size_t)b << 18);
    const int* Srb = Src + ((size_t)b << 18);

    int4 s4 = *(const int4*)(Srb + own);
    unsigned sv[4] = {(unsigned)s4.x, (unsigned)s4.y, (unsigned)s4.z, (unsigned)s4.w};
    int kind[4], idx[4]; unsigned off[4]; int stp[4];
    #pragma unroll
    for (int j = 0; j < 4; ++j) {
        kind[j] = (int)(sv[j] >> 30);
        idx[j]  = (int)(sv[j] & 0x3FFFFu);
        off[j]  = sv[j] & 0x3FFFFFFFu;
        stp[j]  = (int)((sv[j] >> 18) & 7u);
    }

    bool fast = true;
    #pragma unroll
    for (int j = 0; j < 4; ++j) fast = fast && (kind[j] == 0) && (idx[j] == own + j);

    if (fast) {
        #pragma unroll
        for (int c = 0; c < 4; ++c) {
            float4 v = *(const float4*)(inb + (size_t)(c0 + c)*HW + own);
            *(float4*)(outb + (size_t)(c0 + c)*HW + own) = v;
        }
        return;
    }
    #pragma unroll
    for (int c = 0; c < 4; ++c) {
        const float* ic = inb + (size_t)(c0 + c)*HW;
        float r[4];
        #pragma unroll
        for (int j = 0; j < 4; ++j) {
            if (kind[j] == 0)      r[j] = ic[idx[j]];
            else if (kind[j] == 1) r[j] = 0.0f;
            else if (kind[j] == 2) r[j] = bv_replay(prog + off[j], ic);
            else                   r[j] = bv_eval(idx[j], stp[j], Mb, SBb, ic);
        }
        *(float4*)(outb + (size_t)(c0 + c)*HW + own) = make_float4(r[0], r[1], r[2], r[3]);
    }
}

// smooth(0.95*v): conv3x3(ones/18, zero-pad) + center*0.5 -> world ch18,19
__global__ __launch_bounds__(256) void bv_smooth_kernel(
    const float* __restrict__ vin, float* __restrict__ dout)
{
    int idx = blockIdx.x*256 + threadIdx.x;
    if (idx >= BATCH*2*HW) return;
    int x = idx & (WW-1);
    int y = (idx >> 9) & (HH-1);
    int c = (idx >> 18) & 1;
    int b = idx >> 19;
    const float* vb = vin + (size_t)(b*2 + c)*HW;
    const float w18 = (float)(1.0/18.0);
    float acc = 0.0f;
    for (int ky = -1; ky <= 1; ++ky) {
        int yy = y + ky;
        if ((unsigned)yy >= HH) continue;
        for (int kx = -1; kx <= 1; ++kx) {
            int xx2 = x + kx;
            if ((unsigned)xx2 >= WW) continue;
            float s = 0.95f * vb[yy*WW + xx2];
            acc += s * w18;
        }
    }
    float sc = 0.95f * vb[y*WW + x];
    float res = acc + sc * 0.5f;
    dout[((size_t)b*20 + 18 + c)*HW + (size_t)(y<<9) + x] = res;
}

__global__ __launch_bounds__(256) void bv_copyvel_kernel(float* __restrict__ dout)
{
    int idx = blockIdx.x*256 + threadIdx.x;
    if (idx >= BATCH*2*HW) return;
    int x = idx & (WW-1);
    int y = (idx >> 9) & (HH-1);
    int c = (idx >> 18) & 1;
    int b = idx >> 19;
    float v = dout[((size_t)b*20 + 18 + c)*HW + (size_t)(y<<9) + x];
    dout[(size_t)BATCH*20*HW + (size_t)idx] = v;
}

extern "C" void kernel_launch(void* const* d_in, const int* in_sizes, int n_in,
                              void* d_out, int out_size, void* d_ws, size_t ws_size,
                              hipStream_t stream)
{
    const float* world_in   = (const float*)d_in[0];
    const float* vel_in     = (const float*)d_in[1];
    const float* elem_empty = (const float*)d_in[2];
    float* out = (float*)d_out;

    // ws layout (~95.4 MB): worldA (18ch) | vd1 | bk | M | SB | Src | cnt | prog
    float* wsA = (float*)d_ws;                                 // 4*18*HW floats
    float* vd1 = wsA + (size_t)BATCH*NCH*HW;                   // 4*2*HW floats
    unsigned char* bk  = (unsigned char*)(vd1 + (size_t)BATCH*2*HW); // BHW
    unsigned char* Mb  = bk + (size_t)BHW;                     // BHW
    unsigned char* SBb = Mb + (size_t)BHW;                     // BHW
    int* Srcb = (int*)(SBb + (size_t)BHW);                     // BHW ints
    unsigned* pcount = (unsigned*)(Srcb + (size_t)BHW);        // 64 B slot
    unsigned* progb  = pcount + 16;
    size_t used = (size_t)((char*)progb - (char*)d_ws);
    unsigned progcap = 0;
    if (ws_size > used + 4096)
        progcap = (unsigned)((ws_size - used - 4096) / 4);
    if (progcap > (1u << 20)) progcap = 1u << 20;              // 4 MB cap
    float* vel2 = out + (size_t)BATCH*20*HW;                   // out tail

    dim3 blk(256);
    dim3 grd((BHW + 255)/256);
    dim3 g2((BATCH*2*HW + 255)/256);
    dim3 gA(BATCH*16*16);            // 1024 tile-blocks
    dim3 gB(BHW/4/256, 4);           // 1024 x 4 channel-groups

    // ---- iteration 1 ----
    bv_bucket_kernel<<<grd, blk, 0, stream>>>(vel_in, bk, pcount);
    bv_mask_kernel<<<gA, dim3(ANT), 0, stream>>>(world_in, 20, wsA, NCH, bk,
                                                 vel_in, vd1, Mb, SBb, Srcb,
                                                 progb, pcount, progcap, elem_empty);
    bv_apply_kernel<<<gB, blk, 0, stream>>>(world_in, 20, wsA, NCH, Srcb, progb, Mb, SBb);
    // ---- iteration 2 ----
    bv_bucket_kernel<<<grd, blk, 0, stream>>>(vd1, bk, pcount);
    bv_mask_kernel<<<gA, dim3(ANT), 0, stream>>>(wsA, NCH, out, 20, bk,
                                                 vd1, vel2, Mb, SBb, Srcb,
                                                 progb, pcount, progcap, elem_empty);
    bv_apply_kernel<<<gB, blk, 0, stream>>>(wsA, NCH, out, 20, Srcb, progb, Mb, SBb);
    // ---- epilogue ----
    bv_smooth_kernel<<<g2, blk, 0, stream>>>(vel2, out);
    bv_copyvel_kernel<<<g2, blk, 0, stream>>>(out);
}

// Round 11
// 364.364 us; speedup vs baseline: 4.6162x; 1.1200x over previous
//
#include <hip/hip_runtime.h>
#include <math.h>

#define HH 512
#define WW 512
#define HW (HH*WW)          // 262144
#define BATCH 4
#define NCH 18              // simulated channels (18,19 overwritten at end)
#define BHW (BATCH*HW)

__device__ __constant__ int cDG[8] = {-512,-511,1,513,512,511,-1,-513}; // dy*WW+dx
__device__ __constant__ int cDT[8] = {-48,-47,1,49,48,47,-1,-49};       // dy*ATP+dx

// bucket (3 bits) | enough (bit 3); zeroes prog-word and tree-list counters
__global__ __launch_bounds__(256) void bv_bucket_kernel(
    const float* __restrict__ vel, unsigned char* __restrict__ bk,
    unsigned* __restrict__ pcount)
{
    int idx = blockIdx.x*256 + threadIdx.x;
    if (idx == 0) { pcount[0] = 0; pcount[1] = 0; }
    if (idx >= BHW) return;
    int b = idx >> 18;
    int rem = idx & (HW-1);
    const float* vb = vel + (size_t)b*2*HW;
    float vy = vb[rem];
    float vx = vb[HW + rem];
    float a2 = vy*vy;
    float b2 = vx*vx;
    float mag = sqrtf(a2 + b2);
    float xx = vx / (mag + 0.001f);
    float af = (float)acos((double)xx);
    const float inv2pi = (float)(1.0/(2.0*3.14159265358979323846));
    float raw = inv2pi * af;
    float ang = (vy < 0.0f) ? (1.0f - raw) : raw;
    float t = ang * 8.0f + 0.5f;
    int bkt = (int)floorf(t);
    bkt &= 7;
    unsigned char e = (mag > 0.1f) ? (unsigned char)8 : (unsigned char)0;
    bk[idx] = (unsigned char)(bkt | e);
}

#define ATP 48
#define ATC (48*48)   // 2304 = 4*512 + 256
#define ANT 512

// postfix-program builder; dst==nullptr -> count only. Returns word count
// (incl END) or -1 on depth/length overflow. Mirrors the walk semantics.
__device__ int bv_build(int cc, int ss,
                        const unsigned char* __restrict__ MSHb,
                        const unsigned char* __restrict__ SBb,
                        int y0, int x0, unsigned* __restrict__ dst)
{
    int n = 0; bool ok = true;
    int st_c[11], st_s[11], st_p[11]; int sp = 0;
    st_c[0] = cc; st_s[0] = ss; st_p[0] = 0; sp = 1;
    #define BV_EMIT(v) do { if (n < 47) { if (dst) dst[n] = (v); n++; } else ok = false; } while (0)
    while (sp > 0 && ok) {
        int ph = st_p[sp-1];
        if (ph == 0) {
            int c2 = st_c[sp-1], s2 = st_s[sp-1];
            while (true) {
                if (s2 < 0) {
                    int cly = c2 / ATP, clx = c2 - cly*ATP;
                    BV_EMIT((unsigned)((y0 + cly)*WW + (x0 + clx)));
                    sp--; break;
                }
                unsigned m2 = MSHb[c2], k2 = SBb[c2];
                unsigned ev2 = (m2 | k2) & ((2u << s2) - 1u);
                if (!ev2) {
                    int cly = c2 / ATP, clx = c2 - cly*ATP;
                    BV_EMIT((unsigned)((y0 + cly)*WW + (x0 + clx)));
                    sp--; break;
                }
                int b3 = 31 - __builtin_clz(ev2);
                int i2 = (m2 >> b3) & 1, j2 = (k2 >> b3) & 1;
                if (i2 && j2) {
                    st_c[sp-1] = c2; st_s[sp-1] = b3; st_p[sp-1] = 1;
                    if (sp < 11) { st_c[sp] = c2 - cDT[b3]; st_s[sp] = b3 - 1; st_p[sp] = 0; sp++; }
                    else ok = false;
                    break;
                }
                if (i2) { BV_EMIT(1u << 30); sp--; break; }
                c2 -= cDT[b3]; s2 = b3 - 1;
            }
        } else if (ph == 1) {
            st_p[sp-1] = 2;
            if (sp < 11) { st_c[sp] = st_c[sp-1]; st_s[sp] = st_s[sp-1] - 1; st_p[sp] = 0; sp++; }
            else ok = false;
        } else {
            BV_EMIT(2u << 30);   // SUB
            sp--;
        }
    }
    if (!ok) return -1;
    BV_EMIT(3u << 30);           // END
    #undef BV_EMIT
    return ok ? n : -1;
}

// ---- Kernel A: fused mask+evolve + block-aggregated prog AND tree-list
//      allocation (2 global atomics/block). Tree cells go to the list;
//      Src record for them is just a kind-2 marker (apply writes 0,
//      bv_tree_kernel overwrites). kind-3 Src only on list overflow.
__global__ __launch_bounds__(ANT) void bv_mask_kernel(
    const float* __restrict__ Win, int Cin,
    float* __restrict__ Wout, int Cout,
    const unsigned char* __restrict__ bkall,
    const float* __restrict__ vel,
    float* __restrict__ vdout,
    unsigned char* __restrict__ Mg,
    unsigned char* __restrict__ SBg,
    int* __restrict__ SrcOut,
    unsigned* __restrict__ prog,
    unsigned* __restrict__ pcount,     // [0]=prog words, [1]=tree entries
    unsigned progcap,
    uint2* __restrict__ tlist,
    unsigned listcap,
    const float* __restrict__ elem_empty)
{
    __shared__ float A0[ATC], A1[ATC], B0F[ATC], B1F[ATC];   // 36.9 KB
    __shared__ unsigned char KSH[ATC];                       // 2.3 KB
    __shared__ unsigned sCnt[4];   // [0]=prog len sum [1]=prog base [2]=list cnt [3]=list base

    unsigned char* MSHb = (unsigned char*)B0F;               // post-steps M bytes
    unsigned char* SBb  = ((unsigned char*)B0F) + ATC;       // post-steps SB bytes

    const int tid = threadIdx.x;
    const int blk = blockIdx.x;
    const int tx = blk & 15, ty = (blk >> 4) & 15, b = blk >> 8;
    const int x0 = tx*32 - 8, y0 = ty*32 - 8;

    const float* inb  = Win  + (size_t)b*Cin*HW;
    float*       outb = Wout + (size_t)b*Cout*HW;
    const unsigned char* bkb = bkall + ((size_t)b << 18);
    const float* velb = vel   + (size_t)b*2*HW;
    float*       vdb  = vdout + (size_t)b*2*HW;
    unsigned char* Mob  = Mg  + ((size_t)b << 18);
    unsigned char* SBob = SBg + ((size_t)b << 18);
    int*           Srb  = SrcOut + ((size_t)b << 18);

    const float e0 = elem_empty[0];
    const float e1 = elem_empty[1];

    float v0r[4], v1r[4];
    unsigned kreg[4], mreg[4];
    unsigned mtail = 0;

    if (tid == 0) { sCnt[0] = 0; sCnt[2] = 0; }

    // ---- load: LDS + register copies for owned cells ----
    #pragma unroll
    for (int k = 0; k < 4; ++k) {
        int l = tid + (k << 9);
        int ly = l / ATP, lx = l - ly*ATP;
        int gy = y0 + ly, gx = x0 + lx;
        bool in = ((unsigned)gy < HH) && ((unsigned)gx < WW);
        int g = gy*WW + gx;
        float v0 = 0.f, v1 = 0.f; unsigned char kk = 0;
        if (in) { v0 = inb[g]; v1 = inb[HW + g]; kk = bkb[g]; }
        A0[l] = v0; A1[l] = v1; KSH[l] = kk;
        v0r[k] = v0; v1r[k] = v1; kreg[k] = kk; mreg[k] = 0;
    }
    if (tid < 256) {    // tail cells: LDS-resident values, register M
        int l = 2048 + tid;
        int ly = l / ATP, lx = l - ly*ATP;
        int gy = y0 + ly, gx = x0 + lx;
        bool in = ((unsigned)gy < HH) && ((unsigned)gx < WW);
        int g = gy*WW + gx;
        float v0 = 0.f, v1 = 0.f; unsigned char kk = 0;
        if (in) { v0 = inb[g]; v1 = inb[HW + g]; kk = bkb[g]; }
        A0[l] = v0; A1[l] = v1; KSH[l] = kk;
    }
    __syncthreads();

    // ---- 8 fused steps, one barrier each ----
    #pragma unroll
    for (int a = 0; a < 8; ++a) {
        const int doff = cDT[a];
        const unsigned tgt = (unsigned)(a | 8);
        const float* cA0 = (a & 1) ? B0F : A0;
        const float* cA1 = (a & 1) ? B1F : A1;
        float* nA0 = (a & 1) ? A0 : B0F;
        float* nA1 = (a & 1) ? A1 : B1F;
        #pragma unroll
        for (int k = 0; k < 4; ++k) {
            const int l = tid + (k << 9);
            int ln = l + doff; ln = ln < 0 ? 0 : (ln >= ATC ? ATC-1 : ln);
            int lo = l - doff; lo = lo < 0 ? 0 : (lo >= ATC ? ATC-1 : lo);
            float a0l = v0r[k], a1l = v1r[k];
            float a0n = cA0[ln];
            float a0o = cA0[lo], a1o = cA1[lo];
            unsigned ko = KSH[lo];
            bool sal = ((kreg[k] & 15u) == tgt) & (a0n > 0.5f) & !(a1l > 0.5f);
            bool sao = ((ko & 15u) == tgt) & (a0l > 0.5f) & !(a1o > 0.5f);
            mreg[k] |= (sal ? 1u : 0u) << a;
            float sa = sal ? 1.0f : 0.0f;
            float sb = sao ? 1.0f : 0.0f;
            float r0 = a0l - sa*a0l; r0 = r0 - sb*a0l; r0 = r0 + sa*e0; r0 = r0 + sb*a0o;
            float r1 = a1l - sa*a1l; r1 = r1 - sb*a1l; r1 = r1 + sa*e1; r1 = r1 + sb*a1o;
            v0r[k] = r0; v1r[k] = r1;
            nA0[l] = r0; nA1[l] = r1;
        }
        if (tid < 256) {
            const int l = 2048 + tid;
            int ln = l + doff; ln = ln < 0 ? 0 : (ln >= ATC ? ATC-1 : ln);
            int lo = l - doff; lo = lo < 0 ? 0 : (lo >= ATC ? ATC-1 : lo);
            float a0l = cA0[l], a1l = cA1[l];
            float a0n = cA0[ln];
            float a0o = cA0[lo], a1o = cA1[lo];
            unsigned kl = KSH[l], ko = KSH[lo];
            bool sal = ((kl & 15u) == tgt) & (a0n > 0.5f) & !(a1l > 0.5f);
            bool sao = ((ko & 15u) == tgt) & (a0l > 0.5f) & !(a1o > 0.5f);
            if (sal) mtail |= 1u << a;
            float sa = sal ? 1.0f : 0.0f;
            float sb = sao ? 1.0f : 0.0f;
            float r0 = a0l - sa*a0l; r0 = r0 - sb*a0l; r0 = r0 + sa*e0; r0 = r0 + sb*a0o;
            float r1 = a1l - sa*a1l; r1 = r1 - sb*a1l; r1 = r1 + sa*e1; r1 = r1 + sb*a1o;
            nA0[l] = r0; nA1[l] = r1;
        }
        __syncthreads();
    }
    // final ch0/ch1 in A0/A1; B0F/B1F dead -> alias as M/SB byte arrays

    #pragma unroll
    for (int k = 0; k < 4; ++k) MSHb[tid + (k << 9)] = (unsigned char)mreg[k];
    if (tid < 256) MSHb[2048 + tid] = (unsigned char)mtail;
    __syncthreads();

    // SB bits
    for (int l = tid; l < ATC; l += ANT) {
        unsigned sb8 = 0;
        #pragma unroll
        for (int a = 0; a < 8; ++a) {
            int lo = l - cDT[a]; lo = lo < 0 ? 0 : (lo >= ATC ? ATC-1 : lo);
            sb8 |= (unsigned)((MSHb[lo] >> a) & 1) << a;
        }
        SBb[l] = (unsigned char)sb8;
    }
    __syncthreads();

    // ---- pass A: interior writes, vdelta, walk; trees reserve LDS space ----
    int tKind[2]; unsigned tLoc[2], tLL[2], tN[2]; int tCc[2], tSs[2];
    #pragma unroll
    for (int it = 0; it < 2; ++it) {
        tKind[it] = 0;
        int li = tid + (it << 9);
        int iy = li >> 5, ix = li & 31;
        int l = (iy + 8)*ATP + ix + 8;
        int gy = ty*32 + iy, gx = tx*32 + ix;
        int g = gy*WW + gx;
        outb[g]      = A0[l];
        outb[HW + g] = A1[l];
        unsigned mm = MSHb[l], sbb = SBb[l];
        Mob[g]  = (unsigned char)mm;
        SBob[g] = (unsigned char)sbb;

        // vdelta (exact per-step order; vel fixed during iteration)
        float vy = velb[g], vx = velb[HW + g];
        float ddy = vy, ddx = vx;
        unsigned act = mm | sbb;
        if (act) {
            #pragma unroll
            for (int a = 0; a < 8; ++a) {
                if ((act >> a) & 1) {
                    float sa = (float)((mm  >> a) & 1);
                    float sb = (float)((sbb >> a) & 1);
                    float voy = 0.f, vox = 0.f;
                    if (sb != 0.f) {
                        int go = g - cDG[a];     // in-image when sb=1
                        voy = velb[go]; vox = velb[HW + go];
                    }
                    ddy = ddy - (sa*vy)*0.5f; ddy = ddy + (sb*voy)*0.5f;
                    ddx = ddx - (sa*vx)*0.5f; ddx = ddx + (sb*vox)*0.5f;
                }
            }
        }
        vdb[g]      = ddy;
        vdb[HW + g] = ddx;

        // provenance walk in LDS
        int cc = l, ss = 7, kd = 0;
        unsigned m = mm, sb = sbb;
        while (true) {
            unsigned evt = (m | sb) & ((2u << ss) - 1u);
            if (!evt) { kd = 0; break; }
            int bb = 31 - __builtin_clz(evt);
            int ia = (m >> bb) & 1, ib = (sb >> bb) & 1;
            if (ia && ib) { kd = 2; break; }        // tree at (cc, ss)
            if (ia) { kd = 1; break; }              // e=0 for c>=2 -> ZERO
            cc -= cDT[bb]; ss = bb - 1;             // sb-only: exact value move
            if (ss < 0) { kd = 0; break; }
            m = MSHb[cc]; sb = SBb[cc];
        }
        if (kd == 0) {
            int cly = cc / ATP, clx = cc - cly*ATP;
            Srb[g] = (int)(unsigned)((y0 + cly)*WW + (x0 + clx));
        } else if (kd == 1) {
            Srb[g] = (int)(1u << 30);
        } else {
            int n = bv_build(cc, ss, MSHb, SBb, y0, x0, (unsigned*)0);
            tCc[it] = cc; tSs[it] = ss;
            if (n < 0) { tKind[it] = 3; }           // eval-type list entry
            else { tKind[it] = 2; tN[it] = (unsigned)n;
                   tLoc[it] = atomicAdd(&sCnt[0], (unsigned)n); }
            tLL[it] = atomicAdd(&sCnt[2], 1u);
        }
    }
    __syncthreads();
    if (tid == 0) {
        sCnt[1] = sCnt[0] ? atomicAdd(&pcount[0], sCnt[0]) : 0u;
        sCnt[3] = sCnt[2] ? atomicAdd(&pcount[1], sCnt[2]) : 0u;
    }
    __syncthreads();
    unsigned gbase = sCnt[1], lbase = sCnt[3];

    // ---- pass B: emit tree programs + list entries ----
    #pragma unroll
    for (int it = 0; it < 2; ++it) {
        if (tKind[it] == 0) continue;
        int li = tid + (it << 9);
        int iy = li >> 5, ix = li & 31;
        int g = (ty*32 + iy)*WW + tx*32 + ix;
        int cly = tCc[it] / ATP, clx = tCc[it] - cly*ATP;
        unsigned gsrc = (unsigned)((y0 + cly)*WW + (x0 + clx));
        unsigned lidx = lbase + tLL[it];
        unsigned gb = ((unsigned)b << 18) | (unsigned)g;
        if (lidx < listcap) {
            bool asprog = false;
            if (tKind[it] == 2) {
                unsigned o = gbase + tLoc[it];
                if ((unsigned long long)o + tN[it] <= (unsigned long long)progcap) {
                    bv_build(tCc[it], tSs[it], MSHb, SBb, y0, x0, prog + o);
                    tlist[lidx] = make_uint2(gb, o);
                    asprog = true;
                }
            }
            if (!asprog)
                tlist[lidx] = make_uint2(gb, (1u<<31) | ((unsigned)tSs[it]<<28) | gsrc);
            Srb[g] = (int)(2u << 30);               // placeholder marker
        } else {
            Srb[g] = (int)((3u << 30) | ((unsigned)tSs[it] << 18) | gsrc);
        }
    }
}

// ---- fallback evaluator (global masks): list/prog overflow only.
__device__ __attribute__((noinline)) float bv_eval(
    int cell, int stp,
    const unsigned char* __restrict__ M,
    const unsigned char* __restrict__ SB,
    const float* __restrict__ initc)
{
    float vstk[10]; int vsp = 0;
    int cs_cell[10], cs_stp[10], cs_ph[10]; int csp = 0;
    cs_cell[0] = cell; cs_stp[0] = stp; cs_ph[0] = 0; csp = 1;
    while (csp > 0) {
        int ph = cs_ph[csp-1];
        if (ph == 0) {
            int cc = cs_cell[csp-1], ss = cs_stp[csp-1];
            float result = 0.0f; int have = 0;
            while (true) {
                if (ss < 0) { result = initc[cc]; have = 1; break; }
                unsigned m = M[cc], sb = SB[cc];
                unsigned evt = (m | sb) & ((2u << ss) - 1u);
                if (!evt) { result = initc[cc]; have = 1; break; }
                int bb = 31 - __builtin_clz(evt);
                int ia = (m >> bb) & 1, ib = (sb >> bb) & 1;
                if (ia && ib) {
                    cs_cell[csp-1] = cc; cs_stp[csp-1] = bb; cs_ph[csp-1] = 1;
                    cs_cell[csp] = cc - cDG[bb]; cs_stp[csp] = bb - 1; cs_ph[csp] = 0; csp++;
                    break;
                }
                if (ia) { result = 0.0f; have = 1; break; }
                cc -= cDG[bb]; ss = bb - 1;
            }
            if (have) { vstk[vsp++] = result; csp--; }
        } else if (ph == 1) {
            cs_ph[csp-1] = 2;
            cs_cell[csp] = cs_cell[csp-1]; cs_stp[csp] = cs_stp[csp-1] - 1;
            cs_ph[csp] = 0; csp++;
        } else {
            float Bv = vstk[--vsp]; float Av = vstk[--vsp];
            vstk[vsp++] = Av - Bv;
            csp--;
        }
    }
    return vstk[0];
}

// ---- Kernel B: apply provenance; replay-free hot path.
__global__ __launch_bounds__(256) void bv_apply_kernel(
    const float* __restrict__ Win, int Cin,
    float* __restrict__ Wout, int Cout,
    const int* __restrict__ Src,
    const unsigned char* __restrict__ M,
    const unsigned char* __restrict__ SB)
{
    int t = blockIdx.x*256 + threadIdx.x;   // over BHW/4
    if (t >= BHW/4) return;
    const int c0 = 2 + blockIdx.y*4;        // channel group [c0, c0+4)
    int p = t << 2;
    int b = p >> 18;
    int own = p & (HW-1);
    const float* inb  = Win  + (size_t)b*Cin*HW;
    float*       outb = Wout + (size_t)b*Cout*HW;
    const int* Srb = Src + ((size_t)b << 18);

    int4 s4 = *(const int4*)(Srb + own);
    unsigned sv[4] = {(unsigned)s4.x, (unsigned)s4.y, (unsigned)s4.z, (unsigned)s4.w};
    int kind[4], idx[4];
    #pragma unroll
    for (int j = 0; j < 4; ++j) {
        kind[j] = (int)(sv[j] >> 30);
        idx[j]  = (int)(sv[j] & 0x3FFFFu);
    }

    bool fast = true;
    #pragma unroll
    for (int j = 0; j < 4; ++j) fast = fast && (kind[j] == 0) && (idx[j] == own + j);

    if (fast) {
        #pragma unroll
        for (int c = 0; c < 4; ++c) {
            float4 v = *(const float4*)(inb + (size_t)(c0 + c)*HW + own);
            *(float4*)(outb + (size_t)(c0 + c)*HW + own) = v;
        }
        return;
    }
    bool anyeval = false;
    #pragma unroll
    for (int j = 0; j < 4; ++j) anyeval = anyeval || (kind[j] == 3);
    #pragma unroll
    for (int c = 0; c < 4; ++c) {
        const float* ic = inb + (size_t)(c0 + c)*HW;
        float r[4];
        #pragma unroll
        for (int j = 0; j < 4; ++j)
            r[j] = (kind[j] == 0) ? ic[idx[j]] : 0.0f;   // kind1/2 -> 0 (2 = placeholder)
        if (anyeval) {
            const unsigned char* Mb  = M  + ((size_t)b << 18);
            const unsigned char* SBb = SB + ((size_t)b << 18);
            #pragma unroll
            for (int j = 0; j < 4; ++j)
                if (kind[j] == 3)
                    r[j] = bv_eval(idx[j], (int)((sv[j] >> 18) & 7u), Mb, SBb, ic);
        }
        *(float4*)(outb + (size_t)(c0 + c)*HW + own) = make_float4(r[0], r[1], r[2], r[3]);
    }
}

// ---- Kernel C: tree cells only (~0.8% of pixels). One program replay
//      drives 4 channels at once (shared control chain, independent leaves).
__global__ __launch_bounds__(256) void bv_tree_kernel(
    const float* __restrict__ Win, int Cin,
    float* __restrict__ Wout, int Cout,
    const uint2* __restrict__ tlist,
    const unsigned* __restrict__ pcount,   // [1] = entry count
    unsigned listcap,
    const unsigned* __restrict__ prog,
    const unsigned char* __restrict__ M,
    const unsigned char* __restrict__ SB)
{
    unsigned n = pcount[1]; if (n > listcap) n = listcap;
    for (unsigned i = blockIdx.x*256 + threadIdx.x; i < n; i += gridDim.x*256) {
        uint2 e = tlist[i];
        int b = (int)(e.x >> 18);
        int g = (int)(e.x & 0x3FFFFu);
        const float* inb  = Win  + (size_t)b*Cin*HW;
        float*       outb = Wout + (size_t)b*Cout*HW;
        if (e.y >> 31) {   // eval-type (depth overflow; rare)
            int cc = (int)(e.y & 0x3FFFFu);
            int ss = (int)((e.y >> 28) & 7u);
            const unsigned char* Mb  = M  + ((size_t)b << 18);
            const unsigned char* SBb = SB + ((size_t)b << 18);
            #pragma unroll 1
            for (int c = 2; c < NCH; ++c)
                outb[(size_t)c*HW + g] = bv_eval(cc, ss, Mb, SBb, inb + (size_t)c*HW);
        } else {
            unsigned off = e.y;
            #pragma unroll 1
            for (int grp = 0; grp < 4; ++grp) {
                const float* ic0 = inb + (size_t)(2 + grp*4 + 0)*HW;
                const float* ic1 = inb + (size_t)(2 + grp*4 + 1)*HW;
                const float* ic2 = inb + (size_t)(2 + grp*4 + 2)*HW;
                const float* ic3 = inb + (size_t)(2 + grp*4 + 3)*HW;
                float v0[11], v1[11], v2[11], v3[11]; int vsp = 0;
                const unsigned* pr = prog + off;
                while (true) {
                    unsigned w = *pr++;
                    unsigned k = w >> 30;
                    if (k == 0) {
                        unsigned ix = w & 0x3FFFFu;
                        v0[vsp] = ic0[ix]; v1[vsp] = ic1[ix];
                        v2[vsp] = ic2[ix]; v3[vsp] = ic3[ix]; vsp++;
                    } else if (k == 1) {
                        v0[vsp] = 0.f; v1[vsp] = 0.f; v2[vsp] = 0.f; v3[vsp] = 0.f; vsp++;
                    } else if (k == 2) {
                        vsp--;
                        v0[vsp-1] = v0[vsp-1] - v0[vsp];
                        v1[vsp-1] = v1[vsp-1] - v1[vsp];
                        v2[vsp-1] = v2[vsp-1] - v2[vsp];
                        v3[vsp-1] = v3[vsp-1] - v3[vsp];
                    } else break;
                }
                outb[(size_t)(2 + grp*4 + 0)*HW + g] = v0[0];
                outb[(size_t)(2 + grp*4 + 1)*HW + g] = v1[0];
                outb[(size_t)(2 + grp*4 + 2)*HW + g] = v2[0];
                outb[(size_t)(2 + grp*4 + 3)*HW + g] = v3[0];
            }
        }
    }
}

// smooth(0.95*v): conv3x3(ones/18, zero-pad) + center*0.5 -> world ch18,19
__global__ __launch_bounds__(256) void bv_smooth_kernel(
    const float* __restrict__ vin, float* __restrict__ dout)
{
    int idx = blockIdx.x*256 + threadIdx.x;
    if (idx >= BATCH*2*HW) return;
    int x = idx & (WW-1);
    int y = (idx >> 9) & (HH-1);
    int c = (idx >> 18) & 1;
    int b = idx >> 19;
    const float* vb = vin + (size_t)(b*2 + c)*HW;
    const float w18 = (float)(1.0/18.0);
    float acc = 0.0f;
    for (int ky = -1; ky <= 1; ++ky) {
        int yy = y + ky;
        if ((unsigned)yy >= HH) continue;
        for (int kx = -1; kx <= 1; ++kx) {
            int xx2 = x + kx;
            if ((unsigned)xx2 >= WW) continue;
            float s = 0.95f * vb[yy*WW + xx2];
            acc += s * w18;
        }
    }
    float sc = 0.95f * vb[y*WW + x];
    float res = acc + sc * 0.5f;
    dout[((size_t)b*20 + 18 + c)*HW + (size_t)(y<<9) + x] = res;
}

__global__ __launch_bounds__(256) void bv_copyvel_kernel(float* __restrict__ dout)
{
    int idx = blockIdx.x*256 + threadIdx.x;
    if (idx >= BATCH*2*HW) return;
    int x = idx & (WW-1);
    int y = (idx >> 9) & (HH-1);
    int c = (idx >> 18) & 1;
    int b = idx >> 19;
    float v = dout[((size_t)b*20 + 18 + c)*HW + (size_t)(y<<9) + x];
    dout[(size_t)BATCH*20*HW + (size_t)idx] = v;
}

extern "C" void kernel_launch(void* const* d_in, const int* in_sizes, int n_in,
                              void* d_out, int out_size, void* d_ws, size_t ws_size,
                              hipStream_t stream)
{
    const float* world_in   = (const float*)d_in[0];
    const float* vel_in     = (const float*)d_in[1];
    const float* elem_empty = (const float*)d_in[2];
    float* out = (float*)d_out;

    // ws: worldA (18ch) | vd1 | bk | M | SB | Src | cnt | tlist | prog
    float* wsA = (float*)d_ws;                                 // 4*18*HW floats
    float* vd1 = wsA + (size_t)BATCH*NCH*HW;                   // 4*2*HW floats
    unsigned char* bk  = (unsigned char*)(vd1 + (size_t)BATCH*2*HW); // BHW
    unsigned char* Mb  = bk + (size_t)BHW;                     // BHW
    unsigned char* SBb = Mb + (size_t)BHW;                     // BHW
    int* Srcb = (int*)(SBb + (size_t)BHW);                     // BHW ints
    unsigned* pcount = (unsigned*)(Srcb + (size_t)BHW);        // 64 B slot
    const unsigned listcap = 1u << 16;                         // 64K entries
    uint2* tlistb = (uint2*)(pcount + 16);                     // 512 KB
    unsigned* progb = (unsigned*)(tlistb + listcap);
    size_t used = (size_t)((char*)progb - (char*)d_ws);
    unsigned progcap = 0;
    if (ws_size > used + 4096)
        progcap = (unsigned)((ws_size - used - 4096) / 4);
    if (progcap > (1u << 20)) progcap = 1u << 20;              // 4 MB cap
    float* vel2 = out + (size_t)BATCH*20*HW;                   // out tail

    dim3 blk(256);
    dim3 grd((BHW + 255)/256);
    dim3 g2((BATCH*2*HW + 255)/256);
    dim3 gA(BATCH*16*16);            // 1024 tile-blocks
    dim3 gB(BHW/4/256, 4);           // 1024 x 4 channel-groups
    dim3 gT(256);                    // tree kernel, grid-stride

    // ---- iteration 1 ----
    bv_bucket_kernel<<<grd, blk, 0, stream>>>(vel_in, bk, pcount);
    bv_mask_kernel<<<gA, dim3(ANT), 0, stream>>>(world_in, 20, wsA, NCH, bk,
                                                 vel_in, vd1, Mb, SBb, Srcb,
                                                 progb, pcount, progcap,
                                                 tlistb, listcap, elem_empty);
    bv_apply_kernel<<<gB, blk, 0, stream>>>(world_in, 20, wsA, NCH, Srcb, Mb, SBb);
    bv_tree_kernel<<<gT, blk, 0, stream>>>(world_in, 20, wsA, NCH, tlistb, pcount,
                                           listcap, progb, Mb, SBb);
    // ---- iteration 2 ----
    bv_bucket_kernel<<<grd, blk, 0, stream>>>(vd1, bk, pcount);
    bv_mask_kernel<<<gA, dim3(ANT), 0, stream>>>(wsA, NCH, out, 20, bk,
                                                 vd1, vel2, Mb, SBb, Srcb,
                                                 progb, pcount, progcap,
                                                 tlistb, listcap, elem_empty);
    bv_apply_kernel<<<gB, blk, 0, stream>>>(wsA, NCH, out, 20, Srcb, Mb, SBb);
    bv_tree_kernel<<<gT, blk, 0, stream>>>(wsA, NCH, out, 20, tlistb, pcount,
                                           listcap, progb, Mb, SBb);
    // ---- epilogue ----
    bv_smooth_kernel<<<g2, blk, 0, stream>>>(vel2, out);
    bv_copyvel_kernel<<<g2, blk, 0, stream>>>(out);
}

// Round 12
// 248.024 us; speedup vs baseline: 6.7815x; 1.4691x over previous
//
#include <hip/hip_runtime.h>
#include <math.h>

#define HH 512
#define WW 512
#define HW (HH*WW)          // 262144
#define BATCH 4
#define NCH 18              // simulated channels (18,19 overwritten at end)
#define BHW (BATCH*HW)

__device__ __constant__ int cDG[8] = {-512,-511,1,513,512,511,-1,-513}; // dy*WW+dx
__device__ __constant__ int cDT[8] = {-48,-47,1,49,48,47,-1,-49};       // dy*ATP+dx

// bucket (3 bits) | enough (bit 3); zeroes tree-list counter
__global__ __launch_bounds__(256) void bv_bucket_kernel(
    const float* __restrict__ vel, unsigned char* __restrict__ bk,
    unsigned* __restrict__ pcount)
{
    int idx = blockIdx.x*256 + threadIdx.x;
    if (idx == 0) { pcount[0] = 0; pcount[1] = 0; }
    if (idx >= BHW) return;
    int b = idx >> 18;
    int rem = idx & (HW-1);
    const float* vb = vel + (size_t)b*2*HW;
    float vy = vb[rem];
    float vx = vb[HW + rem];
    float a2 = vy*vy;
    float b2 = vx*vx;
    float mag = sqrtf(a2 + b2);
    float xx = vx / (mag + 0.001f);
    float af = (float)acos((double)xx);
    const float inv2pi = (float)(1.0/(2.0*3.14159265358979323846));
    float raw = inv2pi * af;
    float ang = (vy < 0.0f) ? (1.0f - raw) : raw;
    float t = ang * 8.0f + 0.5f;
    int bkt = (int)floorf(t);
    bkt &= 7;
    unsigned char e = (mag > 0.1f) ? (unsigned char)8 : (unsigned char)0;
    bk[idx] = (unsigned char)(bkt | e);
}

#define ATP 48
#define ATC (48*48)   // 2304 = 4*512 + 256
#define ANT 512

// ---- Kernel A: fused mask+evolve; emits ch0/ch1, M, SB, Src records,
//      and a compacted tree-cell list (block-aggregated, 1 global atomic).
//      No program building, no vdelta (separate kernels now).
//      Record kinds: 0=COPY gsrc; 1=ZERO; 2=tree placeholder (tree kernel
//      overwrites); 3=EVAL (ss<<18)|gsrc (list-overflow fallback only).
__global__ __launch_bounds__(ANT) void bv_mask_kernel(
    const float* __restrict__ Win, int Cin,
    float* __restrict__ Wout, int Cout,
    const unsigned char* __restrict__ bkall,
    unsigned char* __restrict__ Mg,
    unsigned char* __restrict__ SBg,
    int* __restrict__ SrcOut,
    unsigned* __restrict__ pcount,     // [1]=tree entries
    uint2* __restrict__ tlist,
    unsigned listcap,
    const float* __restrict__ elem_empty)
{
    __shared__ float A0[ATC], A1[ATC], B0F[ATC], B1F[ATC];   // 36.9 KB
    __shared__ unsigned char KSH[ATC];                       // 2.3 KB
    __shared__ unsigned sCnt[2];   // [0]=list cnt, [1]=list base

    unsigned char* MSHb = (unsigned char*)B0F;               // post-steps M bytes
    unsigned char* SBb  = ((unsigned char*)B0F) + ATC;       // post-steps SB bytes

    const int tid = threadIdx.x;
    const int blk = blockIdx.x;
    const int tx = blk & 15, ty = (blk >> 4) & 15, b = blk >> 8;
    const int x0 = tx*32 - 8, y0 = ty*32 - 8;

    const float* inb  = Win  + (size_t)b*Cin*HW;
    float*       outb = Wout + (size_t)b*Cout*HW;
    const unsigned char* bkb = bkall + ((size_t)b << 18);
    unsigned char* Mob  = Mg  + ((size_t)b << 18);
    unsigned char* SBob = SBg + ((size_t)b << 18);
    int*           Srb  = SrcOut + ((size_t)b << 18);

    const float e0 = elem_empty[0];
    const float e1 = elem_empty[1];

    float v0r[4], v1r[4];
    unsigned kreg[4], mreg[4];
    unsigned mtail = 0;

    if (tid == 0) sCnt[0] = 0;

    // ---- load: LDS + register copies for owned cells ----
    #pragma unroll
    for (int k = 0; k < 4; ++k) {
        int l = tid + (k << 9);
        int ly = l / ATP, lx = l - ly*ATP;
        int gy = y0 + ly, gx = x0 + lx;
        bool in = ((unsigned)gy < HH) && ((unsigned)gx < WW);
        int g = gy*WW + gx;
        float v0 = 0.f, v1 = 0.f; unsigned char kk = 0;
        if (in) { v0 = inb[g]; v1 = inb[HW + g]; kk = bkb[g]; }
        A0[l] = v0; A1[l] = v1; KSH[l] = kk;
        v0r[k] = v0; v1r[k] = v1; kreg[k] = kk; mreg[k] = 0;
    }
    if (tid < 256) {    // tail cells: LDS-resident values, register M
        int l = 2048 + tid;
        int ly = l / ATP, lx = l - ly*ATP;
        int gy = y0 + ly, gx = x0 + lx;
        bool in = ((unsigned)gy < HH) && ((unsigned)gx < WW);
        int g = gy*WW + gx;
        float v0 = 0.f, v1 = 0.f; unsigned char kk = 0;
        if (in) { v0 = inb[g]; v1 = inb[HW + g]; kk = bkb[g]; }
        A0[l] = v0; A1[l] = v1; KSH[l] = kk;
    }
    __syncthreads();

    // ---- 8 fused steps, one barrier each ----
    #pragma unroll
    for (int a = 0; a < 8; ++a) {
        const int doff = cDT[a];
        const unsigned tgt = (unsigned)(a | 8);
        const float* cA0 = (a & 1) ? B0F : A0;
        const float* cA1 = (a & 1) ? B1F : A1;
        float* nA0 = (a & 1) ? A0 : B0F;
        float* nA1 = (a & 1) ? A1 : B1F;
        #pragma unroll
        for (int k = 0; k < 4; ++k) {
            const int l = tid + (k << 9);
            int ln = l + doff; ln = ln < 0 ? 0 : (ln >= ATC ? ATC-1 : ln);
            int lo = l - doff; lo = lo < 0 ? 0 : (lo >= ATC ? ATC-1 : lo);
            float a0l = v0r[k], a1l = v1r[k];
            float a0n = cA0[ln];
            float a0o = cA0[lo], a1o = cA1[lo];
            unsigned ko = KSH[lo];
            bool sal = ((kreg[k] & 15u) == tgt) & (a0n > 0.5f) & !(a1l > 0.5f);
            bool sao = ((ko & 15u) == tgt) & (a0l > 0.5f) & !(a1o > 0.5f);
            mreg[k] |= (sal ? 1u : 0u) << a;
            float sa = sal ? 1.0f : 0.0f;
            float sb = sao ? 1.0f : 0.0f;
            float r0 = a0l - sa*a0l; r0 = r0 - sb*a0l; r0 = r0 + sa*e0; r0 = r0 + sb*a0o;
            float r1 = a1l - sa*a1l; r1 = r1 - sb*a1l; r1 = r1 + sa*e1; r1 = r1 + sb*a1o;
            v0r[k] = r0; v1r[k] = r1;
            nA0[l] = r0; nA1[l] = r1;
        }
        if (tid < 256) {
            const int l = 2048 + tid;
            int ln = l + doff; ln = ln < 0 ? 0 : (ln >= ATC ? ATC-1 : ln);
            int lo = l - doff; lo = lo < 0 ? 0 : (lo >= ATC ? ATC-1 : lo);
            float a0l = cA0[l], a1l = cA1[l];
            float a0n = cA0[ln];
            float a0o = cA0[lo], a1o = cA1[lo];
            unsigned kl = KSH[l], ko = KSH[lo];
            bool sal = ((kl & 15u) == tgt) & (a0n > 0.5f) & !(a1l > 0.5f);
            bool sao = ((ko & 15u) == tgt) & (a0l > 0.5f) & !(a1o > 0.5f);
            if (sal) mtail |= 1u << a;
            float sa = sal ? 1.0f : 0.0f;
            float sb = sao ? 1.0f : 0.0f;
            float r0 = a0l - sa*a0l; r0 = r0 - sb*a0l; r0 = r0 + sa*e0; r0 = r0 + sb*a0o;
            float r1 = a1l - sa*a1l; r1 = r1 - sb*a1l; r1 = r1 + sa*e1; r1 = r1 + sb*a1o;
            nA0[l] = r0; nA1[l] = r1;
        }
        __syncthreads();
    }
    // final ch0/ch1 in A0/A1; B0F/B1F dead -> alias as M/SB byte arrays

    #pragma unroll
    for (int k = 0; k < 4; ++k) MSHb[tid + (k << 9)] = (unsigned char)mreg[k];
    if (tid < 256) MSHb[2048 + tid] = (unsigned char)mtail;
    __syncthreads();

    // SB bits
    for (int l = tid; l < ATC; l += ANT) {
        unsigned sb8 = 0;
        #pragma unroll
        for (int a = 0; a < 8; ++a) {
            int lo = l - cDT[a]; lo = lo < 0 ? 0 : (lo >= ATC ? ATC-1 : lo);
            sb8 |= (unsigned)((MSHb[lo] >> a) & 1) << a;
        }
        SBb[l] = (unsigned char)sb8;
    }
    __syncthreads();

    // ---- pass A: interior writes + provenance walk; trees counted in LDS ----
    int tKind[2]; unsigned tLL[2]; int tCc[2], tSs[2];
    #pragma unroll
    for (int it = 0; it < 2; ++it) {
        tKind[it] = 0;
        int li = tid + (it << 9);
        int iy = li >> 5, ix = li & 31;
        int l = (iy + 8)*ATP + ix + 8;
        int gy = ty*32 + iy, gx = tx*32 + ix;
        int g = gy*WW + gx;
        outb[g]      = A0[l];
        outb[HW + g] = A1[l];
        unsigned mm = MSHb[l], sbb = SBb[l];
        Mob[g]  = (unsigned char)mm;
        SBob[g] = (unsigned char)sbb;

        // provenance walk in LDS
        int cc = l, ss = 7, kd = 0;
        unsigned m = mm, sb = sbb;
        while (true) {
            unsigned evt = (m | sb) & ((2u << ss) - 1u);
            if (!evt) { kd = 0; break; }
            int bb = 31 - __builtin_clz(evt);
            int ia = (m >> bb) & 1, ib = (sb >> bb) & 1;
            if (ia && ib) { kd = 2; break; }        // tree at (cc, ss)
            if (ia) { kd = 1; break; }              // e=0 for c>=2 -> ZERO
            cc -= cDT[bb]; ss = bb - 1;             // sb-only: exact value move
            if (ss < 0) { kd = 0; break; }
            m = MSHb[cc]; sb = SBb[cc];
        }
        if (kd == 0) {
            int cly = cc / ATP, clx = cc - cly*ATP;
            Srb[g] = (int)(unsigned)((y0 + cly)*WW + (x0 + clx));
        } else if (kd == 1) {
            Srb[g] = (int)(1u << 30);
        } else {
            tKind[it] = 1; tCc[it] = cc; tSs[it] = ss;
            tLL[it] = atomicAdd(&sCnt[0], 1u);       // fast LDS atomic
        }
    }
    __syncthreads();
    if (tid == 0) sCnt[1] = sCnt[0] ? atomicAdd(&pcount[1], sCnt[0]) : 0u;
    __syncthreads();
    unsigned lbase = sCnt[1];

    // ---- pass B: emit list entries ----
    #pragma unroll
    for (int it = 0; it < 2; ++it) {
        if (!tKind[it]) continue;
        int li = tid + (it << 9);
        int iy = li >> 5, ix = li & 31;
        int g = (ty*32 + iy)*WW + tx*32 + ix;
        int cly = tCc[it] / ATP, clx = tCc[it] - cly*ATP;
        unsigned gsrc = (unsigned)((y0 + cly)*WW + (x0 + clx));
        unsigned lidx = lbase + tLL[it];
        if (lidx < listcap) {
            tlist[lidx] = make_uint2(((unsigned)b << 18) | (unsigned)g,
                                     ((unsigned)tSs[it] << 28) | gsrc);
            Srb[g] = (int)(2u << 30);               // placeholder marker
        } else {
            Srb[g] = (int)((3u << 30) | ((unsigned)tSs[it] << 18) | gsrc);
        }
    }
}

// ---- vdelta: own-cell M/SB + velocity; exact per-step op order ----
__global__ __launch_bounds__(256) void bv_vdelta_kernel(
    const unsigned char* __restrict__ M,
    const unsigned char* __restrict__ SB,
    const float* __restrict__ vel,
    float* __restrict__ vdout)
{
    int idx = blockIdx.x*256 + threadIdx.x;
    if (idx >= BHW) return;
    int b = idx >> 18;
    int g = idx & (HW-1);
    const float* velb = vel   + (size_t)b*2*HW;
    float*       vdb  = vdout + (size_t)b*2*HW;
    unsigned mm  = M[((size_t)b << 18) + g];
    unsigned sbb = SB[((size_t)b << 18) + g];
    float vy = velb[g], vx = velb[HW + g];
    float ddy = vy, ddx = vx;
    unsigned act = mm | sbb;
    if (act) {
        #pragma unroll
        for (int a = 0; a < 8; ++a) {
            if ((act >> a) & 1) {
                float sa = (float)((mm  >> a) & 1);
                float sb = (float)((sbb >> a) & 1);
                float voy = 0.f, vox = 0.f;
                if (sb != 0.f) {
                    int go = g - cDG[a];     // in-image when sb=1
                    voy = velb[go]; vox = velb[HW + go];
                }
                ddy = ddy - (sa*vy)*0.5f; ddy = ddy + (sb*voy)*0.5f;
                ddx = ddx - (sa*vx)*0.5f; ddx = ddx + (sb*vox)*0.5f;
            }
        }
    }
    vdb[g]      = ddy;
    vdb[HW + g] = ddx;
}

// ---- scalar evaluator (global masks): apply's list-overflow fallback only.
__device__ __attribute__((noinline)) float bv_eval(
    int cell, int stp,
    const unsigned char* __restrict__ M,
    const unsigned char* __restrict__ SB,
    const float* __restrict__ initc)
{
    float vstk[10]; int vsp = 0;
    int cs_cell[10], cs_stp[10], cs_ph[10]; int csp = 0;
    cs_cell[0] = cell; cs_stp[0] = stp; cs_ph[0] = 0; csp = 1;
    while (csp > 0) {
        int ph = cs_ph[csp-1];
        if (ph == 0) {
            int cc = cs_cell[csp-1], ss = cs_stp[csp-1];
            float result = 0.0f; int have = 0;
            while (true) {
                if (ss < 0) { result = initc[cc]; have = 1; break; }
                unsigned m = M[cc], sb = SB[cc];
                unsigned evt = (m | sb) & ((2u << ss) - 1u);
                if (!evt) { result = initc[cc]; have = 1; break; }
                int bb = 31 - __builtin_clz(evt);
                int ia = (m >> bb) & 1, ib = (sb >> bb) & 1;
                if (ia && ib) {
                    cs_cell[csp-1] = cc; cs_stp[csp-1] = bb; cs_ph[csp-1] = 1;
                    cs_cell[csp] = cc - cDG[bb]; cs_stp[csp] = bb - 1; cs_ph[csp] = 0; csp++;
                    break;
                }
                if (ia) { result = 0.0f; have = 1; break; }
                cc -= cDG[bb]; ss = bb - 1;
            }
            if (have) { vstk[vsp++] = result; csp--; }
        } else if (ph == 1) {
            cs_ph[csp-1] = 2;
            cs_cell[csp] = cs_cell[csp-1]; cs_stp[csp] = cs_stp[csp-1] - 1;
            cs_ph[csp] = 0; csp++;
        } else {
            float Bv = vstk[--vsp]; float Av = vstk[--vsp];
            vstk[vsp++] = Av - Bv;
            csp--;
        }
    }
    return vstk[0];
}

// 4-channel evaluator: one control traversal drives 4 value stacks.
__device__ void bv_eval4(int cell, int stp,
    const unsigned char* __restrict__ M,
    const unsigned char* __restrict__ SB,
    const float* __restrict__ i0, const float* __restrict__ i1,
    const float* __restrict__ i2, const float* __restrict__ i3,
    float& r0, float& r1, float& r2, float& r3)
{
    float v0[10], v1[10], v2[10], v3[10]; int vsp = 0;
    int cs_cell[10], cs_stp[10], cs_ph[10]; int csp = 0;
    cs_cell[0] = cell; cs_stp[0] = stp; cs_ph[0] = 0; csp = 1;
    while (csp > 0) {
        int ph = cs_ph[csp-1];
        if (ph == 0) {
            int cc = cs_cell[csp-1], ss = cs_stp[csp-1];
            int have = 0, zero = 0, leaf = 0;
            while (true) {
                if (ss < 0) { leaf = cc; have = 1; break; }
                unsigned m = M[cc], sb = SB[cc];
                unsigned evt = (m | sb) & ((2u << ss) - 1u);
                if (!evt) { leaf = cc; have = 1; break; }
                int bb = 31 - __builtin_clz(evt);
                int ia = (m >> bb) & 1, ib = (sb >> bb) & 1;
                if (ia && ib) {
                    cs_cell[csp-1] = cc; cs_stp[csp-1] = bb; cs_ph[csp-1] = 1;
                    cs_cell[csp] = cc - cDG[bb]; cs_stp[csp] = bb - 1; cs_ph[csp] = 0; csp++;
                    break;
                }
                if (ia) { zero = 1; have = 1; break; }
                cc -= cDG[bb]; ss = bb - 1;
            }
            if (have) {
                if (zero) { v0[vsp]=0.f; v1[vsp]=0.f; v2[vsp]=0.f; v3[vsp]=0.f; }
                else { v0[vsp]=i0[leaf]; v1[vsp]=i1[leaf]; v2[vsp]=i2[leaf]; v3[vsp]=i3[leaf]; }
                vsp++; csp--;
            }
        } else if (ph == 1) {
            cs_ph[csp-1] = 2;
            cs_cell[csp] = cs_cell[csp-1]; cs_stp[csp] = cs_stp[csp-1] - 1;
            cs_ph[csp] = 0; csp++;
        } else {
            vsp--;
            v0[vsp-1] = v0[vsp-1] - v0[vsp];   // fl(wo - w)
            v1[vsp-1] = v1[vsp-1] - v1[vsp];
            v2[vsp-1] = v2[vsp-1] - v2[vsp];
            v3[vsp-1] = v3[vsp-1] - v3[vsp];
            csp--;
        }
    }
    r0 = v0[0]; r1 = v1[0]; r2 = v2[0]; r3 = v3[0];
}

// ---- Kernel B: apply provenance; float4 base + lane patches, no replay.
__global__ __launch_bounds__(256) void bv_apply_kernel(
    const float* __restrict__ Win, int Cin,
    float* __restrict__ Wout, int Cout,
    const int* __restrict__ Src,
    const unsigned char* __restrict__ M,
    const unsigned char* __restrict__ SB)
{
    int t = blockIdx.x*256 + threadIdx.x;   // over BHW/4
    if (t >= BHW/4) return;
    const int c0 = 2 + blockIdx.y*4;        // channel group [c0, c0+4)
    int p = t << 2;
    int b = p >> 18;
    int own = p & (HW-1);
    const float* inb  = Win  + (size_t)b*Cin*HW;
    float*       outb = Wout + (size_t)b*Cout*HW;
    const int* Srb = Src + ((size_t)b << 18);

    int4 s4 = *(const int4*)(Srb + own);
    unsigned sv[4] = {(unsigned)s4.x, (unsigned)s4.y, (unsigned)s4.z, (unsigned)s4.w};
    int kind[4], idx[4]; bool need[4];
    bool allself = true, anyeval = false;
    #pragma unroll
    for (int j = 0; j < 4; ++j) {
        kind[j] = (int)(sv[j] >> 30);
        idx[j]  = (int)(sv[j] & 0x3FFFFu);
        need[j] = (kind[j] != 0) || (idx[j] != own + j);
        allself = allself && !need[j];
        anyeval = anyeval || (kind[j] == 3);
    }

    if (allself) {
        #pragma unroll
        for (int c = 0; c < 4; ++c) {
            float4 v = *(const float4*)(inb + (size_t)(c0 + c)*HW + own);
            *(float4*)(outb + (size_t)(c0 + c)*HW + own) = v;
        }
        return;
    }
    const unsigned char* Mb  = M  + ((size_t)b << 18);
    const unsigned char* SBb = SB + ((size_t)b << 18);
    #pragma unroll
    for (int c = 0; c < 4; ++c) {
        const float* ic = inb + (size_t)(c0 + c)*HW;
        float4 v = *(const float4*)(ic + own);
        float r[4] = {v.x, v.y, v.z, v.w};
        #pragma unroll
        for (int j = 0; j < 4; ++j) {
            if (need[j]) {
                if (kind[j] == 0) r[j] = ic[idx[j]];
                else if (kind[j] == 3) r[j] = bv_eval(idx[j], (int)((sv[j] >> 18) & 7u), Mb, SBb, ic);
                else r[j] = 0.0f;        // ZERO or tree placeholder
            }
        }
        *(float4*)(outb + (size_t)(c0 + c)*HW + own) = make_float4(r[0], r[1], r[2], r[3]);
    }
}

// ---- Kernel C: tree cells (~0.8%); thread per (entry, channel-group).
__global__ __launch_bounds__(256) void bv_tree_kernel(
    const float* __restrict__ Win, int Cin,
    float* __restrict__ Wout, int Cout,
    const uint2* __restrict__ tlist,
    const unsigned* __restrict__ pcount,   // [1] = entry count
    unsigned listcap,
    const unsigned char* __restrict__ M,
    const unsigned char* __restrict__ SB)
{
    unsigned n = pcount[1]; if (n > listcap) n = listcap;
    unsigned total = n * 4;
    for (unsigned i = blockIdx.x*256 + threadIdx.x; i < total; i += gridDim.x*256) {
        unsigned ei = i >> 2; int grp = (int)(i & 3);
        uint2 e = tlist[ei];
        int b = (int)(e.x >> 18);
        int g = (int)(e.x & 0x3FFFFu);
        int cc = (int)(e.y & 0x3FFFFu);
        int ss = (int)((e.y >> 28) & 7u);
        const float* inb  = Win  + (size_t)b*Cin*HW;
        float*       outb = Wout + (size_t)b*Cout*HW;
        const unsigned char* Mb  = M  + ((size_t)b << 18);
        const unsigned char* SBb = SB + ((size_t)b << 18);
        int c0 = 2 + grp*4;
        const float* i0 = inb + (size_t)c0*HW;
        const float* i1 = i0 + HW;
        const float* i2 = i1 + HW;
        const float* i3 = i2 + HW;
        float r0, r1, r2, r3;
        bv_eval4(cc, ss, Mb, SBb, i0, i1, i2, i3, r0, r1, r2, r3);
        outb[(size_t)(c0 + 0)*HW + g] = r0;
        outb[(size_t)(c0 + 1)*HW + g] = r1;
        outb[(size_t)(c0 + 2)*HW + g] = r2;
        outb[(size_t)(c0 + 3)*HW + g] = r3;
    }
}

// smooth(0.95*v): conv3x3(ones/18, zero-pad) + center*0.5 -> world ch18,19
__global__ __launch_bounds__(256) void bv_smooth_kernel(
    const float* __restrict__ vin, float* __restrict__ dout)
{
    int idx = blockIdx.x*256 + threadIdx.x;
    if (idx >= BATCH*2*HW) return;
    int x = idx & (WW-1);
    int y = (idx >> 9) & (HH-1);
    int c = (idx >> 18) & 1;
    int b = idx >> 19;
    const float* vb = vin + (size_t)(b*2 + c)*HW;
    const float w18 = (float)(1.0/18.0);
    float acc = 0.0f;
    for (int ky = -1; ky <= 1; ++ky) {
        int yy = y + ky;
        if ((unsigned)yy >= HH) continue;
        for (int kx = -1; kx <= 1; ++kx) {
            int xx2 = x + kx;
            if ((unsigned)xx2 >= WW) continue;
            float s = 0.95f * vb[yy*WW + xx2];
            acc += s * w18;
        }
    }
    float sc = 0.95f * vb[y*WW + x];
    float res = acc + sc * 0.5f;
    dout[((size_t)b*20 + 18 + c)*HW + (size_t)(y<<9) + x] = res;
}

__global__ __launch_bounds__(256) void bv_copyvel_kernel(float* __restrict__ dout)
{
    int idx = blockIdx.x*256 + threadIdx.x;
    if (idx >= BATCH*2*HW) return;
    int x = idx & (WW-1);
    int y = (idx >> 9) & (HH-1);
    int c = (idx >> 18) & 1;
    int b = idx >> 19;
    float v = dout[((size_t)b*20 + 18 + c)*HW + (size_t)(y<<9) + x];
    dout[(size_t)BATCH*20*HW + (size_t)idx] = v;
}

extern "C" void kernel_launch(void* const* d_in, const int* in_sizes, int n_in,
                              void* d_out, int out_size, void* d_ws, size_t ws_size,
                              hipStream_t stream)
{
    const float* world_in   = (const float*)d_in[0];
    const float* vel_in     = (const float*)d_in[1];
    const float* elem_empty = (const float*)d_in[2];
    float* out = (float*)d_out;

    // ws: worldA (18ch) | vd1 | bk | M | SB | Src | cnt | tlist
    float* wsA = (float*)d_ws;                                 // 4*18*HW floats
    float* vd1 = wsA + (size_t)BATCH*NCH*HW;                   // 4*2*HW floats
    unsigned char* bk  = (unsigned char*)(vd1 + (size_t)BATCH*2*HW); // BHW
    unsigned char* Mb  = bk + (size_t)BHW;                     // BHW
    unsigned char* SBb = Mb + (size_t)BHW;                     // BHW
    int* Srcb = (int*)(SBb + (size_t)BHW);                     // BHW ints
    unsigned* pcount = (unsigned*)(Srcb + (size_t)BHW);        // 64 B slot
    const unsigned listcap = 1u << 16;                         // 64K entries
    uint2* tlistb = (uint2*)(pcount + 16);                     // 512 KB
    float* vel2 = out + (size_t)BATCH*20*HW;                   // out tail

    dim3 blk(256);
    dim3 grd((BHW + 255)/256);
    dim3 g2((BATCH*2*HW + 255)/256);
    dim3 gA(BATCH*16*16);            // 1024 tile-blocks
    dim3 gB(BHW/4/256, 4);           // 1024 x 4 channel-groups
    dim3 gT(256);                    // tree kernel, grid-stride

    // ---- iteration 1 ----
    bv_bucket_kernel<<<grd, blk, 0, stream>>>(vel_in, bk, pcount);
    bv_mask_kernel<<<gA, dim3(ANT), 0, stream>>>(world_in, 20, wsA, NCH, bk,
                                                 Mb, SBb, Srcb, pcount,
                                                 tlistb, listcap, elem_empty);
    bv_vdelta_kernel<<<grd, blk, 0, stream>>>(Mb, SBb, vel_in, vd1);
    bv_apply_kernel<<<gB, blk, 0, stream>>>(world_in, 20, wsA, NCH, Srcb, Mb, SBb);
    bv_tree_kernel<<<gT, blk, 0, stream>>>(world_in, 20, wsA, NCH, tlistb, pcount,
                                           listcap, Mb, SBb);
    // ---- iteration 2 ----
    bv_bucket_kernel<<<grd, blk, 0, stream>>>(vd1, bk, pcount);
    bv_mask_kernel<<<gA, dim3(ANT), 0, stream>>>(wsA, NCH, out, 20, bk,
                                                 Mb, SBb, Srcb, pcount,
                                                 tlistb, listcap, elem_empty);
    bv_vdelta_kernel<<<grd, blk, 0, stream>>>(Mb, SBb, vd1, vel2);
    bv_apply_kernel<<<gB, blk, 0, stream>>>(wsA, NCH, out, 20, Srcb, Mb, SBb);
    bv_tree_kernel<<<gT, blk, 0, stream>>>(wsA, NCH, out, 20, tlistb, pcount,
                                           listcap, Mb, SBb);
    // ---- epilogue ----
    bv_smooth_kernel<<<g2, blk, 0, stream>>>(vel2, out);
    bv_copyvel_kernel<<<g2, blk, 0, stream>>>(out);
}

// Round 14
// 202.019 us; speedup vs baseline: 8.3258x; 1.2277x over previous
//
#include <hip/hip_runtime.h>
#include <math.h>

#define HH 512
#define WW 512
#define HW (HH*WW)          // 262144
#define BATCH 4
#define NCH 18              // simulated channels (18,19 overwritten at end)
#define BHW (BATCH*HW)

__device__ __constant__ int cDG[8] = {-512,-511,1,513,512,511,-1,-513}; // dy*WW+dx
__device__ __constant__ int cDT[8] = {-48,-47,1,49,48,47,-1,-49};       // dy*ATP+dx

// bucket (3 bits) | enough (bit 3); zeroes list counter
__global__ __launch_bounds__(256) void bv_bucket_kernel(
    const float* __restrict__ vel, unsigned char* __restrict__ bk,
    unsigned* __restrict__ pcount)
{
    int idx = blockIdx.x*256 + threadIdx.x;
    if (idx == 0) { pcount[0] = 0; pcount[1] = 0; }
    if (idx >= BHW) return;
    int b = idx >> 18;
    int rem = idx & (HW-1);
    const float* vb = vel + (size_t)b*2*HW;
    float vy = vb[rem];
    float vx = vb[HW + rem];
    float a2 = vy*vy;
    float b2 = vx*vx;
    float mag = sqrtf(a2 + b2);
    float xx = vx / (mag + 0.001f);
    float af = (float)acos((double)xx);
    const float inv2pi = (float)(1.0/(2.0*3.14159265358979323846));
    float raw = inv2pi * af;
    float ang = (vy < 0.0f) ? (1.0f - raw) : raw;
    float t = ang * 8.0f + 0.5f;
    int bkt = (int)floorf(t);
    bkt &= 7;
    unsigned char e = (mag > 0.1f) ? (unsigned char)8 : (unsigned char)0;
    bk[idx] = (unsigned char)(bkt | e);
}

#define ATP 48
#define ATC (48*48)   // 2304 = 4*512 + 256
#define ANT 512

// ---- Kernel A: fused mask+evolve. COMPOSE=false (iter1): emits plain
//      records (trees = lazy kind-2 marker, no list). COMPOSE=true (iter2):
//      composes with Src1 (final = P2 o P1); tree2 and copy2->tree1 cells
//      go to the compacted list (block-aggregated, 1 global atomic).
//      Kinds: 0=COPY gsrc(world_in); 1=ZERO; 2=tree marker/placeholder;
//      3=list-overflow (unreachable; apply emits 0).
template<bool COMPOSE>
__global__ __launch_bounds__(ANT) void bv_mask_kernel(
    const float* __restrict__ Win, int Cin,
    float* __restrict__ Wout, int Cout,
    const unsigned char* __restrict__ bkall,
    unsigned char* __restrict__ Mg,
    unsigned char* __restrict__ SBg,
    int* __restrict__ SrcOut,
    const int* __restrict__ Src1g,     // COMPOSE only
    unsigned* __restrict__ pcount,     // [1]=tree entries (COMPOSE only)
    uint2* __restrict__ tlist,
    unsigned listcap,
    const float* __restrict__ elem_empty)
{
    __shared__ float A0[ATC], A1[ATC], B0F[ATC], B1F[ATC];   // 36.9 KB
    __shared__ unsigned char KSH[ATC];                       // 2.3 KB
    __shared__ unsigned sCnt[2];   // [0]=list cnt, [1]=list base

    unsigned char* MSHb = (unsigned char*)B0F;               // post-steps M bytes
    unsigned char* SBb  = ((unsigned char*)B0F) + ATC;       // post-steps SB bytes

    const int tid = threadIdx.x;
    const int blk = blockIdx.x;
    const int tx = blk & 15, ty = (blk >> 4) & 15, b = blk >> 8;
    const int x0 = tx*32 - 8, y0 = ty*32 - 8;

    const float* inb  = Win  + (size_t)b*Cin*HW;
    float*       outb = Wout + (size_t)b*Cout*HW;
    const unsigned char* bkb = bkall + ((size_t)b << 18);
    unsigned char* Mob  = Mg  + ((size_t)b << 18);
    unsigned char* SBob = SBg + ((size_t)b << 18);
    int*           Srb  = SrcOut + ((size_t)b << 18);

    const float e0 = elem_empty[0];
    const float e1 = elem_empty[1];

    float v0r[4], v1r[4];
    unsigned kreg[4], mreg[4];
    unsigned mtail = 0;

    if (tid == 0) sCnt[0] = 0;

    // ---- load: LDS + register copies for owned cells ----
    #pragma unroll
    for (int k = 0; k < 4; ++k) {
        int l = tid + (k << 9);
        int ly = l / ATP, lx = l - ly*ATP;
        int gy = y0 + ly, gx = x0 + lx;
        bool in = ((unsigned)gy < HH) && ((unsigned)gx < WW);
        int g = gy*WW + gx;
        float v0 = 0.f, v1 = 0.f; unsigned char kk = 0;
        if (in) { v0 = inb[g]; v1 = inb[HW + g]; kk = bkb[g]; }
        A0[l] = v0; A1[l] = v1; KSH[l] = kk;
        v0r[k] = v0; v1r[k] = v1; kreg[k] = kk; mreg[k] = 0;
    }
    if (tid < 256) {    // tail cells: LDS-resident values, register M
        int l = 2048 + tid;
        int ly = l / ATP, lx = l - ly*ATP;
        int gy = y0 + ly, gx = x0 + lx;
        bool in = ((unsigned)gy < HH) && ((unsigned)gx < WW);
        int g = gy*WW + gx;
        float v0 = 0.f, v1 = 0.f; unsigned char kk = 0;
        if (in) { v0 = inb[g]; v1 = inb[HW + g]; kk = bkb[g]; }
        A0[l] = v0; A1[l] = v1; KSH[l] = kk;
    }
    __syncthreads();

    // ---- 8 fused steps, one barrier each ----
    #pragma unroll
    for (int a = 0; a < 8; ++a) {
        const int doff = cDT[a];
        const unsigned tgt = (unsigned)(a | 8);
        const float* cA0 = (a & 1) ? B0F : A0;
        const float* cA1 = (a & 1) ? B1F : A1;
        float* nA0 = (a & 1) ? A0 : B0F;
        float* nA1 = (a & 1) ? A1 : B1F;
        #pragma unroll
        for (int k = 0; k < 4; ++k) {
            const int l = tid + (k << 9);
            int ln = l + doff; ln = ln < 0 ? 0 : (ln >= ATC ? ATC-1 : ln);
            int lo = l - doff; lo = lo < 0 ? 0 : (lo >= ATC ? ATC-1 : lo);
            float a0l = v0r[k], a1l = v1r[k];
            float a0n = cA0[ln];
            float a0o = cA0[lo], a1o = cA1[lo];
            unsigned ko = KSH[lo];
            bool sal = ((kreg[k] & 15u) == tgt) & (a0n > 0.5f) & !(a1l > 0.5f);
            bool sao = ((ko & 15u) == tgt) & (a0l > 0.5f) & !(a1o > 0.5f);
            mreg[k] |= (sal ? 1u : 0u) << a;
            float sa = sal ? 1.0f : 0.0f;
            float sb = sao ? 1.0f : 0.0f;
            float r0 = a0l - sa*a0l; r0 = r0 - sb*a0l; r0 = r0 + sa*e0; r0 = r0 + sb*a0o;
            float r1 = a1l - sa*a1l; r1 = r1 - sb*a1l; r1 = r1 + sa*e1; r1 = r1 + sb*a1o;
            v0r[k] = r0; v1r[k] = r1;
            nA0[l] = r0; nA1[l] = r1;
        }
        if (tid < 256) {
            const int l = 2048 + tid;
            int ln = l + doff; ln = ln < 0 ? 0 : (ln >= ATC ? ATC-1 : ln);
            int lo = l - doff; lo = lo < 0 ? 0 : (lo >= ATC ? ATC-1 : lo);
            float a0l = cA0[l], a1l = cA1[l];
            float a0n = cA0[ln];
            float a0o = cA0[lo], a1o = cA1[lo];
            unsigned kl = KSH[l], ko = KSH[lo];
            bool sal = ((kl & 15u) == tgt) & (a0n > 0.5f) & !(a1l > 0.5f);
            bool sao = ((ko & 15u) == tgt) & (a0l > 0.5f) & !(a1o > 0.5f);
            if (sal) mtail |= 1u << a;
            float sa = sal ? 1.0f : 0.0f;
            float sb = sao ? 1.0f : 0.0f;
            float r0 = a0l - sa*a0l; r0 = r0 - sb*a0l; r0 = r0 + sa*e0; r0 = r0 + sb*a0o;
            float r1 = a1l - sa*a1l; r1 = r1 - sb*a1l; r1 = r1 + sa*e1; r1 = r1 + sb*a1o;
            nA0[l] = r0; nA1[l] = r1;
        }
        __syncthreads();
    }
    // final ch0/ch1 in A0/A1; B0F/B1F dead -> alias as M/SB byte arrays

    #pragma unroll
    for (int k = 0; k < 4; ++k) MSHb[tid + (k << 9)] = (unsigned char)mreg[k];
    if (tid < 256) MSHb[2048 + tid] = (unsigned char)mtail;
    __syncthreads();

    // SB bits
    for (int l = tid; l < ATC; l += ANT) {
        unsigned sb8 = 0;
        #pragma unroll
        for (int a = 0; a < 8; ++a) {
            int lo = l - cDT[a]; lo = lo < 0 ? 0 : (lo >= ATC ? ATC-1 : lo);
            sb8 |= (unsigned)((MSHb[lo] >> a) & 1) << a;
        }
        SBb[l] = (unsigned char)sb8;
    }
    __syncthreads();

    // ---- pass A: interior writes + provenance walk (+composition) ----
    int tNeed[2]; unsigned tLL[2], tEy[2];
    #pragma unroll
    for (int it = 0; it < 2; ++it) {
        tNeed[it] = 0;
        int li = tid + (it << 9);
        int iy = li >> 5, ix = li & 31;
        int l = (iy + 8)*ATP + ix + 8;
        int gy = ty*32 + iy, gx = tx*32 + ix;
        int g = gy*WW + gx;
        outb[g]      = A0[l];
        outb[HW + g] = A1[l];
        unsigned mm = MSHb[l], sbb = SBb[l];
        Mob[g]  = (unsigned char)mm;
        SBob[g] = (unsigned char)sbb;

        // provenance walk in LDS
        int cc = l, ss = 7, kd = 0;
        unsigned m = mm, sb = sbb;
        while (true) {
            unsigned evt = (m | sb) & ((2u << ss) - 1u);
            if (!evt) { kd = 0; break; }
            int bb = 31 - __builtin_clz(evt);
            int ia = (m >> bb) & 1, ib = (sb >> bb) & 1;
            if (ia && ib) { kd = 2; break; }        // tree at (cc, ss)
            if (ia) { kd = 1; break; }              // e=0 for c>=2 -> ZERO
            cc -= cDT[bb]; ss = bb - 1;             // sb-only: exact value move
            if (ss < 0) { kd = 0; break; }
            m = MSHb[cc]; sb = SBb[cc];
        }
        if (kd == 1) {
            Srb[g] = (int)(1u << 30);
        } else if (kd == 0) {
            int cly = cc / ATP, clx = cc - cly*ATP;
            unsigned s = (unsigned)((y0 + cly)*WW + (x0 + clx));
            if (!COMPOSE) {
                Srb[g] = (int)s;
            } else {
                unsigned r1 = (unsigned)Src1g[((size_t)b << 18) + s];
                unsigned k1 = r1 >> 30;
                if (k1 == 0u)      Srb[g] = (int)r1;        // copy o copy
                else if (k1 == 1u) Srb[g] = (int)(1u << 30);
                else { tNeed[it] = 1; tEy[it] = s; }        // type B: tree1 @ s
            }
        } else {
            if (!COMPOSE) {
                Srb[g] = (int)(2u << 30);   // lazy tree1 marker
            } else {
                int cly = cc / ATP, clx = cc - cly*ATP;
                unsigned ccg = (unsigned)((y0 + cly)*WW + (x0 + clx));
                tNeed[it] = 1;
                tEy[it] = (1u << 31) | ((unsigned)ss << 28) | ccg;   // type A
            }
        }
        if (COMPOSE && tNeed[it]) tLL[it] = atomicAdd(&sCnt[0], 1u);
    }
    if constexpr (COMPOSE) {
        __syncthreads();
        if (tid == 0) sCnt[1] = sCnt[0] ? atomicAdd(&pcount[1], sCnt[0]) : 0u;
        __syncthreads();
        unsigned lbase = sCnt[1];
        #pragma unroll
        for (int it = 0; it < 2; ++it) {
            if (!tNeed[it]) continue;
            int li = tid + (it << 9);
            int iy = li >> 5, ix = li & 31;
            int g = (ty*32 + iy)*WW + tx*32 + ix;
            unsigned lidx = lbase + tLL[it];
            if (lidx < listcap) {
                tlist[lidx] = make_uint2(((unsigned)b << 18) | (unsigned)g, tEy[it]);
                Srb[g] = (int)(2u << 30);           // placeholder
            } else {
                Srb[g] = (int)(3u << 30);           // unreachable (cap 16x margin)
            }
        }
    }
}

// ---- vdelta: own-cell M/SB + velocity; exact per-step op order.
//      Optionally emits next-iteration bucket bytes (exact bucket math on
//      the just-computed vd values) and zeroes the list counter.
__global__ __launch_bounds__(256) void bv_vdelta_kernel(
    const unsigned char* __restrict__ M,
    const unsigned char* __restrict__ SB,
    const float* __restrict__ vel,
    float* __restrict__ vdout,
    unsigned char* __restrict__ bkout,   // nullable
    unsigned* __restrict__ pcount)       // nullable
{
    int idx = blockIdx.x*256 + threadIdx.x;
    if (bkout && idx == 0) pcount[1] = 0;
    if (idx >= BHW) return;
    int b = idx >> 18;
    int g = idx & (HW-1);
    const float* velb = vel   + (size_t)b*2*HW;
    float*       vdb  = vdout + (size_t)b*2*HW;
    unsigned mm  = M[((size_t)b << 18) + g];
    unsigned sbb = SB[((size_t)b << 18) + g];
    float vy = velb[g], vx = velb[HW + g];
    float ddy = vy, ddx = vx;
    unsigned act = mm | sbb;
    if (act) {
        #pragma unroll
        for (int a = 0; a < 8; ++a) {
            if ((act >> a) & 1) {
                float sa = (float)((mm  >> a) & 1);
                float sb = (float)((sbb >> a) & 1);
                float voy = 0.f, vox = 0.f;
                if (sb != 0.f) {
                    int go = g - cDG[a];     // in-image when sb=1
                    voy = velb[go]; vox = velb[HW + go];
                }
                ddy = ddy - (sa*vy)*0.5f; ddy = ddy + (sb*voy)*0.5f;
                ddx = ddx - (sa*vx)*0.5f; ddx = ddx + (sb*vox)*0.5f;
            }
        }
    }
    vdb[g]      = ddy;
    vdb[HW + g] = ddx;
    if (bkout) {
        float a2 = ddy*ddy;
        float b2 = ddx*ddx;
        float mag = sqrtf(a2 + b2);
        float xx = ddx / (mag + 0.001f);
        float af = (float)acos((double)xx);
        const float inv2pi = (float)(1.0/(2.0*3.14159265358979323846));
        float raw = inv2pi * af;
        float ang = (ddy < 0.0f) ? (1.0f - raw) : raw;
        float t = ang * 8.0f + 0.5f;
        int bkt = (int)floorf(t);
        bkt &= 7;
        unsigned char e = (mag > 0.1f) ? (unsigned char)8 : (unsigned char)0;
        bkout[idx] = (unsigned char)(bkt | e);
    }
}

// 4-channel evaluator on (M,SB) with DIRECT leaves (iter1 trees).
__device__ void bv_eval4_direct(int cell, int stp,
    const unsigned char* __restrict__ M,
    const unsigned char* __restrict__ SB,
    const float* __restrict__ i0, const float* __restrict__ i1,
    const float* __restrict__ i2, const float* __restrict__ i3,
    float& r0, float& r1, float& r2, float& r3)
{
    float v0[10], v1[10], v2[10], v3[10]; int vsp = 0;
    int cs_cell[10], cs_stp[10], cs_ph[10]; int csp = 0;
    cs_cell[0] = cell; cs_stp[0] = stp; cs_ph[0] = 0; csp = 1;
    while (csp > 0) {
        int ph = cs_ph[csp-1];
        if (ph == 0) {
            int cc = cs_cell[csp-1], ss = cs_stp[csp-1];
            int have = 0, zero = 0, leaf = 0;
            while (true) {
                if (ss < 0) { leaf = cc; have = 1; break; }
                unsigned m = M[cc], sb = SB[cc];
                unsigned evt = (m | sb) & ((2u << ss) - 1u);
                if (!evt) { leaf = cc; have = 1; break; }
                int bb = 31 - __builtin_clz(evt);
                int ia = (m >> bb) & 1, ib = (sb >> bb) & 1;
                if (ia && ib) {
                    cs_cell[csp-1] = cc; cs_stp[csp-1] = bb; cs_ph[csp-1] = 1;
                    cs_cell[csp] = cc - cDG[bb]; cs_stp[csp] = bb - 1; cs_ph[csp] = 0; csp++;
                    break;
                }
                if (ia) { zero = 1; have = 1; break; }
                cc -= cDG[bb]; ss = bb - 1;
            }
            if (have) {
                if (zero) { v0[vsp]=0.f; v1[vsp]=0.f; v2[vsp]=0.f; v3[vsp]=0.f; }
                else { v0[vsp]=i0[leaf]; v1[vsp]=i1[leaf]; v2[vsp]=i2[leaf]; v3[vsp]=i3[leaf]; }
                vsp++; csp--;
            }
        } else if (ph == 1) {
            cs_ph[csp-1] = 2;
            cs_cell[csp] = cs_cell[csp-1]; cs_stp[csp] = cs_stp[csp-1] - 1;
            cs_ph[csp] = 0; csp++;
        } else {
            vsp--;
            v0[vsp-1] = v0[vsp-1] - v0[vsp];   // fl(wo - w)
            v1[vsp-1] = v1[vsp-1] - v1[vsp];
            v2[vsp-1] = v2[vsp-1] - v2[vsp];
            v3[vsp-1] = v3[vsp-1] - v3[vsp];
            csp--;
        }
    }
    r0 = v0[0]; r1 = v1[0]; r2 = v2[0]; r3 = v3[0];
}

// iter1 value at cell L (walk M1/SB1 from (L,7); rare tree -> eval direct)
__device__ void bv_leaf1_4(int L,
    const unsigned char* __restrict__ M1,
    const unsigned char* __restrict__ SB1,
    const float* __restrict__ i0, const float* __restrict__ i1,
    const float* __restrict__ i2, const float* __restrict__ i3,
    float& l0, float& l1, float& l2, float& l3)
{
    int cc = L, ss = 7;
    while (true) {
        unsigned m = M1[cc], sb = SB1[cc];
        unsigned evt = (m | sb) & ((2u << ss) - 1u);
        if (!evt) break;                        // value = input at cc
        int bb = 31 - __builtin_clz(evt);
        int ia = (m >> bb) & 1, ib = (sb >> bb) & 1;
        if (ia && ib) {                         // tree1 at (cc, bb)
            bv_eval4_direct(cc, bb, M1, SB1, i0, i1, i2, i3, l0, l1, l2, l3);
            return;
        }
        if (ia) { l0 = 0.f; l1 = 0.f; l2 = 0.f; l3 = 0.f; return; }
        cc -= cDG[bb]; ss = bb - 1;
        if (ss < 0) break;                      // value = input at cc
    }
    l0 = i0[cc]; l1 = i1[cc]; l2 = i2[cc]; l3 = i3[cc];
}

// 4-channel evaluator on (M2,SB2) with leaves INDIRECTED through iter1.
__device__ void bv_eval4_ind(int cell, int stp,
    const unsigned char* __restrict__ M2,
    const unsigned char* __restrict__ SB2,
    const unsigned char* __restrict__ M1,
    const unsigned char* __restrict__ SB1,
    const float* __restrict__ i0, const float* __restrict__ i1,
    const float* __restrict__ i2, const float* __restrict__ i3,
    float& r0, float& r1, float& r2, float& r3)
{
    float v0[10], v1[10], v2[10], v3[10]; int vsp = 0;
    int cs_cell[10], cs_stp[10], cs_ph[10]; int csp = 0;
    cs_cell[0] = cell; cs_stp[0] = stp; cs_ph[0] = 0; csp = 1;
    while (csp > 0) {
        int ph = cs_ph[csp-1];
        if (ph == 0) {
            int cc = cs_cell[csp-1], ss = cs_stp[csp-1];
            int have = 0, zero = 0, leaf = 0;
            while (true) {
                if (ss < 0) { leaf = cc; have = 1; break; }
                unsigned m = M2[cc], sb = SB2[cc];
                unsigned evt = (m | sb) & ((2u << ss) - 1u);
                if (!evt) { leaf = cc; have = 1; break; }
                int bb = 31 - __builtin_clz(evt);
                int ia = (m >> bb) & 1, ib = (sb >> bb) & 1;
                if (ia && ib) {
                    cs_cell[csp-1] = cc; cs_stp[csp-1] = bb; cs_ph[csp-1] = 1;
                    cs_cell[csp] = cc - cDG[bb]; cs_stp[csp] = bb - 1; cs_ph[csp] = 0; csp++;
                    break;
                }
                if (ia) { zero = 1; have = 1; break; }
                cc -= cDG[bb]; ss = bb - 1;
            }
            if (have) {
                if (zero) { v0[vsp]=0.f; v1[vsp]=0.f; v2[vsp]=0.f; v3[vsp]=0.f; }
                else bv_leaf1_4(leaf, M1, SB1, i0, i1, i2, i3,
                                v0[vsp], v1[vsp], v2[vsp], v3[vsp]);
                vsp++; csp--;
            }
        } else if (ph == 1) {
            cs_ph[csp-1] = 2;
            cs_cell[csp] = cs_cell[csp-1]; cs_stp[csp] = cs_stp[csp-1] - 1;
            cs_ph[csp] = 0; csp++;
        } else {
            vsp--;
            v0[vsp-1] = v0[vsp-1] - v0[vsp];
            v1[vsp-1] = v1[vsp-1] - v1[vsp];
            v2[vsp-1] = v2[vsp-1] - v2[vsp];
            v3[vsp-1] = v3[vsp-1] - v3[vsp];
            csp--;
        }
    }
    r0 = v0[0]; r1 = v1[0]; r2 = v2[0]; r3 = v3[0];
}

// ---- Kernel B: apply composed provenance world_in -> out (single pass).
__global__ __launch_bounds__(256) void bv_apply_kernel(
    const float* __restrict__ Win, int Cin,
    float* __restrict__ Wout, int Cout,
    const int* __restrict__ Src)
{
    int t = blockIdx.x*256 + threadIdx.x;   // over BHW/4
    if (t >= BHW/4) return;
    const int c0 = 2 + blockIdx.y*4;        // channel group [c0, c0+4)
    int p = t << 2;
    int b = p >> 18;
    int own = p & (HW-1);
    const float* inb  = Win  + (size_t)b*Cin*HW;
    float*       outb = Wout + (size_t)b*Cout*HW;
    const int* Srb = Src + ((size_t)b << 18);

    int4 s4 = *(const int4*)(Srb + own);
    unsigned sv[4] = {(unsigned)s4.x, (unsigned)s4.y, (unsigned)s4.z, (unsigned)s4.w};
    int kind[4], idx[4]; bool need[4];
    bool allself = true;
    #pragma unroll
    for (int j = 0; j < 4; ++j) {
        kind[j] = (int)(sv[j] >> 30);
        idx[j]  = (int)(sv[j] & 0x3FFFFu);
        need[j] = (kind[j] != 0) || (idx[j] != own + j);
        allself = allself && !need[j];
    }

    if (allself) {
        #pragma unroll
        for (int c = 0; c < 4; ++c) {
            float4 v = *(const float4*)(inb + (size_t)(c0 + c)*HW + own);
            *(float4*)(outb + (size_t)(c0 + c)*HW + own) = v;
        }
        return;
    }
    #pragma unroll
    for (int c = 0; c < 4; ++c) {
        const float* ic = inb + (size_t)(c0 + c)*HW;
        float4 v = *(const float4*)(ic + own);
        float r[4] = {v.x, v.y, v.z, v.w};
        #pragma unroll
        for (int j = 0; j < 4; ++j) {
            if (need[j])
                r[j] = (kind[j] == 0) ? ic[idx[j]] : 0.0f;  // 1/2/3 -> 0 (tree overwrites)
        }
        *(float4*)(outb + (size_t)(c0 + c)*HW + own) = make_float4(r[0], r[1], r[2], r[3]);
    }
}

// ---- Kernel C: composed tree cells; thread per (entry, channel-group).
//      Type A (e.y bit31): tree2 at (cc,ss) on M2/SB2, leaves via iter1.
//      Type B: value = iter1 output at cell s (walk M1/SB1).
__global__ __launch_bounds__(256) void bv_tree_kernel(
    const float* __restrict__ Win,       // world_in, 20-ch
    float* __restrict__ Wout,            // out, 20-ch
    const uint2* __restrict__ tlist,
    const unsigned* __restrict__ pcount, // [1] = entry count
    unsigned listcap,
    const unsigned char* __restrict__ M1,
    const unsigned char* __restrict__ SB1,
    const unsigned char* __restrict__ M2,
    const unsigned char* __restrict__ SB2)
{
    unsigned n = pcount[1]; if (n > listcap) n = listcap;
    unsigned total = n * 4;
    for (unsigned i = blockIdx.x*256 + threadIdx.x; i < total; i += gridDim.x*256) {
        unsigned ei = i >> 2; int grp = (int)(i & 3);
        uint2 e = tlist[ei];
        int b = (int)((e.x >> 18) & 3u);
        int g = (int)(e.x & 0x3FFFFu);
        const float* inb  = Win  + (size_t)b*20*HW;
        float*       outb = Wout + (size_t)b*20*HW;
        const unsigned char* M1b  = M1  + ((size_t)b << 18);
        const unsigned char* SB1b = SB1 + ((size_t)b << 18);
        int c0 = 2 + grp*4;
        const float* i0 = inb + (size_t)c0*HW;
        const float* i1 = i0 + HW;
        const float* i2 = i1 + HW;
        const float* i3 = i2 + HW;
        float r0, r1, r2, r3;
        if (e.y >> 31) {        // type A: tree2
            int cc = (int)(e.y & 0x3FFFFu);
            int ss = (int)((e.y >> 28) & 7u);
            const unsigned char* M2b  = M2  + ((size_t)b << 18);
            const unsigned char* SB2b = SB2 + ((size_t)b << 18);
            bv_eval4_ind(cc, ss, M2b, SB2b, M1b, SB1b, i0, i1, i2, i3, r0, r1, r2, r3);
        } else {                // type B: iter1 value at s
            int s = (int)(e.y & 0x3FFFFu);
            bv_leaf1_4(s, M1b, SB1b, i0, i1, i2, i3, r0, r1, r2, r3);
        }
        outb[(size_t)(c0 + 0)*HW + g] = r0;
        outb[(size_t)(c0 + 1)*HW + g] = r1;
        outb[(size_t)(c0 + 2)*HW + g] = r2;
        outb[(size_t)(c0 + 3)*HW + g] = r3;
    }
}

// smooth(0.95*v): conv3x3(ones/18, zero-pad) + center*0.5
// -> world ch18,19 AND velocity tail (fused copy; vin is a ws buffer).
__global__ __launch_bounds__(256) void bv_smooth_kernel(
    const float* __restrict__ vin, float* __restrict__ dout)
{
    int idx = blockIdx.x*256 + threadIdx.x;
    if (idx >= BATCH*2*HW) return;
    int x = idx & (WW-1);
    int y = (idx >> 9) & (HH-1);
    int c = (idx >> 18) & 1;
    int b = idx >> 19;
    const float* vb = vin + (size_t)(b*2 + c)*HW;
    const float w18 = (float)(1.0/18.0);
    float acc = 0.0f;
    for (int ky = -1; ky <= 1; ++ky) {
        int yy = y + ky;
        if ((unsigned)yy >= HH) continue;
        for (int kx = -1; kx <= 1; ++kx) {
            int xx2 = x + kx;
            if ((unsigned)xx2 >= WW) continue;
            float s = 0.95f * vb[yy*WW + xx2];
            acc += s * w18;
        }
    }
    float sc = 0.95f * vb[y*WW + x];
    float res = acc + sc * 0.5f;
    dout[((size_t)b*20 + 18 + c)*HW + (size_t)(y<<9) + x] = res;
    dout[(size_t)BATCH*20*HW + (size_t)idx] = res;
}

extern "C" void kernel_launch(void* const* d_in, const int* in_sizes, int n_in,
                              void* d_out, int out_size, void* d_ws, size_t ws_size,
                              hipStream_t stream)
{
    const float* world_in   = (const float*)d_in[0];
    const float* vel_in     = (const float*)d_in[1];
    const float* elem_empty = (const float*)d_in[2];
    float* out = (float*)d_out;

    // ws (~39 MB): w01 | vd1 | vel2 | bk | M1 | SB1 | M2 | SB2 | Src1 | Src2 | cnt | tlist
    float* w01  = (float*)d_ws;                                // 4*2*HW floats
    float* vd1  = w01 + (size_t)BATCH*2*HW;
    float* vel2 = vd1 + (size_t)BATCH*2*HW;
    unsigned char* bk  = (unsigned char*)(vel2 + (size_t)BATCH*2*HW);
    unsigned char* M1  = bk  + (size_t)BHW;
    unsigned char* SB1 = M1  + (size_t)BHW;
    unsigned char* M2  = SB1 + (size_t)BHW;
    unsigned char* SB2 = M2  + (size_t)BHW;
    int* Src1 = (int*)(SB2 + (size_t)BHW);
    int* Src2 = Src1 + (size_t)BHW;
    unsigned* pcount = (unsigned*)(Src2 + (size_t)BHW);
    uint2* tlistb = (uint2*)(pcount + 16);
    const unsigned listcap = 1u << 18;                         // 256K entries, 2 MB

    dim3 blk(256);
    dim3 grd((BHW + 255)/256);
    dim3 g2((BATCH*2*HW + 255)/256);
    dim3 gA(BATCH*16*16);            // 1024 tile-blocks
    dim3 gB(BHW/4/256, 4);           // 1024 x 4 channel-groups
    dim3 gT(256);                    // tree kernel, grid-stride

    // iter1 masks (bucket on vel_in; evolve ch0/1 world_in -> w01)
    bv_bucket_kernel<<<grd, blk, 0, stream>>>(vel_in, bk, pcount);
    bv_mask_kernel<false><<<gA, dim3(ANT), 0, stream>>>(
        world_in, 20, w01, 2, bk, M1, SB1, Src1,
        (const int*)nullptr, pcount, (uint2*)nullptr, 0u, elem_empty);
    // vdelta1 -> vd1; fused bucket2 -> bk; zeroes list counter
    bv_vdelta_kernel<<<grd, blk, 0, stream>>>(M1, SB1, vel_in, vd1, bk, pcount);
    // iter2 masks (evolve ch0/1 w01 -> out; compose Src2 = P2 o P1)
    bv_mask_kernel<true><<<gA, dim3(ANT), 0, stream>>>(
        w01, 2, out, 20, bk, M2, SB2, Src2,
        Src1, pcount, tlistb, listcap, elem_empty);
    // vdelta2 -> vel2 (ws)
    bv_vdelta_kernel<<<grd, blk, 0, stream>>>(M2, SB2, vd1, vel2,
                                              (unsigned char*)nullptr,
                                              (unsigned*)nullptr);
    // passive channels: single composed gather pass + rare tree overwrite
    bv_apply_kernel<<<gB, blk, 0, stream>>>(world_in, 20, out, 20, Src2);
    bv_tree_kernel<<<gT, blk, 0, stream>>>(world_in, out, tlistb, pcount,
                                           listcap, M1, SB1, M2, SB2);
    // epilogue: smoothed velocity -> ch18/19 + tail
    bv_smooth_kernel<<<g2, blk, 0, stream>>>(vel2, out);
}

// Round 15
// 184.670 us; speedup vs baseline: 9.1080x; 1.0939x over previous
//
#include <hip/hip_runtime.h>
#include <math.h>

#define HH 512
#define WW 512
#define HW (HH*WW)          // 262144
#define BATCH 4
#define NCH 18              // simulated channels (18,19 overwritten at end)
#define BHW (BATCH*HW)

__device__ __constant__ int cDG[8] = {-512,-511,1,513,512,511,-1,-513}; // dy*WW+dx
__device__ __constant__ int cDT[8] = {-48,-47,1,49,48,47,-1,-49};       // dy*ATP+dx

// bucket (3 bits) | enough (bit 3); zeroes list counter
__global__ __launch_bounds__(256) void bv_bucket_kernel(
    const float* __restrict__ vel, unsigned char* __restrict__ bk,
    unsigned* __restrict__ pcount)
{
    int idx = blockIdx.x*256 + threadIdx.x;
    if (idx == 0) { pcount[0] = 0; pcount[1] = 0; }
    if (idx >= BHW) return;
    int b = idx >> 18;
    int rem = idx & (HW-1);
    const float* vb = vel + (size_t)b*2*HW;
    float vy = vb[rem];
    float vx = vb[HW + rem];
    float a2 = vy*vy;
    float b2 = vx*vx;
    float mag = sqrtf(a2 + b2);
    float xx = vx / (mag + 0.001f);
    float af = (float)acos((double)xx);
    const float inv2pi = (float)(1.0/(2.0*3.14159265358979323846));
    float raw = inv2pi * af;
    float ang = (vy < 0.0f) ? (1.0f - raw) : raw;
    float t = ang * 8.0f + 0.5f;
    int bkt = (int)floorf(t);
    bkt &= 7;
    unsigned char e = (mag > 0.1f) ? (unsigned char)8 : (unsigned char)0;
    bk[idx] = (unsigned char)(bkt | e);
}

#define ATP 48
#define ATC (48*48)   // 2304 = 4*512 + 256
#define ANT 512
#define PAD 49        // max |doff|; pads replace index clamps

// ---- Kernel A: fused mask+evolve with PADDED LDS (no index clamps ->
//      immediate-offset ds_read). Pad garbage only reaches ring-0 rim
//      cells, never consumed (validity cone) -> outputs deterministic.
//      COMPOSE=false (iter1): plain records. COMPOSE=true (iter2):
//      composes with Src1; trees to compacted list (1 global atomic).
template<bool COMPOSE>
__global__ __launch_bounds__(ANT) void bv_mask_kernel(
    const float* __restrict__ Win, int Cin,
    float* __restrict__ Wout, int Cout,
    const unsigned char* __restrict__ bkall,
    unsigned char* __restrict__ Mg,
    unsigned char* __restrict__ SBg,
    int* __restrict__ SrcOut,
    const int* __restrict__ Src1g,     // COMPOSE only
    unsigned* __restrict__ pcount,     // [1]=tree entries (COMPOSE only)
    uint2* __restrict__ tlist,
    unsigned listcap,
    const float* __restrict__ elem_empty)
{
    // carve: A0|A1|B0|B1 (2402 floats each) | KSH (2402 B) | sCnt
    __shared__ __align__(16) unsigned char SHM[40864];
    float* A0  = ((float*)(SHM +     0)) + PAD;
    float* A1  = ((float*)(SHM +  9608)) + PAD;
    float* B0F = ((float*)(SHM + 19216)) + PAD;
    float* B1F = ((float*)(SHM + 28824)) + PAD;
    unsigned char* KSH = SHM + 38432 + PAD;
    unsigned* sCnt = (unsigned*)(SHM + 40840);

    unsigned char* MSHb = SHM + 19216 + PAD;   // post-steps M bytes (B0F dead)
    unsigned char* SBb  = SHM + 28824 + PAD;   // post-steps SB bytes (B1F dead)

    const int tid = threadIdx.x;
    const int blk = blockIdx.x;
    const int tx = blk & 15, ty = (blk >> 4) & 15, b = blk >> 8;
    const int x0 = tx*32 - 8, y0 = ty*32 - 8;

    const float* inb  = Win  + (size_t)b*Cin*HW;
    float*       outb = Wout + (size_t)b*Cout*HW;
    const unsigned char* bkb = bkall + ((size_t)b << 18);
    unsigned char* Mob  = Mg  + ((size_t)b << 18);
    unsigned char* SBob = SBg + ((size_t)b << 18);
    int*           Srb  = SrcOut + ((size_t)b << 18);

    const float e0 = elem_empty[0];
    const float e1 = elem_empty[1];

    float v0r[4], v1r[4];
    unsigned kreg[4], mreg[4];
    unsigned mtail = 0;

    if (tid == 0) sCnt[0] = 0;

    // ---- load: LDS + register copies for owned cells ----
    #pragma unroll
    for (int k = 0; k < 4; ++k) {
        int l = tid + (k << 9);
        int ly = l / ATP, lx = l - ly*ATP;
        int gy = y0 + ly, gx = x0 + lx;
        bool in = ((unsigned)gy < HH) && ((unsigned)gx < WW);
        int g = gy*WW + gx;
        float v0 = 0.f, v1 = 0.f; unsigned char kk = 0;
        if (in) { v0 = inb[g]; v1 = inb[HW + g]; kk = bkb[g]; }
        A0[l] = v0; A1[l] = v1; KSH[l] = kk;
        v0r[k] = v0; v1r[k] = v1; kreg[k] = kk; mreg[k] = 0;
    }
    if (tid < 256) {    // tail cells: LDS-resident values, register M
        int l = 2048 + tid;
        int ly = l / ATP, lx = l - ly*ATP;
        int gy = y0 + ly, gx = x0 + lx;
        bool in = ((unsigned)gy < HH) && ((unsigned)gx < WW);
        int g = gy*WW + gx;
        float v0 = 0.f, v1 = 0.f; unsigned char kk = 0;
        if (in) { v0 = inb[g]; v1 = inb[HW + g]; kk = bkb[g]; }
        A0[l] = v0; A1[l] = v1; KSH[l] = kk;
    }
    __syncthreads();

    // ---- 8 fused steps, one barrier each; unclamped padded access ----
    #pragma unroll
    for (int a = 0; a < 8; ++a) {
        const int doff = cDT[a];
        const unsigned tgt = (unsigned)(a | 8);
        const float* cA0 = (a & 1) ? B0F : A0;
        const float* cA1 = (a & 1) ? B1F : A1;
        float* nA0 = (a & 1) ? A0 : B0F;
        float* nA1 = (a & 1) ? A1 : B1F;
        #pragma unroll
        for (int k = 0; k < 4; ++k) {
            const int l = tid + (k << 9);
            const int ln = l + doff;
            const int lo = l - doff;
            float a0l = v0r[k], a1l = v1r[k];
            float a0n = cA0[ln];
            float a0o = cA0[lo], a1o = cA1[lo];
            unsigned ko = KSH[lo];
            bool sal = ((kreg[k] & 15u) == tgt) & (a0n > 0.5f) & !(a1l > 0.5f);
            bool sao = ((ko & 15u) == tgt) & (a0l > 0.5f) & !(a1o > 0.5f);
            mreg[k] |= (sal ? 1u : 0u) << a;
            float sa = sal ? 1.0f : 0.0f;
            float sb = sao ? 1.0f : 0.0f;
            float r0 = a0l - sa*a0l; r0 = r0 - sb*a0l; r0 = r0 + sa*e0; r0 = r0 + sb*a0o;
            float r1 = a1l - sa*a1l; r1 = r1 - sb*a1l; r1 = r1 + sa*e1; r1 = r1 + sb*a1o;
            v0r[k] = r0; v1r[k] = r1;
            nA0[l] = r0; nA1[l] = r1;
        }
        if (tid < 256) {
            const int l = 2048 + tid;
            const int ln = l + doff;
            const int lo = l - doff;
            float a0l = cA0[l], a1l = cA1[l];
            float a0n = cA0[ln];
            float a0o = cA0[lo], a1o = cA1[lo];
            unsigned kl = KSH[l], ko = KSH[lo];
            bool sal = ((kl & 15u) == tgt) & (a0n > 0.5f) & !(a1l > 0.5f);
            bool sao = ((ko & 15u) == tgt) & (a0l > 0.5f) & !(a1o > 0.5f);
            if (sal) mtail |= 1u << a;
            float sa = sal ? 1.0f : 0.0f;
            float sb = sao ? 1.0f : 0.0f;
            float r0 = a0l - sa*a0l; r0 = r0 - sb*a0l; r0 = r0 + sa*e0; r0 = r0 + sb*a0o;
            float r1 = a1l - sa*a1l; r1 = r1 - sb*a1l; r1 = r1 + sa*e1; r1 = r1 + sb*a1o;
            nA0[l] = r0; nA1[l] = r1;
        }
        __syncthreads();
    }
    // final ch0/ch1 in A0/A1; B0F/B1F dead -> M/SB byte arrays

    #pragma unroll
    for (int k = 0; k < 4; ++k) MSHb[tid + (k << 9)] = (unsigned char)mreg[k];
    if (tid < 256) MSHb[2048 + tid] = (unsigned char)mtail;
    __syncthreads();

    // SB bits (padded MSHb read, no clamps)
    for (int l = tid; l < ATC; l += ANT) {
        unsigned sb8 = 0;
        #pragma unroll
        for (int a = 0; a < 8; ++a) {
            int lo = l - cDT[a];
            sb8 |= (unsigned)((MSHb[lo] >> a) & 1) << a;
        }
        SBb[l] = (unsigned char)sb8;
    }
    __syncthreads();

    // ---- pass A: interior writes + provenance walk (+composition) ----
    int tNeed[2]; unsigned tLL[2], tEy[2];
    #pragma unroll
    for (int it = 0; it < 2; ++it) {
        tNeed[it] = 0;
        int li = tid + (it << 9);
        int iy = li >> 5, ix = li & 31;
        int l = (iy + 8)*ATP + ix + 8;
        int gy = ty*32 + iy, gx = tx*32 + ix;
        int g = gy*WW + gx;
        outb[g]      = A0[l];
        outb[HW + g] = A1[l];
        unsigned mm = MSHb[l], sbb = SBb[l];
        Mob[g]  = (unsigned char)mm;
        SBob[g] = (unsigned char)sbb;

        // provenance walk in LDS (in-tile by ring invariant)
        int cc = l, ss = 7, kd = 0;
        unsigned m = mm, sb = sbb;
        while (true) {
            unsigned evt = (m | sb) & ((2u << ss) - 1u);
            if (!evt) { kd = 0; break; }
            int bb = 31 - __builtin_clz(evt);
            int ia = (m >> bb) & 1, ib = (sb >> bb) & 1;
            if (ia && ib) { kd = 2; break; }        // tree at (cc, ss)
            if (ia) { kd = 1; break; }              // e=0 for c>=2 -> ZERO
            cc -= cDT[bb]; ss = bb - 1;             // sb-only: exact value move
            if (ss < 0) { kd = 0; break; }
            m = MSHb[cc]; sb = SBb[cc];
        }
        if (kd == 1) {
            Srb[g] = (int)(1u << 30);
        } else if (kd == 0) {
            int cly = cc / ATP, clx = cc - cly*ATP;
            unsigned s = (unsigned)((y0 + cly)*WW + (x0 + clx));
            if (!COMPOSE) {
                Srb[g] = (int)s;
            } else {
                unsigned r1 = (unsigned)Src1g[((size_t)b << 18) + s];
                unsigned k1 = r1 >> 30;
                if (k1 == 0u)      Srb[g] = (int)r1;        // copy o copy
                else if (k1 == 1u) Srb[g] = (int)(1u << 30);
                else { tNeed[it] = 1; tEy[it] = s; }        // type B: tree1 @ s
            }
        } else {
            if (!COMPOSE) {
                Srb[g] = (int)(2u << 30);   // lazy tree1 marker
            } else {
                int cly = cc / ATP, clx = cc - cly*ATP;
                unsigned ccg = (unsigned)((y0 + cly)*WW + (x0 + clx));
                tNeed[it] = 1;
                tEy[it] = (1u << 31) | ((unsigned)ss << 28) | ccg;   // type A
            }
        }
        if (COMPOSE && tNeed[it]) tLL[it] = atomicAdd(&sCnt[0], 1u);
    }
    if constexpr (COMPOSE) {
        __syncthreads();
        if (tid == 0) sCnt[1] = sCnt[0] ? atomicAdd(&pcount[1], sCnt[0]) : 0u;
        __syncthreads();
        unsigned lbase = sCnt[1];
        #pragma unroll
        for (int it = 0; it < 2; ++it) {
            if (!tNeed[it]) continue;
            int li = tid + (it << 9);
            int iy = li >> 5, ix = li & 31;
            int g = (ty*32 + iy)*WW + tx*32 + ix;
            unsigned lidx = lbase + tLL[it];
            if (lidx < listcap) {
                tlist[lidx] = make_uint2(((unsigned)b << 18) | (unsigned)g, tEy[it]);
                Srb[g] = (int)(2u << 30);           // placeholder
            } else {
                Srb[g] = (int)(3u << 30);           // unreachable (cap 16x margin)
            }
        }
    }
}

// ---- vdelta: own-cell M/SB + velocity; exact per-step op order.
//      Optionally emits next-iteration bucket bytes and zeroes list counter.
__global__ __launch_bounds__(256) void bv_vdelta_kernel(
    const unsigned char* __restrict__ M,
    const unsigned char* __restrict__ SB,
    const float* __restrict__ vel,
    float* __restrict__ vdout,
    unsigned char* __restrict__ bkout,   // nullable
    unsigned* __restrict__ pcount)       // nullable
{
    int idx = blockIdx.x*256 + threadIdx.x;
    if (bkout && idx == 0) pcount[1] = 0;
    if (idx >= BHW) return;
    int b = idx >> 18;
    int g = idx & (HW-1);
    const float* velb = vel   + (size_t)b*2*HW;
    float*       vdb  = vdout + (size_t)b*2*HW;
    unsigned mm  = M[((size_t)b << 18) + g];
    unsigned sbb = SB[((size_t)b << 18) + g];
    float vy = velb[g], vx = velb[HW + g];
    float ddy = vy, ddx = vx;
    unsigned act = mm | sbb;
    if (act) {
        #pragma unroll
        for (int a = 0; a < 8; ++a) {
            if ((act >> a) & 1) {
                float sa = (float)((mm  >> a) & 1);
                float sb = (float)((sbb >> a) & 1);
                float voy = 0.f, vox = 0.f;
                if (sb != 0.f) {
                    int go = g - cDG[a];     // in-image when sb=1
                    voy = velb[go]; vox = velb[HW + go];
                }
                ddy = ddy - (sa*vy)*0.5f; ddy = ddy + (sb*voy)*0.5f;
                ddx = ddx - (sa*vx)*0.5f; ddx = ddx + (sb*vox)*0.5f;
            }
        }
    }
    vdb[g]      = ddy;
    vdb[HW + g] = ddx;
    if (bkout) {
        float a2 = ddy*ddy;
        float b2 = ddx*ddx;
        float mag = sqrtf(a2 + b2);
        float xx = ddx / (mag + 0.001f);
        float af = (float)acos((double)xx);
        const float inv2pi = (float)(1.0/(2.0*3.14159265358979323846));
        float raw = inv2pi * af;
        float ang = (ddy < 0.0f) ? (1.0f - raw) : raw;
        float t = ang * 8.0f + 0.5f;
        int bkt = (int)floorf(t);
        bkt &= 7;
        unsigned char e = (mag > 0.1f) ? (unsigned char)8 : (unsigned char)0;
        bkout[idx] = (unsigned char)(bkt | e);
    }
}

// 4-channel evaluator on (M,SB) with DIRECT leaves (iter1 trees).
__device__ void bv_eval4_direct(int cell, int stp,
    const unsigned char* __restrict__ M,
    const unsigned char* __restrict__ SB,
    const float* __restrict__ i0, const float* __restrict__ i1,
    const float* __restrict__ i2, const float* __restrict__ i3,
    float& r0, float& r1, float& r2, float& r3)
{
    float v0[10], v1[10], v2[10], v3[10]; int vsp = 0;
    int cs_cell[10], cs_stp[10], cs_ph[10]; int csp = 0;
    cs_cell[0] = cell; cs_stp[0] = stp; cs_ph[0] = 0; csp = 1;
    while (csp > 0) {
        int ph = cs_ph[csp-1];
        if (ph == 0) {
            int cc = cs_cell[csp-1], ss = cs_stp[csp-1];
            int have = 0, zero = 0, leaf = 0;
            while (true) {
                if (ss < 0) { leaf = cc; have = 1; break; }
                unsigned m = M[cc], sb = SB[cc];
                unsigned evt = (m | sb) & ((2u << ss) - 1u);
                if (!evt) { leaf = cc; have = 1; break; }
                int bb = 31 - __builtin_clz(evt);
                int ia = (m >> bb) & 1, ib = (sb >> bb) & 1;
                if (ia && ib) {
                    cs_cell[csp-1] = cc; cs_stp[csp-1] = bb; cs_ph[csp-1] = 1;
                    cs_cell[csp] = cc - cDG[bb]; cs_stp[csp] = bb - 1; cs_ph[csp] = 0; csp++;
                    break;
                }
                if (ia) { zero = 1; have = 1; break; }
                cc -= cDG[bb]; ss = bb - 1;
            }
            if (have) {
                if (zero) { v0[vsp]=0.f; v1[vsp]=0.f; v2[vsp]=0.f; v3[vsp]=0.f; }
                else { v0[vsp]=i0[leaf]; v1[vsp]=i1[leaf]; v2[vsp]=i2[leaf]; v3[vsp]=i3[leaf]; }
                vsp++; csp--;
            }
        } else if (ph == 1) {
            cs_ph[csp-1] = 2;
            cs_cell[csp] = cs_cell[csp-1]; cs_stp[csp] = cs_stp[csp-1] - 1;
            cs_ph[csp] = 0; csp++;
        } else {
            vsp--;
            v0[vsp-1] = v0[vsp-1] - v0[vsp];   // fl(wo - w)
            v1[vsp-1] = v1[vsp-1] - v1[vsp];
            v2[vsp-1] = v2[vsp-1] - v2[vsp];
            v3[vsp-1] = v3[vsp-1] - v3[vsp];
            csp--;
        }
    }
    r0 = v0[0]; r1 = v1[0]; r2 = v2[0]; r3 = v3[0];
}

// iter1 value at cell L (walk M1/SB1 from (L,7); rare tree -> eval direct)
__device__ void bv_leaf1_4(int L,
    const unsigned char* __restrict__ M1,
    const unsigned char* __restrict__ SB1,
    const float* __restrict__ i0, const float* __restrict__ i1,
    const float* __restrict__ i2, const float* __restrict__ i3,
    float& l0, float& l1, float& l2, float& l3)
{
    int cc = L, ss = 7;
    while (true) {
        unsigned m = M1[cc], sb = SB1[cc];
        unsigned evt = (m | sb) & ((2u << ss) - 1u);
        if (!evt) break;                        // value = input at cc
        int bb = 31 - __builtin_clz(evt);
        int ia = (m >> bb) & 1, ib = (sb >> bb) & 1;
        if (ia && ib) {                         // tree1 at (cc, bb)
            bv_eval4_direct(cc, bb, M1, SB1, i0, i1, i2, i3, l0, l1, l2, l3);
            return;
        }
        if (ia) { l0 = 0.f; l1 = 0.f; l2 = 0.f; l3 = 0.f; return; }
        cc -= cDG[bb]; ss = bb - 1;
        if (ss < 0) break;                      // value = input at cc
    }
    l0 = i0[cc]; l1 = i1[cc]; l2 = i2[cc]; l3 = i3[cc];
}

// 4-channel evaluator on (M2,SB2) with leaves INDIRECTED through iter1.
__device__ void bv_eval4_ind(int cell, int stp,
    const unsigned char* __restrict__ M2,
    const unsigned char* __restrict__ SB2,
    const unsigned char* __restrict__ M1,
    const unsigned char* __restrict__ SB1,
    const float* __restrict__ i0, const float* __restrict__ i1,
    const float* __restrict__ i2, const float* __restrict__ i3,
    float& r0, float& r1, float& r2, float& r3)
{
    float v0[10], v1[10], v2[10], v3[10]; int vsp = 0;
    int cs_cell[10], cs_stp[10], cs_ph[10]; int csp = 0;
    cs_cell[0] = cell; cs_stp[0] = stp; cs_ph[0] = 0; csp = 1;
    while (csp > 0) {
        int ph = cs_ph[csp-1];
        if (ph == 0) {
            int cc = cs_cell[csp-1], ss = cs_stp[csp-1];
            int have = 0, zero = 0, leaf = 0;
            while (true) {
                if (ss < 0) { leaf = cc; have = 1; break; }
                unsigned m = M2[cc], sb = SB2[cc];
                unsigned evt = (m | sb) & ((2u << ss) - 1u);
                if (!evt) { leaf = cc; have = 1; break; }
                int bb = 31 - __builtin_clz(evt);
                int ia = (m >> bb) & 1, ib = (sb >> bb) & 1;
                if (ia && ib) {
                    cs_cell[csp-1] = cc; cs_stp[csp-1] = bb; cs_ph[csp-1] = 1;
                    cs_cell[csp] = cc - cDG[bb]; cs_stp[csp] = bb - 1; cs_ph[csp] = 0; csp++;
                    break;
                }
                if (ia) { zero = 1; have = 1; break; }
                cc -= cDG[bb]; ss = bb - 1;
            }
            if (have) {
                if (zero) { v0[vsp]=0.f; v1[vsp]=0.f; v2[vsp]=0.f; v3[vsp]=0.f; }
                else bv_leaf1_4(leaf, M1, SB1, i0, i1, i2, i3,
                                v0[vsp], v1[vsp], v2[vsp], v3[vsp]);
                vsp++; csp--;
            }
        } else if (ph == 1) {
            cs_ph[csp-1] = 2;
            cs_cell[csp] = cs_cell[csp-1]; cs_stp[csp] = cs_stp[csp-1] - 1;
            cs_ph[csp] = 0; csp++;
        } else {
            vsp--;
            v0[vsp-1] = v0[vsp-1] - v0[vsp];
            v1[vsp-1] = v1[vsp-1] - v1[vsp];
            v2[vsp-1] = v2[vsp-1] - v2[vsp];
            v3[vsp-1] = v3[vsp-1] - v3[vsp];
            csp--;
        }
    }
    r0 = v0[0]; r1 = v1[0]; r2 = v2[0]; r3 = v3[0];
}

// ---- Kernel B: apply composed provenance world_in -> out.
//      8 pixels/thread (2x int4 Src, 2x float4 per channel) for 2x MLP.
__global__ __launch_bounds__(256) void bv_apply_kernel(
    const float* __restrict__ Win, int Cin,
    float* __restrict__ Wout, int Cout,
    const int* __restrict__ Src)
{
    int t = blockIdx.x*256 + threadIdx.x;   // over BHW/8
    if (t >= BHW/8) return;
    const int c0 = 2 + blockIdx.y*4;        // channel group [c0, c0+4)
    int p = t << 3;
    int b = p >> 18;
    int own = p & (HW-1);
    const float* inb  = Win  + (size_t)b*Cin*HW;
    float*       outb = Wout + (size_t)b*Cout*HW;
    const int* Srb = Src + ((size_t)b << 18);

    int4 sA = *(const int4*)(Srb + own);
    int4 sB = *(const int4*)(Srb + own + 4);
    unsigned sv[8] = {(unsigned)sA.x, (unsigned)sA.y, (unsigned)sA.z, (unsigned)sA.w,
                      (unsigned)sB.x, (unsigned)sB.y, (unsigned)sB.z, (unsigned)sB.w};
    int kind[8], idx[8]; bool need[8];
    bool allself = true;
    #pragma unroll
    for (int j = 0; j < 8; ++j) {
        kind[j] = (int)(sv[j] >> 30);
        idx[j]  = (int)(sv[j] & 0x3FFFFu);
        need[j] = (kind[j] != 0) || (idx[j] != own + j);
        allself = allself && !need[j];
    }

    if (allself) {
        #pragma unroll
        for (int c = 0; c < 4; ++c) {
            const float* ic = inb + (size_t)(c0 + c)*HW;
            float*       oc = outb + (size_t)(c0 + c)*HW;
            float4 va = *(const float4*)(ic + own);
            float4 vb = *(const float4*)(ic + own + 4);
            *(float4*)(oc + own)     = va;
            *(float4*)(oc + own + 4) = vb;
        }
        return;
    }
    #pragma unroll
    for (int c = 0; c < 4; ++c) {
        const float* ic = inb + (size_t)(c0 + c)*HW;
        float*       oc = outb + (size_t)(c0 + c)*HW;
        float4 va = *(const float4*)(ic + own);
        float4 vb = *(const float4*)(ic + own + 4);
        float r[8] = {va.x, va.y, va.z, va.w, vb.x, vb.y, vb.z, vb.w};
        #pragma unroll
        for (int j = 0; j < 8; ++j) {
            if (need[j])
                r[j] = (kind[j] == 0) ? ic[idx[j]] : 0.0f;  // 1/2/3 -> 0 (tree overwrites)
        }
        *(float4*)(oc + own)     = make_float4(r[0], r[1], r[2], r[3]);
        *(float4*)(oc + own + 4) = make_float4(r[4], r[5], r[6], r[7]);
    }
}

// ---- Kernel C: composed tree cells; thread per (entry, channel-group).
__global__ __launch_bounds__(256) void bv_tree_kernel(
    const float* __restrict__ Win,       // world_in, 20-ch
    float* __restrict__ Wout,            // out, 20-ch
    const uint2* __restrict__ tlist,
    const unsigned* __restrict__ pcount, // [1] = entry count
    unsigned listcap,
    const unsigned char* __restrict__ M1,
    const unsigned char* __restrict__ SB1,
    const unsigned char* __restrict__ M2,
    const unsigned char* __restrict__ SB2)
{
    unsigned n = pcount[1]; if (n > listcap) n = listcap;
    unsigned total = n * 4;
    for (unsigned i = blockIdx.x*256 + threadIdx.x; i < total; i += gridDim.x*256) {
        unsigned ei = i >> 2; int grp = (int)(i & 3);
        uint2 e = tlist[ei];
        int b = (int)((e.x >> 18) & 3u);
        int g = (int)(e.x & 0x3FFFFu);
        const float* inb  = Win  + (size_t)b*20*HW;
        float*       outb = Wout + (size_t)b*20*HW;
        const unsigned char* M1b  = M1  + ((size_t)b << 18);
        const unsigned char* SB1b = SB1 + ((size_t)b << 18);
        int c0 = 2 + grp*4;
        const float* i0 = inb + (size_t)c0*HW;
        const float* i1 = i0 + HW;
        const float* i2 = i1 + HW;
        const float* i3 = i2 + HW;
        float r0, r1, r2, r3;
        if (e.y >> 31) {        // type A: tree2
            int cc = (int)(e.y & 0x3FFFFu);
            int ss = (int)((e.y >> 28) & 7u);
            const unsigned char* M2b  = M2  + ((size_t)b << 18);
            const unsigned char* SB2b = SB2 + ((size_t)b << 18);
            bv_eval4_ind(cc, ss, M2b, SB2b, M1b, SB1b, i0, i1, i2, i3, r0, r1, r2, r3);
        } else {                // type B: iter1 value at s
            int s = (int)(e.y & 0x3FFFFu);
            bv_leaf1_4(s, M1b, SB1b, i0, i1, i2, i3, r0, r1, r2, r3);
        }
        outb[(size_t)(c0 + 0)*HW + g] = r0;
        outb[(size_t)(c0 + 1)*HW + g] = r1;
        outb[(size_t)(c0 + 2)*HW + g] = r2;
        outb[(size_t)(c0 + 3)*HW + g] = r3;
    }
}

// smooth(0.95*v): conv3x3(ones/18, zero-pad) + center*0.5
// -> world ch18,19 AND velocity tail (fused copy; vin is a ws buffer).
__global__ __launch_bounds__(256) void bv_smooth_kernel(
    const float* __restrict__ vin, float* __restrict__ dout)
{
    int idx = blockIdx.x*256 + threadIdx.x;
    if (idx >= BATCH*2*HW) return;
    int x = idx & (WW-1);
    int y = (idx >> 9) & (HH-1);
    int c = (idx >> 18) & 1;
    int b = idx >> 19;
    const float* vb = vin + (size_t)(b*2 + c)*HW;
    const float w18 = (float)(1.0/18.0);
    float acc = 0.0f;
    for (int ky = -1; ky <= 1; ++ky) {
        int yy = y + ky;
        if ((unsigned)yy >= HH) continue;
        for (int kx = -1; kx <= 1; ++kx) {
            int xx2 = x + kx;
            if ((unsigned)xx2 >= WW) continue;
            float s = 0.95f * vb[yy*WW + xx2];
            acc += s * w18;
        }
    }
    float sc = 0.95f * vb[y*WW + x];
    float res = acc + sc * 0.5f;
    dout[((size_t)b*20 + 18 + c)*HW + (size_t)(y<<9) + x] = res;
    dout[(size_t)BATCH*20*HW + (size_t)idx] = res;
}

extern "C" void kernel_launch(void* const* d_in, const int* in_sizes, int n_in,
                              void* d_out, int out_size, void* d_ws, size_t ws_size,
                              hipStream_t stream)
{
    const float* world_in   = (const float*)d_in[0];
    const float* vel_in     = (const float*)d_in[1];
    const float* elem_empty = (const float*)d_in[2];
    float* out = (float*)d_out;

    // ws (~39 MB): w01 | vd1 | vel2 | bk | M1 | SB1 | M2 | SB2 | Src1 | Src2 | cnt | tlist
    float* w01  = (float*)d_ws;                                // 4*2*HW floats
    float* vd1  = w01 + (size_t)BATCH*2*HW;
    float* vel2 = vd1 + (size_t)BATCH*2*HW;
    unsigned char* bk  = (unsigned char*)(vel2 + (size_t)BATCH*2*HW);
    unsigned char* M1  = bk  + (size_t)BHW;
    unsigned char* SB1 = M1  + (size_t)BHW;
    unsigned char* M2  = SB1 + (size_t)BHW;
    unsigned char* SB2 = M2  + (size_t)BHW;
    int* Src1 = (int*)(SB2 + (size_t)BHW);
    int* Src2 = Src1 + (size_t)BHW;
    unsigned* pcount = (unsigned*)(Src2 + (size_t)BHW);
    uint2* tlistb = (uint2*)(pcount + 16);
    const unsigned listcap = 1u << 18;                         // 256K entries, 2 MB

    dim3 blk(256);
    dim3 grd((BHW + 255)/256);
    dim3 g2((BATCH*2*HW + 255)/256);
    dim3 gA(BATCH*16*16);            // 1024 tile-blocks
    dim3 gB(BHW/8/256, 4);           // 512 x 4 channel-groups
    dim3 gT(256);                    // tree kernel, grid-stride

    // iter1 masks (bucket on vel_in; evolve ch0/1 world_in -> w01)
    bv_bucket_kernel<<<grd, blk, 0, stream>>>(vel_in, bk, pcount);
    bv_mask_kernel<false><<<gA, dim3(ANT), 0, stream>>>(
        world_in, 20, w01, 2, bk, M1, SB1, Src1,
        (const int*)nullptr, pcount, (uint2*)nullptr, 0u, elem_empty);
    // vdelta1 -> vd1; fused bucket2 -> bk; zeroes list counter
    bv_vdelta_kernel<<<grd, blk, 0, stream>>>(M1, SB1, vel_in, vd1, bk, pcount);
    // iter2 masks (evolve ch0/1 w01 -> out; compose Src2 = P2 o P1)
    bv_mask_kernel<true><<<gA, dim3(ANT), 0, stream>>>(
        w01, 2, out, 20, bk, M2, SB2, Src2,
        Src1, pcount, tlistb, listcap, elem_empty);
    // vdelta2 -> vel2 (ws)
    bv_vdelta_kernel<<<grd, blk, 0, stream>>>(M2, SB2, vd1, vel2,
                                              (unsigned char*)nullptr,
                                              (unsigned*)nullptr);
    // passive channels: single composed gather pass + rare tree overwrite
    bv_apply_kernel<<<gB, blk, 0, stream>>>(world_in, 20, out, 20, Src2);
    bv_tree_kernel<<<gT, blk, 0, stream>>>(world_in, out, tlistb, pcount,
                                           listcap, M1, SB1, M2, SB2);
    // epilogue: smoothed velocity -> ch18/19 + tail
    bv_smooth_kernel<<<g2, blk, 0, stream>>>(vel2, out);
}

// Round 16
// 174.744 us; speedup vs baseline: 9.6253x; 1.0568x over previous
//
#include <hip/hip_runtime.h>
#include <math.h>

#define HH 512
#define WW 512
#define HW (HH*WW)          // 262144
#define BATCH 4
#define NCH 18              // simulated channels (18,19 overwritten at end)
#define BHW (BATCH*HW)

__device__ __constant__ int cDG[8] = {-512,-511,1,513,512,511,-1,-513}; // dy*WW+dx
__device__ __constant__ int cDT[8] = {-48,-47,1,49,48,47,-1,-49};       // dy*ATP+dx

// bucket (3 bits) | enough (bit 3); zeroes list counter
__global__ __launch_bounds__(256) void bv_bucket_kernel(
    const float* __restrict__ vel, unsigned char* __restrict__ bk,
    unsigned* __restrict__ pcount)
{
    int idx = blockIdx.x*256 + threadIdx.x;
    if (idx == 0) { pcount[0] = 0; pcount[1] = 0; }
    if (idx >= BHW) return;
    int b = idx >> 18;
    int rem = idx & (HW-1);
    const float* vb = vel + (size_t)b*2*HW;
    float vy = vb[rem];
    float vx = vb[HW + rem];
    float a2 = vy*vy;
    float b2 = vx*vx;
    float mag = sqrtf(a2 + b2);
    float xx = vx / (mag + 0.001f);
    float af = (float)acos((double)xx);
    const float inv2pi = (float)(1.0/(2.0*3.14159265358979323846));
    float raw = inv2pi * af;
    float ang = (vy < 0.0f) ? (1.0f - raw) : raw;
    float t = ang * 8.0f + 0.5f;
    int bkt = (int)floorf(t);
    bkt &= 7;
    unsigned char e = (mag > 0.1f) ? (unsigned char)8 : (unsigned char)0;
    bk[idx] = (unsigned char)(bkt | e);
}

#define ATP 48
#define ATC (48*48)   // 2304 = 4*512 + 256
#define ANT 512
#define PAD 49        // max |doff|; pads replace index clamps

// ---- Kernel A: fused mask+evolve with PADDED LDS (no index clamps ->
//      immediate-offset ds_read). Pad garbage only reaches ring-0 rim
//      cells, never consumed (validity cone) -> outputs deterministic.
//      COMPOSE=false (iter1): plain records. COMPOSE=true (iter2):
//      composes with Src1; trees to compacted list (1 global atomic).
template<bool COMPOSE>
__global__ __launch_bounds__(ANT) void bv_mask_kernel(
    const float* __restrict__ Win, int Cin,
    float* __restrict__ Wout, int Cout,
    const unsigned char* __restrict__ bkall,
    unsigned char* __restrict__ Mg,
    unsigned char* __restrict__ SBg,
    int* __restrict__ SrcOut,
    const int* __restrict__ Src1g,     // COMPOSE only
    unsigned* __restrict__ pcount,     // [1]=tree entries (COMPOSE only)
    uint2* __restrict__ tlist,
    unsigned listcap,
    const float* __restrict__ elem_empty)
{
    // carve: A0|A1|B0|B1 (2402 floats each) | KSH (2402 B) | sCnt
    __shared__ __align__(16) unsigned char SHM[40864];
    float* A0  = ((float*)(SHM +     0)) + PAD;
    float* A1  = ((float*)(SHM +  9608)) + PAD;
    float* B0F = ((float*)(SHM + 19216)) + PAD;
    float* B1F = ((float*)(SHM + 28824)) + PAD;
    unsigned char* KSH = SHM + 38432 + PAD;
    unsigned* sCnt = (unsigned*)(SHM + 40840);

    unsigned char* MSHb = SHM + 19216 + PAD;   // post-steps M bytes (B0F dead)
    unsigned char* SBb  = SHM + 28824 + PAD;   // post-steps SB bytes (B1F dead)

    const int tid = threadIdx.x;
    const int blk = blockIdx.x;
    const int tx = blk & 15, ty = (blk >> 4) & 15, b = blk >> 8;
    const int x0 = tx*32 - 8, y0 = ty*32 - 8;

    const float* inb  = Win  + (size_t)b*Cin*HW;
    float*       outb = Wout + (size_t)b*Cout*HW;
    const unsigned char* bkb = bkall + ((size_t)b << 18);
    unsigned char* Mob  = Mg  + ((size_t)b << 18);
    unsigned char* SBob = SBg + ((size_t)b << 18);
    int*           Srb  = SrcOut + ((size_t)b << 18);

    const float e0 = elem_empty[0];
    const float e1 = elem_empty[1];

    float v0r[4], v1r[4];
    unsigned kreg[4], mreg[4];
    unsigned mtail = 0;

    if (tid == 0) sCnt[0] = 0;

    // ---- load: LDS + register copies for owned cells ----
    #pragma unroll
    for (int k = 0; k < 4; ++k) {
        int l = tid + (k << 9);
        int ly = l / ATP, lx = l - ly*ATP;
        int gy = y0 + ly, gx = x0 + lx;
        bool in = ((unsigned)gy < HH) && ((unsigned)gx < WW);
        int g = gy*WW + gx;
        float v0 = 0.f, v1 = 0.f; unsigned char kk = 0;
        if (in) { v0 = inb[g]; v1 = inb[HW + g]; kk = bkb[g]; }
        A0[l] = v0; A1[l] = v1; KSH[l] = kk;
        v0r[k] = v0; v1r[k] = v1; kreg[k] = kk; mreg[k] = 0;
    }
    if (tid < 256) {    // tail cells: LDS-resident values, register M
        int l = 2048 + tid;
        int ly = l / ATP, lx = l - ly*ATP;
        int gy = y0 + ly, gx = x0 + lx;
        bool in = ((unsigned)gy < HH) && ((unsigned)gx < WW);
        int g = gy*WW + gx;
        float v0 = 0.f, v1 = 0.f; unsigned char kk = 0;
        if (in) { v0 = inb[g]; v1 = inb[HW + g]; kk = bkb[g]; }
        A0[l] = v0; A1[l] = v1; KSH[l] = kk;
    }
    __syncthreads();

    // ---- 8 fused steps, one barrier each; unclamped padded access ----
    #pragma unroll
    for (int a = 0; a < 8; ++a) {
        const int doff = cDT[a];
        const unsigned tgt = (unsigned)(a | 8);
        const float* cA0 = (a & 1) ? B0F : A0;
        const float* cA1 = (a & 1) ? B1F : A1;
        float* nA0 = (a & 1) ? A0 : B0F;
        float* nA1 = (a & 1) ? A1 : B1F;
        #pragma unroll
        for (int k = 0; k < 4; ++k) {
            const int l = tid + (k << 9);
            const int ln = l + doff;
            const int lo = l - doff;
            float a0l = v0r[k], a1l = v1r[k];
            float a0n = cA0[ln];
            float a0o = cA0[lo], a1o = cA1[lo];
            unsigned ko = KSH[lo];
            bool sal = ((kreg[k] & 15u) == tgt) & (a0n > 0.5f) & !(a1l > 0.5f);
            bool sao = ((ko & 15u) == tgt) & (a0l > 0.5f) & !(a1o > 0.5f);
            mreg[k] |= (sal ? 1u : 0u) << a;
            float sa = sal ? 1.0f : 0.0f;
            float sb = sao ? 1.0f : 0.0f;
            float r0 = a0l - sa*a0l; r0 = r0 - sb*a0l; r0 = r0 + sa*e0; r0 = r0 + sb*a0o;
            float r1 = a1l - sa*a1l; r1 = r1 - sb*a1l; r1 = r1 + sa*e1; r1 = r1 + sb*a1o;
            v0r[k] = r0; v1r[k] = r1;
            nA0[l] = r0; nA1[l] = r1;
        }
        if (tid < 256) {
            const int l = 2048 + tid;
            const int ln = l + doff;
            const int lo = l - doff;
            float a0l = cA0[l], a1l = cA1[l];
            float a0n = cA0[ln];
            float a0o = cA0[lo], a1o = cA1[lo];
            unsigned kl = KSH[l], ko = KSH[lo];
            bool sal = ((kl & 15u) == tgt) & (a0n > 0.5f) & !(a1l > 0.5f);
            bool sao = ((ko & 15u) == tgt) & (a0l > 0.5f) & !(a1o > 0.5f);
            if (sal) mtail |= 1u << a;
            float sa = sal ? 1.0f : 0.0f;
            float sb = sao ? 1.0f : 0.0f;
            float r0 = a0l - sa*a0l; r0 = r0 - sb*a0l; r0 = r0 + sa*e0; r0 = r0 + sb*a0o;
            float r1 = a1l - sa*a1l; r1 = r1 - sb*a1l; r1 = r1 + sa*e1; r1 = r1 + sb*a1o;
            nA0[l] = r0; nA1[l] = r1;
        }
        __syncthreads();
    }
    // final ch0/ch1 in A0/A1; B0F/B1F dead -> M/SB byte arrays

    #pragma unroll
    for (int k = 0; k < 4; ++k) MSHb[tid + (k << 9)] = (unsigned char)mreg[k];
    if (tid < 256) MSHb[2048 + tid] = (unsigned char)mtail;
    __syncthreads();

    // SB bits (padded MSHb read, no clamps)
    for (int l = tid; l < ATC; l += ANT) {
        unsigned sb8 = 0;
        #pragma unroll
        for (int a = 0; a < 8; ++a) {
            int lo = l - cDT[a];
            sb8 |= (unsigned)((MSHb[lo] >> a) & 1) << a;
        }
        SBb[l] = (unsigned char)sb8;
    }
    __syncthreads();

    // ---- pass A: interior writes + provenance walk (+composition) ----
    int tNeed[2]; unsigned tLL[2], tEy[2];
    #pragma unroll
    for (int it = 0; it < 2; ++it) {
        tNeed[it] = 0;
        int li = tid + (it << 9);
        int iy = li >> 5, ix = li & 31;
        int l = (iy + 8)*ATP + ix + 8;
        int gy = ty*32 + iy, gx = tx*32 + ix;
        int g = gy*WW + gx;
        outb[g]      = A0[l];
        outb[HW + g] = A1[l];
        unsigned mm = MSHb[l], sbb = SBb[l];
        Mob[g]  = (unsigned char)mm;
        SBob[g] = (unsigned char)sbb;

        // provenance walk in LDS (in-tile by ring invariant)
        int cc = l, ss = 7, kd = 0;
        unsigned m = mm, sb = sbb;
        while (true) {
            unsigned evt = (m | sb) & ((2u << ss) - 1u);
            if (!evt) { kd = 0; break; }
            int bb = 31 - __builtin_clz(evt);
            int ia = (m >> bb) & 1, ib = (sb >> bb) & 1;
            if (ia && ib) { kd = 2; break; }        // tree at (cc, ss)
            if (ia) { kd = 1; break; }              // e=0 for c>=2 -> ZERO
            cc -= cDT[bb]; ss = bb - 1;             // sb-only: exact value move
            if (ss < 0) { kd = 0; break; }
            m = MSHb[cc]; sb = SBb[cc];
        }
        if (kd == 1) {
            Srb[g] = (int)(1u << 30);
        } else if (kd == 0) {
            int cly = cc / ATP, clx = cc - cly*ATP;
            unsigned s = (unsigned)((y0 + cly)*WW + (x0 + clx));
            if (!COMPOSE) {
                Srb[g] = (int)s;
            } else {
                unsigned r1 = (unsigned)Src1g[((size_t)b << 18) + s];
                unsigned k1 = r1 >> 30;
                if (k1 == 0u)      Srb[g] = (int)r1;        // copy o copy
                else if (k1 == 1u) Srb[g] = (int)(1u << 30);
                else { tNeed[it] = 1; tEy[it] = s; }        // type B: tree1 @ s
            }
        } else {
            if (!COMPOSE) {
                Srb[g] = (int)(2u << 30);   // lazy tree1 marker
            } else {
                int cly = cc / ATP, clx = cc - cly*ATP;
                unsigned ccg = (unsigned)((y0 + cly)*WW + (x0 + clx));
                tNeed[it] = 1;
                tEy[it] = (1u << 31) | ((unsigned)ss << 28) | ccg;   // type A
            }
        }
        if (COMPOSE && tNeed[it]) tLL[it] = atomicAdd(&sCnt[0], 1u);
    }
    if constexpr (COMPOSE) {
        __syncthreads();
        if (tid == 0) sCnt[1] = sCnt[0] ? atomicAdd(&pcount[1], sCnt[0]) : 0u;
        __syncthreads();
        unsigned lbase = sCnt[1];
        #pragma unroll
        for (int it = 0; it < 2; ++it) {
            if (!tNeed[it]) continue;
            int li = tid + (it << 9);
            int iy = li >> 5, ix = li & 31;
            int g = (ty*32 + iy)*WW + tx*32 + ix;
            unsigned lidx = lbase + tLL[it];
            if (lidx < listcap) {
                tlist[lidx] = make_uint2(((unsigned)b << 18) | (unsigned)g, tEy[it]);
                Srb[g] = (int)(2u << 30);           // placeholder
            } else {
                Srb[g] = (int)(3u << 30);           // unreachable (cap 16x margin)
            }
        }
    }
}

// ---- vdelta: own-cell M/SB + velocity; exact per-step op order.
//      Optionally emits next-iteration bucket bytes and zeroes list counter.
__global__ __launch_bounds__(256) void bv_vdelta_kernel(
    const unsigned char* __restrict__ M,
    const unsigned char* __restrict__ SB,
    const float* __restrict__ vel,
    float* __restrict__ vdout,
    unsigned char* __restrict__ bkout,   // nullable
    unsigned* __restrict__ pcount)       // nullable
{
    int idx = blockIdx.x*256 + threadIdx.x;
    if (bkout && idx == 0) pcount[1] = 0;
    if (idx >= BHW) return;
    int b = idx >> 18;
    int g = idx & (HW-1);
    const float* velb = vel   + (size_t)b*2*HW;
    float*       vdb  = vdout + (size_t)b*2*HW;
    unsigned mm  = M[((size_t)b << 18) + g];
    unsigned sbb = SB[((size_t)b << 18) + g];
    float vy = velb[g], vx = velb[HW + g];
    float ddy = vy, ddx = vx;
    unsigned act = mm | sbb;
    if (act) {
        #pragma unroll
        for (int a = 0; a < 8; ++a) {
            if ((act >> a) & 1) {
                float sa = (float)((mm  >> a) & 1);
                float sb = (float)((sbb >> a) & 1);
                float voy = 0.f, vox = 0.f;
                if (sb != 0.f) {
                    int go = g - cDG[a];     // in-image when sb=1
                    voy = velb[go]; vox = velb[HW + go];
                }
                ddy = ddy - (sa*vy)*0.5f; ddy = ddy + (sb*voy)*0.5f;
                ddx = ddx - (sa*vx)*0.5f; ddx = ddx + (sb*vox)*0.5f;
            }
        }
    }
    vdb[g]      = ddy;
    vdb[HW + g] = ddx;
    if (bkout) {
        float a2 = ddy*ddy;
        float b2 = ddx*ddx;
        float mag = sqrtf(a2 + b2);
        float xx = ddx / (mag + 0.001f);
        float af = (float)acos((double)xx);
        const float inv2pi = (float)(1.0/(2.0*3.14159265358979323846));
        float raw = inv2pi * af;
        float ang = (ddy < 0.0f) ? (1.0f - raw) : raw;
        float t = ang * 8.0f + 0.5f;
        int bkt = (int)floorf(t);
        bkt &= 7;
        unsigned char e = (mag > 0.1f) ? (unsigned char)8 : (unsigned char)0;
        bkout[idx] = (unsigned char)(bkt | e);
    }
}

// ---- scalar evaluator on (M,SB), DIRECT leaves. Depth <= 9.
__device__ __attribute__((noinline)) float bv_eval(
    int cell, int stp,
    const unsigned char* __restrict__ M,
    const unsigned char* __restrict__ SB,
    const float* __restrict__ initc)
{
    float vstk[10]; int vsp = 0;
    int cs_cell[10], cs_stp[10], cs_ph[10]; int csp = 0;
    cs_cell[0] = cell; cs_stp[0] = stp; cs_ph[0] = 0; csp = 1;
    while (csp > 0) {
        int ph = cs_ph[csp-1];
        if (ph == 0) {
            int cc = cs_cell[csp-1], ss = cs_stp[csp-1];
            float result = 0.0f; int have = 0;
            while (true) {
                if (ss < 0) { result = initc[cc]; have = 1; break; }
                unsigned m = M[cc], sb = SB[cc];
                unsigned evt = (m | sb) & ((2u << ss) - 1u);
                if (!evt) { result = initc[cc]; have = 1; break; }
                int bb = 31 - __builtin_clz(evt);
                int ia = (m >> bb) & 1, ib = (sb >> bb) & 1;
                if (ia && ib) {
                    cs_cell[csp-1] = cc; cs_stp[csp-1] = bb; cs_ph[csp-1] = 1;
                    cs_cell[csp] = cc - cDG[bb]; cs_stp[csp] = bb - 1; cs_ph[csp] = 0; csp++;
                    break;
                }
                if (ia) { result = 0.0f; have = 1; break; }
                cc -= cDG[bb]; ss = bb - 1;
            }
            if (have) { vstk[vsp++] = result; csp--; }
        } else if (ph == 1) {
            cs_ph[csp-1] = 2;
            cs_cell[csp] = cs_cell[csp-1]; cs_stp[csp] = cs_stp[csp-1] - 1;
            cs_ph[csp] = 0; csp++;
        } else {
            float Bv = vstk[--vsp]; float Av = vstk[--vsp];
            vstk[vsp++] = Av - Bv;   // fl(wo - w)
            csp--;
        }
    }
    return vstk[0];
}

// iter1 value at cell L, one channel (walk M1/SB1; rare tree -> bv_eval)
__device__ float bv_leaf1_1(int L,
    const unsigned char* __restrict__ M1,
    const unsigned char* __restrict__ SB1,
    const float* __restrict__ ic)
{
    int cc = L, ss = 7;
    while (true) {
        unsigned m = M1[cc], sb = SB1[cc];
        unsigned evt = (m | sb) & ((2u << ss) - 1u);
        if (!evt) break;                        // value = input at cc
        int bb = 31 - __builtin_clz(evt);
        int ia = (m >> bb) & 1, ib = (sb >> bb) & 1;
        if (ia && ib) return bv_eval(cc, bb, M1, SB1, ic);   // tree1
        if (ia) return 0.0f;
        cc -= cDG[bb]; ss = bb - 1;
        if (ss < 0) break;                      // value = input at cc
    }
    return ic[cc];
}

// scalar evaluator on (M2,SB2) with leaves INDIRECTED through iter1.
__device__ float bv_eval1_ind(int cell, int stp,
    const unsigned char* __restrict__ M2,
    const unsigned char* __restrict__ SB2,
    const unsigned char* __restrict__ M1,
    const unsigned char* __restrict__ SB1,
    const float* __restrict__ ic)
{
    float vstk[10]; int vsp = 0;
    int cs_cell[10], cs_stp[10], cs_ph[10]; int csp = 0;
    cs_cell[0] = cell; cs_stp[0] = stp; cs_ph[0] = 0; csp = 1;
    while (csp > 0) {
        int ph = cs_ph[csp-1];
        if (ph == 0) {
            int cc = cs_cell[csp-1], ss = cs_stp[csp-1];
            int have = 0, zero = 0, leaf = 0;
            while (true) {
                if (ss < 0) { leaf = cc; have = 1; break; }
                unsigned m = M2[cc], sb = SB2[cc];
                unsigned evt = (m | sb) & ((2u << ss) - 1u);
                if (!evt) { leaf = cc; have = 1; break; }
                int bb = 31 - __builtin_clz(evt);
                int ia = (m >> bb) & 1, ib = (sb >> bb) & 1;
                if (ia && ib) {
                    cs_cell[csp-1] = cc; cs_stp[csp-1] = bb; cs_ph[csp-1] = 1;
                    cs_cell[csp] = cc - cDG[bb]; cs_stp[csp] = bb - 1; cs_ph[csp] = 0; csp++;
                    break;
                }
                if (ia) { zero = 1; have = 1; break; }
                cc -= cDG[bb]; ss = bb - 1;
            }
            if (have) {
                vstk[vsp++] = zero ? 0.0f : bv_leaf1_1(leaf, M1, SB1, ic);
                csp--;
            }
        } else if (ph == 1) {
            cs_ph[csp-1] = 2;
            cs_cell[csp] = cs_cell[csp-1]; cs_stp[csp] = cs_stp[csp-1] - 1;
            cs_ph[csp] = 0; csp++;
        } else {
            float Bv = vstk[--vsp]; float Av = vstk[--vsp];
            vstk[vsp++] = Av - Bv;
            csp--;
        }
    }
    return vstk[0];
}

// ---- Kernel B: apply composed provenance world_in -> out.
//      8 pixels/thread (2x int4 Src, 2x float4 per channel) for 2x MLP.
__global__ __launch_bounds__(256) void bv_apply_kernel(
    const float* __restrict__ Win, int Cin,
    float* __restrict__ Wout, int Cout,
    const int* __restrict__ Src)
{
    int t = blockIdx.x*256 + threadIdx.x;   // over BHW/8
    if (t >= BHW/8) return;
    const int c0 = 2 + blockIdx.y*4;        // channel group [c0, c0+4)
    int p = t << 3;
    int b = p >> 18;
    int own = p & (HW-1);
    const float* inb  = Win  + (size_t)b*Cin*HW;
    float*       outb = Wout + (size_t)b*Cout*HW;
    const int* Srb = Src + ((size_t)b << 18);

    int4 sA = *(const int4*)(Srb + own);
    int4 sB = *(const int4*)(Srb + own + 4);
    unsigned sv[8] = {(unsigned)sA.x, (unsigned)sA.y, (unsigned)sA.z, (unsigned)sA.w,
                      (unsigned)sB.x, (unsigned)sB.y, (unsigned)sB.z, (unsigned)sB.w};
    int kind[8], idx[8]; bool need[8];
    bool allself = true;
    #pragma unroll
    for (int j = 0; j < 8; ++j) {
        kind[j] = (int)(sv[j] >> 30);
        idx[j]  = (int)(sv[j] & 0x3FFFFu);
        need[j] = (kind[j] != 0) || (idx[j] != own + j);
        allself = allself && !need[j];
    }

    if (allself) {
        #pragma unroll
        for (int c = 0; c < 4; ++c) {
            const float* ic = inb + (size_t)(c0 + c)*HW;
            float*       oc = outb + (size_t)(c0 + c)*HW;
            float4 va = *(const float4*)(ic + own);
            float4 vb = *(const float4*)(ic + own + 4);
            *(float4*)(oc + own)     = va;
            *(float4*)(oc + own + 4) = vb;
        }
        return;
    }
    #pragma unroll
    for (int c = 0; c < 4; ++c) {
        const float* ic = inb + (size_t)(c0 + c)*HW;
        float*       oc = outb + (size_t)(c0 + c)*HW;
        float4 va = *(const float4*)(ic + own);
        float4 vb = *(const float4*)(ic + own + 4);
        float r[8] = {va.x, va.y, va.z, va.w, vb.x, vb.y, vb.z, vb.w};
        #pragma unroll
        for (int j = 0; j < 8; ++j) {
            if (need[j])
                r[j] = (kind[j] == 0) ? ic[idx[j]] : 0.0f;  // 1/2/3 -> 0 (tree overwrites)
        }
        *(float4*)(oc + own)     = make_float4(r[0], r[1], r[2], r[3]);
        *(float4*)(oc + own + 4) = make_float4(r[4], r[5], r[6], r[7]);
    }
}

// ---- Kernel C: composed tree cells; thread per (entry, CHANNEL).
//      16 lanes share one entry -> identical control flow (walk bytes
//      L1-broadcast); one float stack per thread (1/4 the scratch).
__global__ __launch_bounds__(256) void bv_tree_kernel(
    const float* __restrict__ Win,       // world_in, 20-ch
    float* __restrict__ Wout,            // out, 20-ch
    const uint2* __restrict__ tlist,
    const unsigned* __restrict__ pcount, // [1] = entry count
    unsigned listcap,
    const unsigned char* __restrict__ M1,
    const unsigned char* __restrict__ SB1,
    const unsigned char* __restrict__ M2,
    const unsigned char* __restrict__ SB2)
{
    unsigned n = pcount[1]; if (n > listcap) n = listcap;
    unsigned total = n * 16;
    for (unsigned i = blockIdx.x*256 + threadIdx.x; i < total; i += gridDim.x*256) {
        unsigned ei = i >> 4; int c = 2 + (int)(i & 15);
        uint2 e = tlist[ei];
        int b = (int)((e.x >> 18) & 3u);
        int g = (int)(e.x & 0x3FFFFu);
        const float* ic = Win  + (size_t)b*20*HW + (size_t)c*HW;
        float*       oc = Wout + (size_t)b*20*HW + (size_t)c*HW;
        const unsigned char* M1b  = M1  + ((size_t)b << 18);
        const unsigned char* SB1b = SB1 + ((size_t)b << 18);
        float r;
        if (e.y >> 31) {        // type A: tree2
            int cc = (int)(e.y & 0x3FFFFu);
            int ss = (int)((e.y >> 28) & 7u);
            const unsigned char* M2b  = M2  + ((size_t)b << 18);
            const unsigned char* SB2b = SB2 + ((size_t)b << 18);
            r = bv_eval1_ind(cc, ss, M2b, SB2b, M1b, SB1b, ic);
        } else {                // type B: iter1 value at s
            int s = (int)(e.y & 0x3FFFFu);
            r = bv_leaf1_1(s, M1b, SB1b, ic);
        }
        oc[g] = r;
    }
}

// smooth(0.95*v): conv3x3(ones/18, zero-pad) + center*0.5
// -> world ch18,19 AND velocity tail (fused copy; vin is a ws buffer).
__global__ __launch_bounds__(256) void bv_smooth_kernel(
    const float* __restrict__ vin, float* __restrict__ dout)
{
    int idx = blockIdx.x*256 + threadIdx.x;
    if (idx >= BATCH*2*HW) return;
    int x = idx & (WW-1);
    int y = (idx >> 9) & (HH-1);
    int c = (idx >> 18) & 1;
    int b = idx >> 19;
    const float* vb = vin + (size_t)(b*2 + c)*HW;
    const float w18 = (float)(1.0/18.0);
    float acc = 0.0f;
    for (int ky = -1; ky <= 1; ++ky) {
        int yy = y + ky;
        if ((unsigned)yy >= HH) continue;
        for (int kx = -1; kx <= 1; ++kx) {
            int xx2 = x + kx;
            if ((unsigned)xx2 >= WW) continue;
            float s = 0.95f * vb[yy*WW + xx2];
            acc += s * w18;
        }
    }
    float sc = 0.95f * vb[y*WW + x];
    float res = acc + sc * 0.5f;
    dout[((size_t)b*20 + 18 + c)*HW + (size_t)(y<<9) + x] = res;
    dout[(size_t)BATCH*20*HW + (size_t)idx] = res;
}

extern "C" void kernel_launch(void* const* d_in, const int* in_sizes, int n_in,
                              void* d_out, int out_size, void* d_ws, size_t ws_size,
                              hipStream_t stream)
{
    const float* world_in   = (const float*)d_in[0];
    const float* vel_in     = (const float*)d_in[1];
    const float* elem_empty = (const float*)d_in[2];
    float* out = (float*)d_out;

    // ws (~39 MB): w01 | vd1 | vel2 | bk | M1 | SB1 | M2 | SB2 | Src1 | Src2 | cnt | tlist
    float* w01  = (float*)d_ws;                                // 4*2*HW floats
    float* vd1  = w01 + (size_t)BATCH*2*HW;
    float* vel2 = vd1 + (size_t)BATCH*2*HW;
    unsigned char* bk  = (unsigned char*)(vel2 + (size_t)BATCH*2*HW);
    unsigned char* M1  = bk  + (size_t)BHW;
    unsigned char* SB1 = M1  + (size_t)BHW;
    unsigned char* M2  = SB1 + (size_t)BHW;
    unsigned char* SB2 = M2  + (size_t)BHW;
    int* Src1 = (int*)(SB2 + (size_t)BHW);
    int* Src2 = Src1 + (size_t)BHW;
    unsigned* pcount = (unsigned*)(Src2 + (size_t)BHW);
    uint2* tlistb = (uint2*)(pcount + 16);
    const unsigned listcap = 1u << 18;                         // 256K entries, 2 MB

    dim3 blk(256);
    dim3 grd((BHW + 255)/256);
    dim3 g2((BATCH*2*HW + 255)/256);
    dim3 gA(BATCH*16*16);            // 1024 tile-blocks
    dim3 gB(BHW/8/256, 4);           // 512 x 4 channel-groups
    dim3 gT(1024);                   // tree kernel, grid-stride

    // iter1 masks (bucket on vel_in; evolve ch0/1 world_in -> w01)
    bv_bucket_kernel<<<grd, blk, 0, stream>>>(vel_in, bk, pcount);
    bv_mask_kernel<false><<<gA, dim3(ANT), 0, stream>>>(
        world_in, 20, w01, 2, bk, M1, SB1, Src1,
        (const int*)nullptr, pcount, (uint2*)nullptr, 0u, elem_empty);
    // vdelta1 -> vd1; fused bucket2 -> bk; zeroes list counter
    bv_vdelta_kernel<<<grd, blk, 0, stream>>>(M1, SB1, vel_in, vd1, bk, pcount);
    // iter2 masks (evolve ch0/1 w01 -> out; compose Src2 = P2 o P1)
    bv_mask_kernel<true><<<gA, dim3(ANT), 0, stream>>>(
        w01, 2, out, 20, bk, M2, SB2, Src2,
        Src1, pcount, tlistb, listcap, elem_empty);
    // vdelta2 -> vel2 (ws)
    bv_vdelta_kernel<<<grd, blk, 0, stream>>>(M2, SB2, vd1, vel2,
                                              (unsigned char*)nullptr,
                                              (unsigned*)nullptr);
    // passive channels: single composed gather pass + rare tree overwrite
    bv_apply_kernel<<<gB, blk, 0, stream>>>(world_in, 20, out, 20, Src2);
    bv_tree_kernel<<<gT, blk, 0, stream>>>(world_in, out, tlistb, pcount,
                                           listcap, M1, SB1, M2, SB2);
    // epilogue: smoothed velocity -> ch18/19 + tail
    bv_smooth_kernel<<<g2, blk, 0, stream>>>(vel2, out);
}